// Round 1
// baseline (2863.247 us; speedup 1.0000x reference)
//
#include <hip/hip_runtime.h>

#define TT 4
#define RR 8
#define NH 8
#define DKK 32

typedef float floatx4 __attribute__((ext_vector_type(4)));
typedef __bf16 bf16x8 __attribute__((ext_vector_type(8)));

__device__ __forceinline__ float us2f(unsigned short s){
    union{unsigned int u; float f;} x; x.u = ((unsigned int)s) << 16; return x.f;
}
__device__ __forceinline__ float lo2f(unsigned int u){
    union{unsigned int x; float f;} a; a.x = u << 16; return a.f;
}
__device__ __forceinline__ float hi2f(unsigned int u){
    union{unsigned int x; float f;} a; a.x = u & 0xffff0000u; return a.f;
}
__device__ __forceinline__ unsigned short f2us(float f){
    union{float f; unsigned int u;} x; x.f = f;
    unsigned int u = x.u;
    unsigned int r = (u + 0x7fffu + ((u >> 16) & 1u)) >> 16;   // RNE bf16
    return (unsigned short)r;
}
__device__ __forceinline__ float ldf(const void* p, int i, int isf32){
    return isf32 ? ((const float*)p)[i] : us2f(((const unsigned short*)p)[i]);
}
__device__ __forceinline__ float4 ldf4(const void* p, int i, int isf32){  // i % 4 == 0
    if (isf32) return *reinterpret_cast<const float4*>((const float*)p + i);
    uint2 u = *reinterpret_cast<const uint2*>((const unsigned short*)p + i);
    float4 r; r.x = lo2f(u.x); r.y = hi2f(u.x); r.z = lo2f(u.y); r.w = hi2f(u.y);
    return r;
}
__device__ __forceinline__ const int* sel3(const int* a, const int* b, const int* c, int s){
    return (s == 0) ? a : (s == 1) ? b : c;
}
__device__ __forceinline__ int sw32(int row, int g){
    return row * 32 + ((g ^ (row >> 2)) & 3) * 8;
}

// ---- per-array dtype flags: meta[30+id] = 0 bf16 / 1 fp32 / -1 unknown ----
__global__ void k_flags(const void* p0, const void* p1, const void* p2, const void* p3,
                        const void* p4, const void* p5, const void* p6, const void* p7,
                        const void* p8, const void* p9, const void* p10, const void* p11,
                        const void* p12,
                        int n0, int n1, int n2, int n3, int n4, int n5, int n6, int n7,
                        int n8, int n9, int n10, int n11, int n12,
                        int* __restrict__ meta)
{
    const void* ps[13] = {p0,p1,p2,p3,p4,p5,p6,p7,p8,p9,p10,p11,p12};
    int ns[13] = {n0,n1,n2,n3,n4,n5,n6,n7,n8,n9,n10,n11,n12};
    int id = blockIdx.x;
    const unsigned short* p = (const unsigned short*)ps[id];
    int half = ns[id] >> 1;
    int nsamp = (half < 256) ? half : 256;
    int step = (nsamp > 0) ? (half / nsamp) : 1;
    int tid = threadIdx.x;
    int sane = 0, nzv = 0;
    if (tid < nsamp){
        unsigned short u = p[2 * (tid * step)];
        nzv = (u != 0);
        int e = (u >> 7) & 0xFF;
        sane = (e >= 100 && e <= 140) ? 1 : 0;
    }
    __shared__ int c_s[4], c_n[4];
    unsigned long long ms = __ballot(sane != 0);
    unsigned long long mn = __ballot(nzv != 0);
    if ((tid & 63) == 0){ c_s[tid >> 6] = (int)__popcll(ms); c_n[tid >> 6] = (int)__popcll(mn); }
    __syncthreads();
    if (tid == 0){
        int cs = c_s[0] + c_s[1] + c_s[2] + c_s[3];
        int cn = c_n[0] + c_n[1] + c_n[2] + c_n[3];
        meta[30 + id] = (cn == 0) ? -1 : ((2 * cs >= nsamp) ? 0 : 1);
    }
}
__global__ void k_flagfix(int* meta){
    if (threadIdx.x == 0 && blockIdx.x == 0){
        int xf = meta[30]; if (xf < 0) xf = 1;
        meta[30] = xf; meta[24] = xf;
        for (int j = 1; j < 13; j++) if (meta[30 + j] < 0) meta[30 + j] = xf;
    }
}

// ---- identify src/dst/etype among the three E-sized int arrays ----
__global__ void k_trio(const int* pa, const int* pb, const int* pc, int E, int n,
                       int* __restrict__ meta){
    const int* ps[3] = {pa, pb, pc};
    int c = blockIdx.x, tid = threadIdx.x;
    const int* p = ps[c];
    int step = E / 1024; if (step < 1) step = 1;
    int mx = 0, hits = 0;
    for (int j = 0; j < 4; j++){
        long long e = (long long)(tid + j * 256) * step;
        if (e < E){
            int v = p[e];
            mx = max(mx, v);
            hits += (v == (int)(e % n)) ? 1 : 0;
        }
    }
    __shared__ int smx[4], sh[4];
    for (int o = 32; o; o >>= 1){ mx = max(mx, __shfl_down(mx, o, 64)); hits += __shfl_down(hits, o, 64); }
    if ((tid & 63) == 0){ smx[tid >> 6] = mx; sh[tid >> 6] = hits; }
    __syncthreads();
    if (tid == 0){
        mx = max(max(smx[0], smx[1]), max(smx[2], smx[3]));
        hits = sh[0] + sh[1] + sh[2] + sh[3];
        meta[44 + c] = mx; meta[47 + c] = hits;
    }
}
__global__ void k_pick(int* meta){
    if (threadIdx.x == 0 && blockIdx.x == 0){
        int m0 = meta[44], m1 = meta[45], m2 = meta[46];
        int h[3] = {meta[47], meta[48], meta[49]};
        int et = (m2 < 8) ? 2 : ((m0 < 8) ? 0 : ((m1 < 8) ? 1 : 2));
        int a = -1, b = -1;
        for (int c = 0; c < 3; c++) if (c != et){ if (a < 0) a = c; else b = c; }
        int srcsel = a, dstsel = b;
        if (h[a] >= 1000 && h[b] < 1000){ dstsel = a; srcsel = b; }
        meta[25] = srcsel; meta[26] = dstsel; meta[27] = et;
    }
}

// ---- fallbacks ----
__global__ void k_zerofill(float* out, int tot){
    int i = blockIdx.x * 256 + threadIdx.x;
    if (i < tot) out[i] = 0.f;
}
__global__ void k_copy(const void* __restrict__ xv, float* __restrict__ out,
                       const int* __restrict__ meta, int tot){
    int isf32 = meta[24];
    int i = blockIdx.x * 256 + threadIdx.x;
    if (i < tot) out[i] = ldf(xv, i, isf32);
}

// ---- bucket build (validated r3) ----
__global__ void k_init(int* meta){
    if (threadIdx.x < 24) meta[threadIdx.x] = 0;
}
__global__ void k_count(const int* __restrict__ nt, int* __restrict__ meta, int n){
    int i = blockIdx.x * 256 + threadIdx.x;
    int t = (i < n) ? (nt[i] & 3) : -1;
    int lane = threadIdx.x & 63;
    #pragma unroll
    for (int tt = 0; tt < TT; tt++){
        unsigned long long m = __ballot(t == tt);
        if (m){
            int leader = __builtin_ctzll(m);
            if (lane == leader) atomicAdd(&meta[tt], (int)__popcll(m));
        }
    }
}
__global__ void k_prefix(int* meta){
    if (threadIdx.x == 0){
        int off = 0, tb = 0;
        for (int t = 0; t < TT; t++){
            int c = meta[t];
            meta[4 + t]  = off;
            meta[13 + t] = off;
            meta[8 + t]  = tb;
            off += c;
            tb  += (c + 63) >> 6;
        }
        meta[12] = tb;
    }
}
__global__ void k_scatter(const int* __restrict__ nt, int* __restrict__ meta,
                          int* __restrict__ perm, int n){
    int i = blockIdx.x * 256 + threadIdx.x;
    int t = (i < n) ? (nt[i] & 3) : -1;
    int lane = threadIdx.x & 63;
    #pragma unroll
    for (int tt = 0; tt < TT; tt++){
        unsigned long long m = __ballot(t == tt);
        if (m){
            int leader = __builtin_ctzll(m);
            int base = 0;
            if (lane == leader) base = atomicAdd(&meta[13 + tt], (int)__popcll(m));
            base = __shfl(base, leader, 64);
            if (t == tt){
                int rank = __popcll(m & ((1ull << lane) - 1ull));
                perm[base + rank] = i;
            }
        }
    }
}

// ---- weight transpose: WT[m][outcol][k] = W[m][k][outcol] ----
__global__ void k_transW(const void* __restrict__ Wk, const void* __restrict__ Wq,
                         const void* __restrict__ Wv, const void* __restrict__ Wa,
                         unsigned short* __restrict__ WT, const int* __restrict__ meta)
{
    int idx = blockIdx.x * 256 + threadIdx.x;
    int m   = idx >> 16;
    int loc = idx & 65535;
    int j = loc >> 8, k = loc & 255;
    int mt = m >> 2, t = m & 3;
    const void* W = (mt == 0) ? Wk : (mt == 1) ? Wq : (mt == 2) ? Wv : Wa;
    int flag = meta[31 + mt];
    WT[idx] = f2us(ldf(W, t * 65536 + k * 256 + j, flag));
}

// ---- rel-table prep for MFMA path: hi/lo bf16 split; RMT transposed ----
// RAT[r][h][d][e] = rel_att[r][h][d][e]   (B layout [outcol=d][k=e])
// RMT[r][h][e][d] = rel_msg[r][h][d][e]   (B layout [outcol=e][k=d])
__global__ void k_transR(const void* __restrict__ rel_att, const void* __restrict__ rel_msg,
                         unsigned short* __restrict__ RATh, unsigned short* __restrict__ RATl,
                         unsigned short* __restrict__ RMTh, unsigned short* __restrict__ RMTl,
                         const int* __restrict__ meta)
{
    int idx = blockIdx.x * 256 + threadIdx.x;       // 0..65535
    int fra = meta[39], frm = meta[40];
    float wa = ldf(rel_att, idx, fra);
    unsigned short ha = f2us(wa);
    RATh[idx] = ha;
    RATl[idx] = f2us(wa - us2f(ha));
    int quad = idx >> 10, loc = idx & 1023, d = loc >> 5, e = loc & 31;
    float wm = ldf(rel_msg, quad * 1024 + d * 32 + e, frm);
    unsigned short hm = f2us(wm);
    int oidx = quad * 1024 + e * 32 + d;
    RMTh[oidx] = hm;
    RMTl[oidx] = f2us(wm - us2f(hm));
}

// ---- batched rel transform GEMM: out[n][r*256 + h*32 + col] =
//      sum_k A[n][h*32+k] * B[r][h][col][k]  (B split hi+lo bf16) ----
__global__ __launch_bounds__(256) void k_rel(
    const unsigned short* __restrict__ Ain,
    const unsigned short* __restrict__ Bhi, const unsigned short* __restrict__ Blo,
    float* __restrict__ outF, unsigned short* __restrict__ outH, int n)
{
    int base = blockIdx.x * 64;
    __shared__ __align__(16) unsigned short As[64 * 264];   // pad 8 halfs/row
    int tid = threadIdx.x;
    #pragma unroll
    for (int c = 0; c < 8; c++){
        int G = c * 256 + tid;            // granule of 8 halfs, 0..2047
        int row = G >> 5, g = G & 31;
        int node = base + row;
        uint4 v;
        if (node < n) v = *reinterpret_cast<const uint4*>(Ain + (size_t)node * 256 + g * 8);
        else { v.x = v.y = v.z = v.w = 0u; }
        *reinterpret_cast<uint4*>(&As[row * 264 + g * 8]) = v;
    }
    __syncthreads();
    int wave = tid >> 6, lane = tid & 63;
    int m16 = lane & 15, quad = lane >> 4;
    int r0 = wave * 16;

    bf16x8 a[8];
    #pragma unroll
    for (int h = 0; h < 8; h++)
        a[h] = *reinterpret_cast<const bf16x8*>(&As[(r0 + m16) * 264 + h * 32 + quad * 8]);

    for (int r = 0; r < RR; r++){
        floatx4 acc[8][2] = {};
        #pragma unroll
        for (int h = 0; h < 8; h++){
            #pragma unroll
            for (int ct = 0; ct < 2; ct++){
                int bix = (((r * 8 + h) * 32) + ct * 16 + m16) * 32 + quad * 8;
                bf16x8 bh = *reinterpret_cast<const bf16x8*>(Bhi + bix);
                bf16x8 bl = *reinterpret_cast<const bf16x8*>(Blo + bix);
                acc[h][ct] = __builtin_amdgcn_mfma_f32_16x16x32_bf16(a[h], bh, acc[h][ct], 0, 0, 0);
                acc[h][ct] = __builtin_amdgcn_mfma_f32_16x16x32_bf16(a[h], bl, acc[h][ct], 0, 0, 0);
            }
        }
        #pragma unroll
        for (int h = 0; h < 8; h++){
            #pragma unroll
            for (int ct = 0; ct < 2; ct++){
                #pragma unroll
                for (int reg = 0; reg < 4; reg++){
                    int row = r0 + quad * 4 + reg;
                    int node = base + row;
                    if (node < n){
                        int col = r * 256 + h * 32 + ct * 16 + m16;
                        float v = acc[h][ct][reg];
                        if (outF) outF[(size_t)node * 2048 + col] = v;
                        else      outH[(size_t)node * 2048 + col] = f2us(v);
                    }
                }
            }
        }
    }
}

// ---- CSR build ----
__global__ void k_zero(int* a, int n){
    int i = blockIdx.x * 256 + threadIdx.x;
    if (i < n) a[i] = 0;
}
__global__ void k_deg(const int* p2, const int* p3, const int* p4,
                      int* __restrict__ cnt, const int* __restrict__ meta, int E, int n){
    const int* dst = sel3(p2, p3, p4, meta[26]);
    int e = blockIdx.x * 256 + threadIdx.x;
    if (e < E){
        int d = dst[e];
        if (d >= 0 && d < n) atomicAdd(&cnt[d], 1);
    }
}
__global__ void k_scan1(const int* __restrict__ cnt, int* __restrict__ rowp,
                        int* __restrict__ bsum, int n){
    __shared__ int s[256];
    int b = blockIdx.x, tid = threadIdx.x;
    int i = b * 256 + tid;
    int v = (i < n) ? cnt[i] : 0;
    s[tid] = v;
    __syncthreads();
    for (int d = 1; d < 256; d <<= 1){
        int add = (tid >= d) ? s[tid - d] : 0;
        __syncthreads();
        s[tid] += add;
        __syncthreads();
    }
    if (i < n) rowp[i] = s[tid] - v;
    if (tid == 255) bsum[b] = s[255];
}
__global__ void k_scan2(int* bsum, int* rowp, int nb, int n){
    if (threadIdx.x == 0){
        int run = 0;
        for (int b = 0; b < nb; b++){ int t = bsum[b]; bsum[b] = run; run += t; }
        rowp[n] = run;
    }
}
__global__ void k_scan3(int* rowp, const int* __restrict__ bsum, int n){
    int i = blockIdx.x * 256 + threadIdx.x;
    if (i < n) rowp[i] += bsum[i >> 8];
}
__global__ void k_escat(const int* p2, const int* p3, const int* p4,
                        int* __restrict__ cur, const int* __restrict__ rowp,
                        int* __restrict__ eix, const int* __restrict__ meta, int E, int n){
    const int* dst = sel3(p2, p3, p4, meta[26]);
    int e = blockIdx.x * 256 + threadIdx.x;
    if (e < E){
        int d = dst[e];
        if (d >= 0 && d < n){
            int pos = atomicAdd(&cur[d], 1);
            eix[rowp[d] + pos] = e;
        }
    }
}

// ---- MFMA typed GEMM: QKV (validated r3, fp32-in adapted) ----
__global__ __launch_bounds__(256) void k_gemm_qkv(
    const void* __restrict__ Xv,
    const int* __restrict__ perm, const int* __restrict__ meta,
    const unsigned short* __restrict__ WT,
    const void* __restrict__ bk, const void* __restrict__ bq, const void* __restrict__ bv,
    unsigned short* __restrict__ kb, unsigned short* __restrict__ qb,
    unsigned short* __restrict__ vb)
{
    int rt = blockIdx.x;
    if (rt >= meta[12]) return;
    int fx = meta[30];
    int t = 0;
    while (t < TT - 1 && rt >= meta[8 + t + 1]) t++;
    int lt = rt - meta[8 + t];
    int rowStart = meta[4 + t] + (lt << 6);
    int rowEnd   = meta[4 + t] + meta[t];

    int ct = blockIdx.y;          // 0..5
    int mt = ct >> 1;             // 0=k 1=q 2=v
    int c0 = (ct & 1) * 128;
    const unsigned short* Wm = WT + (((mt << 2) + t) << 16);
    const void* bias = (mt == 0) ? bk : (mt == 1) ? bq : bv;
    int fb = meta[35 + mt];
    unsigned short* outb = (mt == 0) ? kb : (mt == 1) ? qb : vb;

    __shared__ __align__(16) unsigned short As[64 * 32];
    __shared__ __align__(16) unsigned short Bs[128 * 32];
    __shared__ int nodeIdx[64];

    int tid = threadIdx.x;
    if (tid < 64){
        int p = rowStart + tid;
        nodeIdx[tid] = perm[(p < rowEnd) ? p : (rowEnd - 1)];
    }
    __syncthreads();

    int wave = tid >> 6, lane = tid & 63;
    int wr = (wave >> 1) * 32;
    int wc = (wave & 1) * 64;
    int m16 = lane & 15, quad = lane >> 4;

    int arow = tid & 63, aseg = tid >> 6;
    int anode = nodeIdx[arow];

    floatx4 acc[2][4] = {};

    for (int k0 = 0; k0 < 256; k0 += 32){
        __syncthreads();
        uint4 av;
        if (fx){
            const float* af = (const float*)Xv + anode * 256 + aseg * 8 + k0;
            float4 f0 = *reinterpret_cast<const float4*>(af);
            float4 f1 = *reinterpret_cast<const float4*>(af + 4);
            av.x = (unsigned)f2us(f0.x) | ((unsigned)f2us(f0.y) << 16);
            av.y = (unsigned)f2us(f0.z) | ((unsigned)f2us(f0.w) << 16);
            av.z = (unsigned)f2us(f1.x) | ((unsigned)f2us(f1.y) << 16);
            av.w = (unsigned)f2us(f1.z) | ((unsigned)f2us(f1.w) << 16);
        } else {
            av = *reinterpret_cast<const uint4*>((const unsigned short*)Xv + anode * 256 + aseg * 8 + k0);
        }
        *reinterpret_cast<uint4*>(&As[sw32(arow, aseg)]) = av;
        #pragma unroll
        for (int it = 0; it < 2; it++){
            int idx2 = tid + it * 256;
            int cc = idx2 >> 2, g = idx2 & 3;
            uint4 bv4 = *reinterpret_cast<const uint4*>(Wm + (c0 + cc) * 256 + k0 + g * 8);
            *reinterpret_cast<uint4*>(&Bs[sw32(cc, g)]) = bv4;
        }
        __syncthreads();
        bf16x8 a[2], b[4];
        #pragma unroll
        for (int r = 0; r < 2; r++)
            a[r] = *reinterpret_cast<const bf16x8*>(&As[sw32(wr + r * 16 + m16, quad)]);
        #pragma unroll
        for (int c = 0; c < 4; c++)
            b[c] = *reinterpret_cast<const bf16x8*>(&Bs[sw32(wc + c * 16 + m16, quad)]);
        #pragma unroll
        for (int r = 0; r < 2; r++)
            #pragma unroll
            for (int c = 0; c < 4; c++)
                acc[r][c] = __builtin_amdgcn_mfma_f32_16x16x32_bf16(a[r], b[c], acc[r][c], 0, 0, 0);
    }

    #pragma unroll
    for (int r = 0; r < 2; r++){
        #pragma unroll
        for (int reg = 0; reg < 4; reg++){
            int row = wr + r * 16 + quad * 4 + reg;
            if (rowStart + row < rowEnd){
                int node = nodeIdx[row];
                #pragma unroll
                for (int c = 0; c < 4; c++){
                    int gc = c0 + wc + c * 16 + m16;
                    float v = acc[r][c][reg] + ldf(bias, t * 256 + gc, fb);
                    outb[node * 256 + gc] = f2us(v);
                }
            }
        }
    }
}

// ---- MFMA typed GEMM: output projection + skip gate (fp32 out) ----
__global__ __launch_bounds__(256) void k_gemm_out(
    const unsigned short* __restrict__ A,
    const void* __restrict__ Xv,
    const int* __restrict__ perm, const int* __restrict__ meta,
    const unsigned short* __restrict__ WTa,
    const void* __restrict__ ba, const void* __restrict__ skipv,
    float* __restrict__ out)
{
    int rt = blockIdx.x;
    if (rt >= meta[12]) return;
    int fx = meta[30], fba = meta[38], fsk = meta[42];
    int t = 0;
    while (t < TT - 1 && rt >= meta[8 + t + 1]) t++;
    int lt = rt - meta[8 + t];
    int rowStart = meta[4 + t] + (lt << 6);
    int rowEnd   = meta[4 + t] + meta[t];
    int c0 = blockIdx.y * 128;
    const unsigned short* Wm = WTa + (t << 16);
    float sg = ldf(skipv, t, fsk);
    float ag = 1.f / (1.f + __expf(-sg));

    __shared__ __align__(16) unsigned short As[64 * 32];
    __shared__ __align__(16) unsigned short Bs[128 * 32];
    __shared__ int nodeIdx[64];

    int tid = threadIdx.x;
    if (tid < 64){
        int p = rowStart + tid;
        nodeIdx[tid] = perm[(p < rowEnd) ? p : (rowEnd - 1)];
    }
    __syncthreads();

    int wave = tid >> 6, lane = tid & 63;
    int wr = (wave >> 1) * 32;
    int wc = (wave & 1) * 64;
    int m16 = lane & 15, quad = lane >> 4;

    int arow = tid & 63, aseg = tid >> 6;
    int anode = nodeIdx[arow];
    const unsigned short* aptr = A + anode * 256 + aseg * 8;

    floatx4 acc[2][4] = {};

    for (int k0 = 0; k0 < 256; k0 += 32){
        __syncthreads();
        uint4 av = *reinterpret_cast<const uint4*>(aptr + k0);
        *reinterpret_cast<uint4*>(&As[sw32(arow, aseg)]) = av;
        #pragma unroll
        for (int it = 0; it < 2; it++){
            int idx2 = tid + it * 256;
            int cc = idx2 >> 2, g = idx2 & 3;
            uint4 bv4 = *reinterpret_cast<const uint4*>(Wm + (c0 + cc) * 256 + k0 + g * 8);
            *reinterpret_cast<uint4*>(&Bs[sw32(cc, g)]) = bv4;
        }
        __syncthreads();
        bf16x8 a[2], b[4];
        #pragma unroll
        for (int r = 0; r < 2; r++)
            a[r] = *reinterpret_cast<const bf16x8*>(&As[sw32(wr + r * 16 + m16, quad)]);
        #pragma unroll
        for (int c = 0; c < 4; c++)
            b[c] = *reinterpret_cast<const bf16x8*>(&Bs[sw32(wc + c * 16 + m16, quad)]);
        #pragma unroll
        for (int r = 0; r < 2; r++)
            #pragma unroll
            for (int c = 0; c < 4; c++)
                acc[r][c] = __builtin_amdgcn_mfma_f32_16x16x32_bf16(a[r], b[c], acc[r][c], 0, 0, 0);
    }

    #pragma unroll
    for (int r = 0; r < 2; r++){
        #pragma unroll
        for (int reg = 0; reg < 4; reg++){
            int row = wr + r * 16 + quad * 4 + reg;
            if (rowStart + row < rowEnd){
                int node = nodeIdx[row];
                #pragma unroll
                for (int c = 0; c < 4; c++){
                    int gc = c0 + wc + c * 16 + m16;
                    float v = acc[r][c][reg] + ldf(ba, t * 256 + gc, fba);
                    float xv = ldf(Xv, node * 256 + gc, fx);
                    out[node * 256 + gc] = v * ag + xv * (1.f - ag);
                }
            }
        }
    }
}

// ---- VALU fallback projections (validated r7) ----
__global__ __launch_bounds__(256) void k_proj(
    const void* __restrict__ X, const int* __restrict__ nt,
    const void* __restrict__ Wk, const void* __restrict__ Wq, const void* __restrict__ Wv,
    const void* __restrict__ bk, const void* __restrict__ bq, const void* __restrict__ bv,
    unsigned short* __restrict__ kb, unsigned short* __restrict__ qtb,
    unsigned short* __restrict__ vb,
    const int* __restrict__ meta, int n)
{
    int i = blockIdx.x, tid = threadIdx.x;
    int fx = meta[30];
    int t = nt[i] & 3;
    __shared__ float xs[256];
    __shared__ float red[3][4][256];
    xs[tid] = ldf(X, i * 256 + tid, fx);
    __syncthreads();
    int seg = tid >> 6;
    int cg  = (tid & 63) * 4;
    int base = t * 65536 + cg;
    #pragma unroll
    for (int m = 0; m < 3; m++){
        const void* W = (m == 0) ? Wk : (m == 1) ? Wq : Wv;
        int fw = meta[31 + m];
        float ax = 0.f, ay = 0.f, az = 0.f, aw = 0.f;
        for (int k = seg * 64; k < seg * 64 + 64; k++){
            float xv = xs[k];
            float4 w = ldf4(W, base + k * 256, fw);
            ax += xv * w.x; ay += xv * w.y; az += xv * w.z; aw += xv * w.w;
        }
        float4 st = {ax, ay, az, aw};
        *reinterpret_cast<float4*>(&red[m][seg][cg]) = st;
    }
    __syncthreads();
    #pragma unroll
    for (int m = 0; m < 3; m++){
        const void* B = (m == 0) ? bk : (m == 1) ? bq : bv;
        unsigned short* O = (m == 0) ? kb : (m == 1) ? qtb : vb;
        float v = red[m][0][tid] + red[m][1][tid] + red[m][2][tid] + red[m][3][tid]
                + ldf(B, t * 256 + tid, meta[35 + m]);
        O[i * 256 + tid] = f2us(v);
    }
}
__global__ __launch_bounds__(256) void k_out(
    const unsigned short* __restrict__ tb,
    const void* __restrict__ X, const int* __restrict__ nt,
    const void* __restrict__ Wa, const void* __restrict__ ba,
    const void* __restrict__ skipv,
    float* __restrict__ out,
    const int* __restrict__ meta, int n)
{
    int i = blockIdx.x, tid = threadIdx.x;
    int fx = meta[30], fwa = meta[34], fba = meta[38], fsk = meta[42];
    int t = nt[i] & 3;
    __shared__ float xs[256];
    __shared__ float red[4][256];
    xs[tid] = us2f(tb[i * 256 + tid]);
    __syncthreads();
    int seg = tid >> 6;
    int cg  = (tid & 63) * 4;
    int base = t * 65536 + cg;
    float ax = 0.f, ay = 0.f, az = 0.f, aw = 0.f;
    for (int k = seg * 64; k < seg * 64 + 64; k++){
        float xv = xs[k];
        float4 w = ldf4(Wa, base + k * 256, fwa);
        ax += xv * w.x; ay += xv * w.y; az += xv * w.z; aw += xv * w.w;
    }
    float4 st = {ax, ay, az, aw};
    *reinterpret_cast<float4*>(&red[seg][cg]) = st;
    __syncthreads();
    float v = red[0][tid] + red[1][tid] + red[2][tid] + red[3][tid]
            + ldf(ba, t * 256 + tid, fba);
    float sg = ldf(skipv, t, fsk);
    float a  = 1.f / (1.f + __expf(-sg));
    float xv = ldf(X, i * 256 + tid, fx);
    out[i * 256 + tid] = v * a + xv * (1.f - a);
}

// ---- node attention + messages (fallback path, validated) ----
__global__ __launch_bounds__(256) void k_node2(
    unsigned short* qtb,
    const unsigned short* __restrict__ kb, const unsigned short* __restrict__ vb,
    const int* p2, const int* p3, const int* p4,
    const int* __restrict__ rowp, const int* __restrict__ eix,
    const void* __restrict__ rel_att, const void* __restrict__ rel_msg,
    const void* __restrict__ rel_pri,
    const int* __restrict__ meta, int n)
{
    const int* srcv = sel3(p2, p3, p4, meta[25]);
    const int* etv  = sel3(p2, p3, p4, meta[27]);
    int fra = meta[39], frm = meta[40], fpri = meta[41];
    int i = blockIdx.x, tid = threadIdx.x;
    int h5 = tid >> 5, z = tid & 31;

    __shared__ float qs[256];
    __shared__ float qA[RR * NH * 33];
    __shared__ float msum[RR][256];
    __shared__ float attS[16][NH];
    __shared__ float wnew[16][NH];
    __shared__ float mcur[RR][NH], dcur[RR][NH], scf[RR][NH];
    __shared__ int s_src[16], s_et[16];
    __shared__ float s_pri[RR * NH];
    __shared__ int s_mask;

    int e0 = rowp[i], deg = rowp[i + 1] - e0;

    if (tid < RR * NH) s_pri[tid] = ldf(rel_pri, tid, fpri);
    if (tid == 0) s_mask = 0;
    qs[tid] = us2f(qtb[i * 256 + tid]);
    #pragma unroll
    for (int r = 0; r < RR; r++) msum[r][tid] = 0.f;
    if (tid < RR * NH){ mcur[tid >> 3][tid & 7] = -1e30f; dcur[tid >> 3][tid & 7] = 0.f; }
    __syncthreads();

    {
        const float* qq = &qs[h5 * 32];
        #pragma unroll
        for (int r = 0; r < RR; r++){
            int base = (r * NH + h5) * 1024 + z * 32;
            float a0 = 0.f;
            #pragma unroll
            for (int e4 = 0; e4 < 8; e4++){
                float4 w = ldf4(rel_att, base + e4 * 4, fra);
                const float* q4 = qq + e4 * 4;
                a0 += w.x * q4[0] + w.y * q4[1] + w.z * q4[2] + w.w * q4[3];
            }
            qA[(r * NH + h5) * 33 + z] = a0;
        }
    }
    __syncthreads();

    for (int done = 0; done < deg; done += 16){
        int cs = min(16, deg - done);
        if (tid < cs){
            int e = eix[e0 + done + tid];
            int sj = srcv[e]; sj = (sj < 0) ? 0 : (sj >= n) ? n - 1 : sj;
            s_src[tid] = sj;
            int rr = etv[e] & 7;
            s_et[tid] = rr;
            atomicOr(&s_mask, 1 << rr);
        }
        __syncthreads();
        {
            int j = tid >> 4, hh = (tid >> 1) & 7, half = tid & 1;
            float pt = 0.f;
            if (j < cs){
                int sj = s_src[j], rj = s_et[j];
                const unsigned short* kp = kb + sj * 256 + hh * 32 + half * 16;
                const float* qa = &qA[(rj * NH + hh) * 33 + half * 16];
                uint4 u0 = *reinterpret_cast<const uint4*>(kp);
                uint4 u1 = *reinterpret_cast<const uint4*>(kp + 8);
                pt = lo2f(u0.x) * qa[0]  + hi2f(u0.x) * qa[1]
                   + lo2f(u0.y) * qa[2]  + hi2f(u0.y) * qa[3]
                   + lo2f(u0.z) * qa[4]  + hi2f(u0.z) * qa[5]
                   + lo2f(u0.w) * qa[6]  + hi2f(u0.w) * qa[7]
                   + lo2f(u1.x) * qa[8]  + hi2f(u1.x) * qa[9]
                   + lo2f(u1.y) * qa[10] + hi2f(u1.y) * qa[11]
                   + lo2f(u1.z) * qa[12] + hi2f(u1.z) * qa[13]
                   + lo2f(u1.w) * qa[14] + hi2f(u1.w) * qa[15];
            }
            pt += __shfl_xor(pt, 1);
            if (j < cs && half == 0)
                attS[j][hh] = pt * s_pri[s_et[j] * NH + hh] * 0.17677669529663687f;
        }
        __syncthreads();
        if (tid < RR * NH){
            int r = tid >> 3, hh = tid & 7;
            float m_old = mcur[r][hh];
            float m_new = m_old;
            for (int j = 0; j < cs; j++) if (s_et[j] == r) m_new = fmaxf(m_new, attS[j][hh]);
            float scale = __expf(m_old - m_new);
            float den = dcur[r][hh] * scale;
            for (int j = 0; j < cs; j++) if (s_et[j] == r) den += __expf(attS[j][hh] - m_new);
            mcur[r][hh] = m_new; dcur[r][hh] = den; scf[r][hh] = scale;
        }
        __syncthreads();
        #pragma unroll
        for (int r = 0; r < RR; r++) msum[r][tid] *= scf[r][h5];
        if (tid < cs * NH){
            int j = tid >> 3, hh = tid & 7;
            wnew[j][hh] = __expf(attS[j][hh] - mcur[s_et[j]][hh]);
        }
        __syncthreads();
        {
            float vvf[16];
            #pragma unroll
            for (int j = 0; j < 16; j++)
                if (j < cs) vvf[j] = us2f(vb[s_src[j] * 256 + tid]);
            for (int j = 0; j < cs; j++)
                msum[s_et[j]][tid] += wnew[j][h5] * vvf[j];
        }
        __syncthreads();
    }

    int mask = s_mask;
    #pragma unroll
    for (int r = 0; r < RR; r++){
        if ((mask >> r) & 1) msum[r][tid] /= dcur[r][h5];
    }
    __syncthreads();

    float tacc = 0.f;
    for (int r = 0; r < RR; r++){
        if (!((mask >> r) & 1)) continue;
        const float* ms = &msum[r][h5 * 32];
        int base = (r * NH + h5) * 1024 + z;
        float a0 = 0.f;
        #pragma unroll
        for (int c = 0; c < 32; c++)
            a0 += ms[c] * ldf(rel_msg, base + c * 32, frm);
        tacc += a0;
    }
    int np = __popc(mask); if (np == 0) np = 1;
    qtb[i * 256 + tid] = f2us(tacc / (float)np);
}

// ---- node attention + messages using precomputed qt (f32) and v_r (bf16):
//      no rel-table reads, register message accumulators ----
__global__ __launch_bounds__(256) void k_node3(
    unsigned short* qtb,
    const unsigned short* __restrict__ kb,
    const unsigned short* __restrict__ vr,
    const float* __restrict__ qt,
    const int* p2, const int* p3, const int* p4,
    const int* __restrict__ rowp, const int* __restrict__ eix,
    const void* __restrict__ rel_pri,
    const int* __restrict__ meta, int n)
{
    const int* srcv = sel3(p2, p3, p4, meta[25]);
    const int* etv  = sel3(p2, p3, p4, meta[27]);
    int fpri = meta[41];
    int i = blockIdx.x, tid = threadIdx.x;
    int h5 = tid >> 5;

    __shared__ float qA[RR * NH * 33];
    __shared__ float attS[16][NH];
    __shared__ float wnew[16][NH];
    __shared__ float mcur[RR][NH], dcur[RR][NH], scf[RR][NH];
    __shared__ int s_src[16], s_et[16];
    __shared__ float s_pri[RR * NH];
    __shared__ int s_mask;

    int e0 = rowp[i], deg = rowp[i + 1] - e0;

    if (tid < RR * NH) s_pri[tid] = ldf(rel_pri, tid, fpri);
    if (tid == 0) s_mask = 0;
    // stage this node's qt row (8 KB) into LDS with the bank-safe [r][h][33] layout
    {
        const float4* qp = reinterpret_cast<const float4*>(qt + (size_t)i * 2048);
        #pragma unroll
        for (int c = 0; c < 2; c++){
            int G = c * 256 + tid;          // float4 index 0..511 (coalesced)
            int r = G >> 6, g4 = G & 63;
            float4 v = qp[G];
            int h = g4 >> 3, dd = (g4 & 7) * 4;
            float* dst = &qA[(r * NH + h) * 33 + dd];
            dst[0] = v.x; dst[1] = v.y; dst[2] = v.z; dst[3] = v.w;
        }
    }
    float racc[RR];
    #pragma unroll
    for (int r = 0; r < RR; r++) racc[r] = 0.f;
    if (tid < RR * NH){ mcur[tid >> 3][tid & 7] = -1e30f; dcur[tid >> 3][tid & 7] = 0.f; }
    __syncthreads();

    for (int done = 0; done < deg; done += 16){
        int cs = min(16, deg - done);
        if (tid < cs){
            int e = eix[e0 + done + tid];
            int sj = srcv[e]; sj = (sj < 0) ? 0 : (sj >= n) ? n - 1 : sj;
            s_src[tid] = sj;
            int rr = etv[e] & 7;
            s_et[tid] = rr;
            atomicOr(&s_mask, 1 << rr);
        }
        __syncthreads();
        // issue v_r gathers early: latency hides under dots + softmax (T14)
        float vvf[16];
        #pragma unroll
        for (int j = 0; j < 16; j++){
            vvf[j] = (j < cs)
                ? us2f(vr[(size_t)s_src[j] * 2048 + (size_t)s_et[j] * 256 + tid])
                : 0.f;
        }
        // attention dots: (j, h, half) parallel across 256 threads
        {
            int j = tid >> 4, hh = (tid >> 1) & 7, half = tid & 1;
            float pt = 0.f;
            if (j < cs){
                int sj = s_src[j], rj = s_et[j];
                const unsigned short* kp = kb + sj * 256 + hh * 32 + half * 16;
                const float* qa = &qA[(rj * NH + hh) * 33 + half * 16];
                uint4 u0 = *reinterpret_cast<const uint4*>(kp);
                uint4 u1 = *reinterpret_cast<const uint4*>(kp + 8);
                pt = lo2f(u0.x) * qa[0]  + hi2f(u0.x) * qa[1]
                   + lo2f(u0.y) * qa[2]  + hi2f(u0.y) * qa[3]
                   + lo2f(u0.z) * qa[4]  + hi2f(u0.z) * qa[5]
                   + lo2f(u0.w) * qa[6]  + hi2f(u0.w) * qa[7]
                   + lo2f(u1.x) * qa[8]  + hi2f(u1.x) * qa[9]
                   + lo2f(u1.y) * qa[10] + hi2f(u1.y) * qa[11]
                   + lo2f(u1.z) * qa[12] + hi2f(u1.z) * qa[13]
                   + lo2f(u1.w) * qa[14] + hi2f(u1.w) * qa[15];
            }
            pt += __shfl_xor(pt, 1);
            if (j < cs && half == 0)
                attS[j][hh] = pt * s_pri[s_et[j] * NH + hh] * 0.17677669529663687f;
        }
        __syncthreads();
        if (tid < RR * NH){
            int r = tid >> 3, hh = tid & 7;
            float m_old = mcur[r][hh];
            float m_new = m_old;
            for (int j = 0; j < cs; j++) if (s_et[j] == r) m_new = fmaxf(m_new, attS[j][hh]);
            float scale = __expf(m_old - m_new);
            float den = dcur[r][hh] * scale;
            for (int j = 0; j < cs; j++) if (s_et[j] == r) den += __expf(attS[j][hh] - m_new);
            mcur[r][hh] = m_new; dcur[r][hh] = den; scf[r][hh] = scale;
        }
        __syncthreads();
        #pragma unroll
        for (int r = 0; r < RR; r++) racc[r] *= scf[r][h5];
        if (tid < cs * NH){
            int j = tid >> 3, hh = tid & 7;
            wnew[j][hh] = __expf(attS[j][hh] - mcur[s_et[j]][hh]);
        }
        __syncthreads();
        // register accumulation: branchless select over r (no LDS rmw chain)
        #pragma unroll
        for (int j = 0; j < 16; j++){
            if (j < cs){
                float w = wnew[j][h5] * vvf[j];
                int et = s_et[j];
                #pragma unroll
                for (int r = 0; r < RR; r++)
                    racc[r] += (et == r) ? w : 0.f;
            }
        }
        __syncthreads();
    }

    int mask = s_mask;
    float tacc = 0.f;
    #pragma unroll
    for (int r = 0; r < RR; r++)
        if ((mask >> r) & 1) tacc += racc[r] / dcur[r][h5];
    int np = __popc(mask); if (np == 0) np = 1;
    qtb[i * 256 + tid] = f2us(tacc / (float)np);
}

extern "C" void kernel_launch(void* const* d_in, const int* in_sizes, int n_in,
                              void* d_out, int out_size, void* d_ws, size_t ws_size,
                              hipStream_t stream)
{
    const void* x        = d_in[0];
    const int* node_type = (const int*)d_in[1];
    const int* p2        = (const int*)d_in[2];
    const int* p3        = (const int*)d_in[3];
    const int* p4        = (const int*)d_in[4];
    const void* Wk = d_in[5];  const void* bk = d_in[6];
    const void* Wq = d_in[7];  const void* bq = d_in[8];
    const void* Wv = d_in[9];  const void* bv = d_in[10];
    const void* Wa = d_in[11]; const void* ba = d_in[12];
    const void* rel_att = d_in[13];
    const void* rel_msg = d_in[14];
    const void* rel_pri = d_in[15];
    const void* skipv   = d_in[16];
    float* out = (float*)d_out;

    bool ok = (n_in == 17);
    if (ok){
        ok = ok && (in_sizes[0] == in_sizes[1] * 256);
        ok = ok && (in_sizes[2] == in_sizes[3]) && (in_sizes[3] == in_sizes[4]);
        ok = ok && (in_sizes[5] == 262144) && (in_sizes[7] == 262144)
                && (in_sizes[9] == 262144) && (in_sizes[11] == 262144);
        ok = ok && (in_sizes[6] == 1024) && (in_sizes[8] == 1024)
                && (in_sizes[10] == 1024) && (in_sizes[12] == 1024);
        ok = ok && (in_sizes[13] == 65536) && (in_sizes[14] == 65536);
        ok = ok && (in_sizes[15] == 64) && (in_sizes[16] == 4);
        ok = ok && (out_size == in_sizes[0]);
    }
    if (!ok){
        k_zerofill<<<(out_size + 255) / 256, 256, 0, stream>>>(out, out_size);
        return;
    }

    int n = in_sizes[1];
    int E = in_sizes[2];
    int nb = (n + 255) / 256;
    int eb = (E + 255) / 256;

    char* ws = (char*)d_ws;
    int* meta = (int*)ws;
    size_t off = 256;
    int* cnt  = (int*)(ws + off); off += ((size_t)n * 4 + 255) & ~(size_t)255;
    int* bsum = (int*)(ws + off); off += ((size_t)nb * 4 + 255) & ~(size_t)255;
    int* rowp = (int*)(ws + off); off += ((size_t)(n + 1) * 4 + 255) & ~(size_t)255;
    int* eix  = (int*)(ws + off); off += ((size_t)E * 4 + 255) & ~(size_t)255;
    unsigned short* kb2 = (unsigned short*)(ws + off); off += (size_t)n * 256 * 2;
    unsigned short* vb2 = (unsigned short*)(ws + off); off += (size_t)n * 256 * 2;
    unsigned short* qtb = (unsigned short*)(ws + off); off += (size_t)n * 256 * 2;
    size_t off_lean = off;
    int* perm = (int*)(ws + off); off += ((size_t)n * 4 + 255) & ~(size_t)255;
    unsigned short* WT = (unsigned short*)(ws + off); off += (size_t)16 * 65536 * 2;
    size_t off_full = off;
    // ---- new tier: rel-transform GEMM buffers ----
    unsigned short* RATh = (unsigned short*)(ws + off); off += (size_t)65536 * 2;
    unsigned short* RATl = (unsigned short*)(ws + off); off += (size_t)65536 * 2;
    unsigned short* RMTh = (unsigned short*)(ws + off); off += (size_t)65536 * 2;
    unsigned short* RMTl = (unsigned short*)(ws + off); off += (size_t)65536 * 2;
    float* qtf = (float*)(ws + off);          off += (size_t)n * 2048 * 4;
    unsigned short* vrb = (unsigned short*)(ws + off); off += (size_t)n * 2048 * 2;
    size_t off_new = off;

    k_flags<<<13, 256, 0, stream>>>(x, Wk, Wq, Wv, Wa, bk, bq, bv, ba,
                                    rel_att, rel_msg, rel_pri, skipv,
                                    in_sizes[0], in_sizes[5], in_sizes[7], in_sizes[9],
                                    in_sizes[11], in_sizes[6], in_sizes[8], in_sizes[10],
                                    in_sizes[12], in_sizes[13], in_sizes[14],
                                    in_sizes[15], in_sizes[16], meta);
    k_flagfix<<<1, 64, 0, stream>>>(meta);

    if (ws_size < off_lean){
        k_copy<<<(n * 256 + 255) / 256, 256, 0, stream>>>(x, out, meta, n * 256);
        return;
    }
    bool full  = (ws_size >= off_full);
    bool full2 = (ws_size >= off_new);

    k_trio<<<3, 256, 0, stream>>>(p2, p3, p4, E, n, meta);
    k_pick<<<1, 64, 0, stream>>>(meta);

    // CSR
    k_zero<<<nb, 256, 0, stream>>>(cnt, n);
    k_deg<<<eb, 256, 0, stream>>>(p2, p3, p4, cnt, meta, E, n);
    k_scan1<<<nb, 256, 0, stream>>>(cnt, rowp, bsum, n);
    k_scan2<<<1, 64, 0, stream>>>(bsum, rowp, nb, n);
    k_scan3<<<nb, 256, 0, stream>>>(rowp, bsum, n);
    k_zero<<<nb, 256, 0, stream>>>(cnt, n);
    k_escat<<<eb, 256, 0, stream>>>(p2, p3, p4, cnt, rowp, eix, meta, E, n);

    if (full){
        k_init<<<1, 64, 0, stream>>>(meta);
        k_count<<<nb, 256, 0, stream>>>(node_type, meta, n);
        k_prefix<<<1, 64, 0, stream>>>(meta);
        k_scatter<<<nb, 256, 0, stream>>>(node_type, meta, perm, n);
        k_transW<<<4096, 256, 0, stream>>>(Wk, Wq, Wv, Wa, WT, meta);
        int maxRT = n / 64 + TT;
        k_gemm_qkv<<<dim3(maxRT, 6), 256, 0, stream>>>(x, perm, meta, WT, bk, bq, bv,
                                                       kb2, qtb, vb2);
        if (full2){
            int nt64 = (n + 63) / 64;
            k_transR<<<256, 256, 0, stream>>>(rel_att, rel_msg, RATh, RATl, RMTh, RMTl, meta);
            k_rel<<<nt64, 256, 0, stream>>>(qtb, RATh, RATl, qtf, (unsigned short*)nullptr, n);
            k_rel<<<nt64, 256, 0, stream>>>(vb2, RMTh, RMTl, (float*)nullptr, vrb, n);
            k_node3<<<n, 256, 0, stream>>>(qtb, kb2, vrb, qtf, p2, p3, p4, rowp, eix,
                                           rel_pri, meta, n);
        } else {
            k_node2<<<n, 256, 0, stream>>>(qtb, kb2, vb2, p2, p3, p4, rowp, eix,
                                           rel_att, rel_msg, rel_pri, meta, n);
        }
        k_gemm_out<<<dim3(maxRT, 2), 256, 0, stream>>>(qtb, x, perm, meta,
                                                       WT + 12 * 65536, ba, skipv, out);
    } else {
        k_proj<<<n, 256, 0, stream>>>(x, node_type, Wk, Wq, Wv, bk, bq, bv,
                                      kb2, qtb, vb2, meta, n);
        k_node2<<<n, 256, 0, stream>>>(qtb, kb2, vb2, p2, p3, p4, rowp, eix,
                                       rel_att, rel_msg, rel_pri, meta, n);
        k_out<<<n, 256, 0, stream>>>(qtb, x, node_type, Wa, ba, skipv, out, meta, n);
    }
}

// Round 2
// 1453.516 us; speedup vs baseline: 1.9699x; 1.9699x over previous
//
#include <hip/hip_runtime.h>

#define TT 4
#define RR 8
#define NH 8
#define DKK 32

typedef float floatx4 __attribute__((ext_vector_type(4)));
typedef __bf16 bf16x8 __attribute__((ext_vector_type(8)));

__device__ __forceinline__ float us2f(unsigned short s){
    union{unsigned int u; float f;} x; x.u = ((unsigned int)s) << 16; return x.f;
}
__device__ __forceinline__ float lo2f(unsigned int u){
    union{unsigned int x; float f;} a; a.x = u << 16; return a.f;
}
__device__ __forceinline__ float hi2f(unsigned int u){
    union{unsigned int x; float f;} a; a.x = u & 0xffff0000u; return a.f;
}
__device__ __forceinline__ unsigned short f2us(float f){
    union{float f; unsigned int u;} x; x.f = f;
    unsigned int u = x.u;
    unsigned int r = (u + 0x7fffu + ((u >> 16) & 1u)) >> 16;   // RNE bf16
    return (unsigned short)r;
}
__device__ __forceinline__ float ldf(const void* p, int i, int isf32){
    return isf32 ? ((const float*)p)[i] : us2f(((const unsigned short*)p)[i]);
}
__device__ __forceinline__ float4 ldf4(const void* p, int i, int isf32){  // i % 4 == 0
    if (isf32) return *reinterpret_cast<const float4*>((const float*)p + i);
    uint2 u = *reinterpret_cast<const uint2*>((const unsigned short*)p + i);
    float4 r; r.x = lo2f(u.x); r.y = hi2f(u.x); r.z = lo2f(u.y); r.w = hi2f(u.y);
    return r;
}
__device__ __forceinline__ const int* sel3(const int* a, const int* b, const int* c, int s){
    return (s == 0) ? a : (s == 1) ? b : c;
}
__device__ __forceinline__ int sw32(int row, int g){
    return row * 32 + ((g ^ (row >> 2)) & 3) * 8;
}

// ---- per-array dtype flags: meta[30+id] = 0 bf16 / 1 fp32 / -1 unknown ----
__global__ void k_flags(const void* p0, const void* p1, const void* p2, const void* p3,
                        const void* p4, const void* p5, const void* p6, const void* p7,
                        const void* p8, const void* p9, const void* p10, const void* p11,
                        const void* p12,
                        int n0, int n1, int n2, int n3, int n4, int n5, int n6, int n7,
                        int n8, int n9, int n10, int n11, int n12,
                        int* __restrict__ meta)
{
    const void* ps[13] = {p0,p1,p2,p3,p4,p5,p6,p7,p8,p9,p10,p11,p12};
    int ns[13] = {n0,n1,n2,n3,n4,n5,n6,n7,n8,n9,n10,n11,n12};
    int id = blockIdx.x;
    const unsigned short* p = (const unsigned short*)ps[id];
    int half = ns[id] >> 1;
    int nsamp = (half < 256) ? half : 256;
    int step = (nsamp > 0) ? (half / nsamp) : 1;
    int tid = threadIdx.x;
    int sane = 0, nzv = 0;
    if (tid < nsamp){
        unsigned short u = p[2 * (tid * step)];
        nzv = (u != 0);
        int e = (u >> 7) & 0xFF;
        sane = (e >= 100 && e <= 140) ? 1 : 0;
    }
    __shared__ int c_s[4], c_n[4];
    unsigned long long ms = __ballot(sane != 0);
    unsigned long long mn = __ballot(nzv != 0);
    if ((tid & 63) == 0){ c_s[tid >> 6] = (int)__popcll(ms); c_n[tid >> 6] = (int)__popcll(mn); }
    __syncthreads();
    if (tid == 0){
        int cs = c_s[0] + c_s[1] + c_s[2] + c_s[3];
        int cn = c_n[0] + c_n[1] + c_n[2] + c_n[3];
        meta[30 + id] = (cn == 0) ? -1 : ((2 * cs >= nsamp) ? 0 : 1);
    }
}
__global__ void k_flagfix(int* meta){
    if (threadIdx.x == 0 && blockIdx.x == 0){
        int xf = meta[30]; if (xf < 0) xf = 1;
        meta[30] = xf; meta[24] = xf;
        for (int j = 1; j < 13; j++) if (meta[30 + j] < 0) meta[30 + j] = xf;
    }
}

// ---- identify src/dst/etype among the three E-sized int arrays ----
__global__ void k_trio(const int* pa, const int* pb, const int* pc, int E, int n,
                       int* __restrict__ meta){
    const int* ps[3] = {pa, pb, pc};
    int c = blockIdx.x, tid = threadIdx.x;
    const int* p = ps[c];
    int step = E / 1024; if (step < 1) step = 1;
    int mx = 0, hits = 0;
    for (int j = 0; j < 4; j++){
        long long e = (long long)(tid + j * 256) * step;
        if (e < E){
            int v = p[e];
            mx = max(mx, v);
            hits += (v == (int)(e % n)) ? 1 : 0;
        }
    }
    __shared__ int smx[4], sh[4];
    for (int o = 32; o; o >>= 1){ mx = max(mx, __shfl_down(mx, o, 64)); hits += __shfl_down(hits, o, 64); }
    if ((tid & 63) == 0){ smx[tid >> 6] = mx; sh[tid >> 6] = hits; }
    __syncthreads();
    if (tid == 0){
        mx = max(max(smx[0], smx[1]), max(smx[2], smx[3]));
        hits = sh[0] + sh[1] + sh[2] + sh[3];
        meta[44 + c] = mx; meta[47 + c] = hits;
    }
}
__global__ void k_pick(int* meta){
    if (threadIdx.x == 0 && blockIdx.x == 0){
        int m0 = meta[44], m1 = meta[45], m2 = meta[46];
        int h[3] = {meta[47], meta[48], meta[49]};
        int et = (m2 < 8) ? 2 : ((m0 < 8) ? 0 : ((m1 < 8) ? 1 : 2));
        int a = -1, b = -1;
        for (int c = 0; c < 3; c++) if (c != et){ if (a < 0) a = c; else b = c; }
        int srcsel = a, dstsel = b;
        if (h[a] >= 1000 && h[b] < 1000){ dstsel = a; srcsel = b; }
        meta[25] = srcsel; meta[26] = dstsel; meta[27] = et;
    }
}

// ---- fallbacks ----
__global__ void k_zerofill(float* out, int tot){
    int i = blockIdx.x * 256 + threadIdx.x;
    if (i < tot) out[i] = 0.f;
}
__global__ void k_copy(const void* __restrict__ xv, float* __restrict__ out,
                       const int* __restrict__ meta, int tot){
    int isf32 = meta[24];
    int i = blockIdx.x * 256 + threadIdx.x;
    if (i < tot) out[i] = ldf(xv, i, isf32);
}

// ---- bucket build (validated r3) ----
__global__ void k_init(int* meta){
    if (threadIdx.x < 24) meta[threadIdx.x] = 0;
}
__global__ void k_count(const int* __restrict__ nt, int* __restrict__ meta, int n){
    int i = blockIdx.x * 256 + threadIdx.x;
    int t = (i < n) ? (nt[i] & 3) : -1;
    int lane = threadIdx.x & 63;
    #pragma unroll
    for (int tt = 0; tt < TT; tt++){
        unsigned long long m = __ballot(t == tt);
        if (m){
            int leader = __builtin_ctzll(m);
            if (lane == leader) atomicAdd(&meta[tt], (int)__popcll(m));
        }
    }
}
__global__ void k_prefix(int* meta){
    if (threadIdx.x == 0){
        int off = 0, tb = 0;
        for (int t = 0; t < TT; t++){
            int c = meta[t];
            meta[4 + t]  = off;
            meta[13 + t] = off;
            meta[8 + t]  = tb;
            off += c;
            tb  += (c + 63) >> 6;
        }
        meta[12] = tb;
    }
}
__global__ void k_scatter(const int* __restrict__ nt, int* __restrict__ meta,
                          int* __restrict__ perm, int n){
    int i = blockIdx.x * 256 + threadIdx.x;
    int t = (i < n) ? (nt[i] & 3) : -1;
    int lane = threadIdx.x & 63;
    #pragma unroll
    for (int tt = 0; tt < TT; tt++){
        unsigned long long m = __ballot(t == tt);
        if (m){
            int leader = __builtin_ctzll(m);
            int base = 0;
            if (lane == leader) base = atomicAdd(&meta[13 + tt], (int)__popcll(m));
            base = __shfl(base, leader, 64);
            if (t == tt){
                int rank = __popcll(m & ((1ull << lane) - 1ull));
                perm[base + rank] = i;
            }
        }
    }
}

// ---- weight transpose: WT[m][outcol][k] = W[m][k][outcol] ----
__global__ void k_transW(const void* __restrict__ Wk, const void* __restrict__ Wq,
                         const void* __restrict__ Wv, const void* __restrict__ Wa,
                         unsigned short* __restrict__ WT, const int* __restrict__ meta)
{
    int idx = blockIdx.x * 256 + threadIdx.x;
    int m   = idx >> 16;
    int loc = idx & 65535;
    int j = loc >> 8, k = loc & 255;
    int mt = m >> 2, t = m & 3;
    const void* W = (mt == 0) ? Wk : (mt == 1) ? Wq : (mt == 2) ? Wv : Wa;
    int flag = meta[31 + mt];
    WT[idx] = f2us(ldf(W, t * 65536 + k * 256 + j, flag));
}

// ---- rel-table prep for MFMA path: hi/lo bf16 split; RMT transposed ----
// RAT[r][h][d][e] = rel_att[r][h][d][e]   (B layout [outcol=d][k=e])
// RMT[r][h][e][d] = rel_msg[r][h][d][e]   (B layout [outcol=e][k=d])
__global__ void k_transR(const void* __restrict__ rel_att, const void* __restrict__ rel_msg,
                         unsigned short* __restrict__ RATh, unsigned short* __restrict__ RATl,
                         unsigned short* __restrict__ RMTh, unsigned short* __restrict__ RMTl,
                         const int* __restrict__ meta)
{
    int idx = blockIdx.x * 256 + threadIdx.x;       // 0..65535
    int fra = meta[39], frm = meta[40];
    float wa = ldf(rel_att, idx, fra);
    unsigned short ha = f2us(wa);
    RATh[idx] = ha;
    RATl[idx] = f2us(wa - us2f(ha));
    int quad = idx >> 10, loc = idx & 1023, d = loc >> 5, e = loc & 31;
    float wm = ldf(rel_msg, quad * 1024 + d * 32 + e, frm);
    unsigned short hm = f2us(wm);
    int oidx = quad * 1024 + e * 32 + d;
    RMTh[oidx] = hm;
    RMTl[oidx] = f2us(wm - us2f(hm));
}

// ---- batched qt GEMM: qt[node-c0][r*256 + h*32 + d] =
//      sum_e q[node][h*32+e] * rel_att[r][h][d][e]  (hi/lo bf16 B, f32 out) ----
__global__ __launch_bounds__(256) void k_relq(
    const unsigned short* __restrict__ Ain,
    const unsigned short* __restrict__ Bhi, const unsigned short* __restrict__ Blo,
    float* __restrict__ outF, int c0, int cend)
{
    int base = c0 + blockIdx.x * 64;
    __shared__ __align__(16) unsigned short As[64 * 264];
    int tid = threadIdx.x;
    #pragma unroll
    for (int c = 0; c < 8; c++){
        int G = c * 256 + tid;            // granule of 8 halfs
        int row = G >> 5, g = G & 31;
        int node = base + row;
        uint4 v;
        if (node < cend) v = *reinterpret_cast<const uint4*>(Ain + (size_t)node * 256 + g * 8);
        else { v.x = v.y = v.z = v.w = 0u; }
        *reinterpret_cast<uint4*>(&As[row * 264 + g * 8]) = v;
    }
    __syncthreads();
    int wave = tid >> 6, lane = tid & 63;
    int m16 = lane & 15, quad = lane >> 4;
    int r0 = wave * 16;

    bf16x8 a[8];
    #pragma unroll
    for (int h = 0; h < 8; h++)
        a[h] = *reinterpret_cast<const bf16x8*>(&As[(r0 + m16) * 264 + h * 32 + quad * 8]);

    for (int r = 0; r < RR; r++){
        floatx4 acc[8][2] = {};
        #pragma unroll
        for (int h = 0; h < 8; h++){
            #pragma unroll
            for (int ct = 0; ct < 2; ct++){
                int bix = (((r * 8 + h) * 32) + ct * 16 + m16) * 32 + quad * 8;
                bf16x8 bh = *reinterpret_cast<const bf16x8*>(Bhi + bix);
                bf16x8 bl = *reinterpret_cast<const bf16x8*>(Blo + bix);
                acc[h][ct] = __builtin_amdgcn_mfma_f32_16x16x32_bf16(a[h], bh, acc[h][ct], 0, 0, 0);
                acc[h][ct] = __builtin_amdgcn_mfma_f32_16x16x32_bf16(a[h], bl, acc[h][ct], 0, 0, 0);
            }
        }
        #pragma unroll
        for (int h = 0; h < 8; h++){
            #pragma unroll
            for (int ct = 0; ct < 2; ct++){
                #pragma unroll
                for (int reg = 0; reg < 4; reg++){
                    int row = r0 + quad * 4 + reg;
                    int node = base + row;
                    if (node < cend){
                        int col = r * 256 + h * 32 + ct * 16 + m16;
                        outF[(size_t)(node - c0) * 2048 + col] = acc[h][ct][reg];
                    }
                }
            }
        }
    }
}

// ---- batched rel_msg GEMM: t[node][h*32+e] = sum_{r,d} M[node][r,h*32+d]*rel_msg[r,h,d,e]
//      M stored as hi/lo bf16 planes inside the chunk row (written by k_node4) ----
__global__ __launch_bounds__(256) void k_relmsg(
    const float* __restrict__ Mv,
    const unsigned short* __restrict__ Bhi, const unsigned short* __restrict__ Blo,
    unsigned short* __restrict__ outT, int c0, int cend)
{
    int base = c0 + blockIdx.x * 64;
    __shared__ __align__(16) unsigned short Ahi[64 * 264];
    __shared__ __align__(16) unsigned short Alo[64 * 264];
    int tid = threadIdx.x;
    int wave = tid >> 6, lane = tid & 63;
    int m16 = lane & 15, quad = lane >> 4;
    int r0 = wave * 16;

    floatx4 acc[8][2] = {};

    for (int r = 0; r < RR; r++){
        __syncthreads();
        #pragma unroll
        for (int it = 0; it < 8; it++){
            int G = it * 256 + tid;       // granule of 8 halfs: 64 rows x 32 granules
            int row = G >> 5, g = G & 31;
            int node = base + row;
            uint4 vh, vl;
            vh.x = vh.y = vh.z = vh.w = 0u;
            vl = vh;
            if (node < cend){
                const unsigned short* Mrow =
                    (const unsigned short*)((const char*)Mv + (size_t)(node - c0) * 8192);
                vh = *reinterpret_cast<const uint4*>(Mrow + r * 256 + g * 8);
                vl = *reinterpret_cast<const uint4*>(Mrow + 2048 + r * 256 + g * 8);
            }
            *reinterpret_cast<uint4*>(&Ahi[row * 264 + g * 8]) = vh;
            *reinterpret_cast<uint4*>(&Alo[row * 264 + g * 8]) = vl;
        }
        __syncthreads();
        #pragma unroll
        for (int h = 0; h < 8; h++){
            bf16x8 ah = *reinterpret_cast<const bf16x8*>(&Ahi[(r0 + m16) * 264 + h * 32 + quad * 8]);
            bf16x8 al = *reinterpret_cast<const bf16x8*>(&Alo[(r0 + m16) * 264 + h * 32 + quad * 8]);
            #pragma unroll
            for (int ct = 0; ct < 2; ct++){
                int bix = (((r * 8 + h) * 32) + ct * 16 + m16) * 32 + quad * 8;
                bf16x8 bh = *reinterpret_cast<const bf16x8*>(Bhi + bix);
                bf16x8 bl = *reinterpret_cast<const bf16x8*>(Blo + bix);
                acc[h][ct] = __builtin_amdgcn_mfma_f32_16x16x32_bf16(ah, bh, acc[h][ct], 0, 0, 0);
                acc[h][ct] = __builtin_amdgcn_mfma_f32_16x16x32_bf16(al, bh, acc[h][ct], 0, 0, 0);
                acc[h][ct] = __builtin_amdgcn_mfma_f32_16x16x32_bf16(ah, bl, acc[h][ct], 0, 0, 0);
            }
        }
    }
    #pragma unroll
    for (int h = 0; h < 8; h++){
        #pragma unroll
        for (int ct = 0; ct < 2; ct++){
            #pragma unroll
            for (int reg = 0; reg < 4; reg++){
                int row = r0 + quad * 4 + reg;
                int node = base + row;
                if (node < cend)
                    outT[(size_t)node * 256 + h * 32 + ct * 16 + m16] = f2us(acc[h][ct][reg]);
            }
        }
    }
}

// ---- CSR build ----
__global__ void k_zero(int* a, int n){
    int i = blockIdx.x * 256 + threadIdx.x;
    if (i < n) a[i] = 0;
}
__global__ void k_deg(const int* p2, const int* p3, const int* p4,
                      int* __restrict__ cnt, const int* __restrict__ meta, int E, int n){
    const int* dst = sel3(p2, p3, p4, meta[26]);
    int e = blockIdx.x * 256 + threadIdx.x;
    if (e < E){
        int d = dst[e];
        if (d >= 0 && d < n) atomicAdd(&cnt[d], 1);
    }
}
__global__ void k_scan1(const int* __restrict__ cnt, int* __restrict__ rowp,
                        int* __restrict__ bsum, int n){
    __shared__ int s[256];
    int b = blockIdx.x, tid = threadIdx.x;
    int i = b * 256 + tid;
    int v = (i < n) ? cnt[i] : 0;
    s[tid] = v;
    __syncthreads();
    for (int d = 1; d < 256; d <<= 1){
        int add = (tid >= d) ? s[tid - d] : 0;
        __syncthreads();
        s[tid] += add;
        __syncthreads();
    }
    if (i < n) rowp[i] = s[tid] - v;
    if (tid == 255) bsum[b] = s[255];
}
__global__ void k_scan2(int* bsum, int* rowp, int nb, int n){
    if (threadIdx.x == 0){
        int run = 0;
        for (int b = 0; b < nb; b++){ int t = bsum[b]; bsum[b] = run; run += t; }
        rowp[n] = run;
    }
}
__global__ void k_scan3(int* rowp, const int* __restrict__ bsum, int n){
    int i = blockIdx.x * 256 + threadIdx.x;
    if (i < n) rowp[i] += bsum[i >> 8];
}
__global__ void k_escat(const int* p2, const int* p3, const int* p4,
                        int* __restrict__ cur, const int* __restrict__ rowp,
                        int* __restrict__ eix, const int* __restrict__ meta, int E, int n){
    const int* dst = sel3(p2, p3, p4, meta[26]);
    int e = blockIdx.x * 256 + threadIdx.x;
    if (e < E){
        int d = dst[e];
        if (d >= 0 && d < n){
            int pos = atomicAdd(&cur[d], 1);
            eix[rowp[d] + pos] = e;
        }
    }
}

// ---- MFMA typed GEMM: QKV (validated r3, fp32-in adapted) ----
__global__ __launch_bounds__(256) void k_gemm_qkv(
    const void* __restrict__ Xv,
    const int* __restrict__ perm, const int* __restrict__ meta,
    const unsigned short* __restrict__ WT,
    const void* __restrict__ bk, const void* __restrict__ bq, const void* __restrict__ bv,
    unsigned short* __restrict__ kb, unsigned short* __restrict__ qb,
    unsigned short* __restrict__ vb)
{
    int rt = blockIdx.x;
    if (rt >= meta[12]) return;
    int fx = meta[30];
    int t = 0;
    while (t < TT - 1 && rt >= meta[8 + t + 1]) t++;
    int lt = rt - meta[8 + t];
    int rowStart = meta[4 + t] + (lt << 6);
    int rowEnd   = meta[4 + t] + meta[t];

    int ct = blockIdx.y;          // 0..5
    int mt = ct >> 1;             // 0=k 1=q 2=v
    int c0 = (ct & 1) * 128;
    const unsigned short* Wm = WT + (((mt << 2) + t) << 16);
    const void* bias = (mt == 0) ? bk : (mt == 1) ? bq : bv;
    int fb = meta[35 + mt];
    unsigned short* outb = (mt == 0) ? kb : (mt == 1) ? qb : vb;

    __shared__ __align__(16) unsigned short As[64 * 32];
    __shared__ __align__(16) unsigned short Bs[128 * 32];
    __shared__ int nodeIdx[64];

    int tid = threadIdx.x;
    if (tid < 64){
        int p = rowStart + tid;
        nodeIdx[tid] = perm[(p < rowEnd) ? p : (rowEnd - 1)];
    }
    __syncthreads();

    int wave = tid >> 6, lane = tid & 63;
    int wr = (wave >> 1) * 32;
    int wc = (wave & 1) * 64;
    int m16 = lane & 15, quad = lane >> 4;

    int arow = tid & 63, aseg = tid >> 6;
    int anode = nodeIdx[arow];

    floatx4 acc[2][4] = {};

    for (int k0 = 0; k0 < 256; k0 += 32){
        __syncthreads();
        uint4 av;
        if (fx){
            const float* af = (const float*)Xv + anode * 256 + aseg * 8 + k0;
            float4 f0 = *reinterpret_cast<const float4*>(af);
            float4 f1 = *reinterpret_cast<const float4*>(af + 4);
            av.x = (unsigned)f2us(f0.x) | ((unsigned)f2us(f0.y) << 16);
            av.y = (unsigned)f2us(f0.z) | ((unsigned)f2us(f0.w) << 16);
            av.z = (unsigned)f2us(f1.x) | ((unsigned)f2us(f1.y) << 16);
            av.w = (unsigned)f2us(f1.z) | ((unsigned)f2us(f1.w) << 16);
        } else {
            av = *reinterpret_cast<const uint4*>((const unsigned short*)Xv + anode * 256 + aseg * 8 + k0);
        }
        *reinterpret_cast<uint4*>(&As[sw32(arow, aseg)]) = av;
        #pragma unroll
        for (int it = 0; it < 2; it++){
            int idx2 = tid + it * 256;
            int cc = idx2 >> 2, g = idx2 & 3;
            uint4 bv4 = *reinterpret_cast<const uint4*>(Wm + (c0 + cc) * 256 + k0 + g * 8);
            *reinterpret_cast<uint4*>(&Bs[sw32(cc, g)]) = bv4;
        }
        __syncthreads();
        bf16x8 a[2], b[4];
        #pragma unroll
        for (int r = 0; r < 2; r++)
            a[r] = *reinterpret_cast<const bf16x8*>(&As[sw32(wr + r * 16 + m16, quad)]);
        #pragma unroll
        for (int c = 0; c < 4; c++)
            b[c] = *reinterpret_cast<const bf16x8*>(&Bs[sw32(wc + c * 16 + m16, quad)]);
        #pragma unroll
        for (int r = 0; r < 2; r++)
            #pragma unroll
            for (int c = 0; c < 4; c++)
                acc[r][c] = __builtin_amdgcn_mfma_f32_16x16x32_bf16(a[r], b[c], acc[r][c], 0, 0, 0);
    }

    #pragma unroll
    for (int r = 0; r < 2; r++){
        #pragma unroll
        for (int reg = 0; reg < 4; reg++){
            int row = wr + r * 16 + quad * 4 + reg;
            if (rowStart + row < rowEnd){
                int node = nodeIdx[row];
                #pragma unroll
                for (int c = 0; c < 4; c++){
                    int gc = c0 + wc + c * 16 + m16;
                    float v = acc[r][c][reg] + ldf(bias, t * 256 + gc, fb);
                    outb[node * 256 + gc] = f2us(v);
                }
            }
        }
    }
}

// ---- MFMA typed GEMM: output projection + skip gate (fp32 out) ----
__global__ __launch_bounds__(256) void k_gemm_out(
    const unsigned short* __restrict__ A,
    const void* __restrict__ Xv,
    const int* __restrict__ perm, const int* __restrict__ meta,
    const unsigned short* __restrict__ WTa,
    const void* __restrict__ ba, const void* __restrict__ skipv,
    float* __restrict__ out)
{
    int rt = blockIdx.x;
    if (rt >= meta[12]) return;
    int fx = meta[30], fba = meta[38], fsk = meta[42];
    int t = 0;
    while (t < TT - 1 && rt >= meta[8 + t + 1]) t++;
    int lt = rt - meta[8 + t];
    int rowStart = meta[4 + t] + (lt << 6);
    int rowEnd   = meta[4 + t] + meta[t];
    int c0 = blockIdx.y * 128;
    const unsigned short* Wm = WTa + (t << 16);
    float sg = ldf(skipv, t, fsk);
    float ag = 1.f / (1.f + __expf(-sg));

    __shared__ __align__(16) unsigned short As[64 * 32];
    __shared__ __align__(16) unsigned short Bs[128 * 32];
    __shared__ int nodeIdx[64];

    int tid = threadIdx.x;
    if (tid < 64){
        int p = rowStart + tid;
        nodeIdx[tid] = perm[(p < rowEnd) ? p : (rowEnd - 1)];
    }
    __syncthreads();

    int wave = tid >> 6, lane = tid & 63;
    int wr = (wave >> 1) * 32;
    int wc = (wave & 1) * 64;
    int m16 = lane & 15, quad = lane >> 4;

    int arow = tid & 63, aseg = tid >> 6;
    int anode = nodeIdx[arow];
    const unsigned short* aptr = A + anode * 256 + aseg * 8;

    floatx4 acc[2][4] = {};

    for (int k0 = 0; k0 < 256; k0 += 32){
        __syncthreads();
        uint4 av = *reinterpret_cast<const uint4*>(aptr + k0);
        *reinterpret_cast<uint4*>(&As[sw32(arow, aseg)]) = av;
        #pragma unroll
        for (int it = 0; it < 2; it++){
            int idx2 = tid + it * 256;
            int cc = idx2 >> 2, g = idx2 & 3;
            uint4 bv4 = *reinterpret_cast<const uint4*>(Wm + (c0 + cc) * 256 + k0 + g * 8);
            *reinterpret_cast<uint4*>(&Bs[sw32(cc, g)]) = bv4;
        }
        __syncthreads();
        bf16x8 a[2], b[4];
        #pragma unroll
        for (int r = 0; r < 2; r++)
            a[r] = *reinterpret_cast<const bf16x8*>(&As[sw32(wr + r * 16 + m16, quad)]);
        #pragma unroll
        for (int c = 0; c < 4; c++)
            b[c] = *reinterpret_cast<const bf16x8*>(&Bs[sw32(wc + c * 16 + m16, quad)]);
        #pragma unroll
        for (int r = 0; r < 2; r++)
            #pragma unroll
            for (int c = 0; c < 4; c++)
                acc[r][c] = __builtin_amdgcn_mfma_f32_16x16x32_bf16(a[r], b[c], acc[r][c], 0, 0, 0);
    }

    #pragma unroll
    for (int r = 0; r < 2; r++){
        #pragma unroll
        for (int reg = 0; reg < 4; reg++){
            int row = wr + r * 16 + quad * 4 + reg;
            if (rowStart + row < rowEnd){
                int node = nodeIdx[row];
                #pragma unroll
                for (int c = 0; c < 4; c++){
                    int gc = c0 + wc + c * 16 + m16;
                    float v = acc[r][c][reg] + ldf(ba, t * 256 + gc, fba);
                    float xv = ldf(Xv, node * 256 + gc, fx);
                    out[node * 256 + gc] = v * ag + xv * (1.f - ag);
                }
            }
        }
    }
}

// ---- VALU fallback projections (validated r7) ----
__global__ __launch_bounds__(256) void k_proj(
    const void* __restrict__ X, const int* __restrict__ nt,
    const void* __restrict__ Wk, const void* __restrict__ Wq, const void* __restrict__ Wv,
    const void* __restrict__ bk, const void* __restrict__ bq, const void* __restrict__ bv,
    unsigned short* __restrict__ kb, unsigned short* __restrict__ qtb,
    unsigned short* __restrict__ vb,
    const int* __restrict__ meta, int n)
{
    int i = blockIdx.x, tid = threadIdx.x;
    int fx = meta[30];
    int t = nt[i] & 3;
    __shared__ float xs[256];
    __shared__ float red[3][4][256];
    xs[tid] = ldf(X, i * 256 + tid, fx);
    __syncthreads();
    int seg = tid >> 6;
    int cg  = (tid & 63) * 4;
    int base = t * 65536 + cg;
    #pragma unroll
    for (int m = 0; m < 3; m++){
        const void* W = (m == 0) ? Wk : (m == 1) ? Wq : Wv;
        int fw = meta[31 + m];
        float ax = 0.f, ay = 0.f, az = 0.f, aw = 0.f;
        for (int k = seg * 64; k < seg * 64 + 64; k++){
            float xv = xs[k];
            float4 w = ldf4(W, base + k * 256, fw);
            ax += xv * w.x; ay += xv * w.y; az += xv * w.z; aw += xv * w.w;
        }
        float4 st = {ax, ay, az, aw};
        *reinterpret_cast<float4*>(&red[m][seg][cg]) = st;
    }
    __syncthreads();
    #pragma unroll
    for (int m = 0; m < 3; m++){
        const void* B = (m == 0) ? bk : (m == 1) ? bq : bv;
        unsigned short* O = (m == 0) ? kb : (m == 1) ? qtb : vb;
        float v = red[m][0][tid] + red[m][1][tid] + red[m][2][tid] + red[m][3][tid]
                + ldf(B, t * 256 + tid, meta[35 + m]);
        O[i * 256 + tid] = f2us(v);
    }
}
__global__ __launch_bounds__(256) void k_out(
    const unsigned short* __restrict__ tb,
    const void* __restrict__ X, const int* __restrict__ nt,
    const void* __restrict__ Wa, const void* __restrict__ ba,
    const void* __restrict__ skipv,
    float* __restrict__ out,
    const int* __restrict__ meta, int n)
{
    int i = blockIdx.x, tid = threadIdx.x;
    int fx = meta[30], fwa = meta[34], fba = meta[38], fsk = meta[42];
    int t = nt[i] & 3;
    __shared__ float xs[256];
    __shared__ float red[4][256];
    xs[tid] = us2f(tb[i * 256 + tid]);
    __syncthreads();
    int seg = tid >> 6;
    int cg  = (tid & 63) * 4;
    int base = t * 65536 + cg;
    float ax = 0.f, ay = 0.f, az = 0.f, aw = 0.f;
    for (int k = seg * 64; k < seg * 64 + 64; k++){
        float xv = xs[k];
        float4 w = ldf4(Wa, base + k * 256, fwa);
        ax += xv * w.x; ay += xv * w.y; az += xv * w.z; aw += xv * w.w;
    }
    float4 st = {ax, ay, az, aw};
    *reinterpret_cast<float4*>(&red[seg][cg]) = st;
    __syncthreads();
    float v = red[0][tid] + red[1][tid] + red[2][tid] + red[3][tid]
            + ldf(ba, t * 256 + tid, fba);
    float sg = ldf(skipv, t, fsk);
    float a  = 1.f / (1.f + __expf(-sg));
    float xv = ldf(X, i * 256 + tid, fx);
    out[i * 256 + tid] = v * a + xv * (1.f - a);
}

// ---- node attention + messages (fallback path, validated) ----
__global__ __launch_bounds__(256) void k_node2(
    unsigned short* qtb,
    const unsigned short* __restrict__ kb, const unsigned short* __restrict__ vb,
    const int* p2, const int* p3, const int* p4,
    const int* __restrict__ rowp, const int* __restrict__ eix,
    const void* __restrict__ rel_att, const void* __restrict__ rel_msg,
    const void* __restrict__ rel_pri,
    const int* __restrict__ meta, int n)
{
    const int* srcv = sel3(p2, p3, p4, meta[25]);
    const int* etv  = sel3(p2, p3, p4, meta[27]);
    int fra = meta[39], frm = meta[40], fpri = meta[41];
    int i = blockIdx.x, tid = threadIdx.x;
    int h5 = tid >> 5, z = tid & 31;

    __shared__ float qs[256];
    __shared__ float qA[RR * NH * 33];
    __shared__ float msum[RR][256];
    __shared__ float attS[16][NH];
    __shared__ float wnew[16][NH];
    __shared__ float mcur[RR][NH], dcur[RR][NH], scf[RR][NH];
    __shared__ int s_src[16], s_et[16];
    __shared__ float s_pri[RR * NH];
    __shared__ int s_mask;

    int e0 = rowp[i], deg = rowp[i + 1] - e0;

    if (tid < RR * NH) s_pri[tid] = ldf(rel_pri, tid, fpri);
    if (tid == 0) s_mask = 0;
    qs[tid] = us2f(qtb[i * 256 + tid]);
    #pragma unroll
    for (int r = 0; r < RR; r++) msum[r][tid] = 0.f;
    if (tid < RR * NH){ mcur[tid >> 3][tid & 7] = -1e30f; dcur[tid >> 3][tid & 7] = 0.f; }
    __syncthreads();

    {
        const float* qq = &qs[h5 * 32];
        #pragma unroll
        for (int r = 0; r < RR; r++){
            int base = (r * NH + h5) * 1024 + z * 32;
            float a0 = 0.f;
            #pragma unroll
            for (int e4 = 0; e4 < 8; e4++){
                float4 w = ldf4(rel_att, base + e4 * 4, fra);
                const float* q4 = qq + e4 * 4;
                a0 += w.x * q4[0] + w.y * q4[1] + w.z * q4[2] + w.w * q4[3];
            }
            qA[(r * NH + h5) * 33 + z] = a0;
        }
    }
    __syncthreads();

    for (int done = 0; done < deg; done += 16){
        int cs = min(16, deg - done);
        if (tid < cs){
            int e = eix[e0 + done + tid];
            int sj = srcv[e]; sj = (sj < 0) ? 0 : (sj >= n) ? n - 1 : sj;
            s_src[tid] = sj;
            int rr = etv[e] & 7;
            s_et[tid] = rr;
            atomicOr(&s_mask, 1 << rr);
        }
        __syncthreads();
        {
            int j = tid >> 4, hh = (tid >> 1) & 7, half = tid & 1;
            float pt = 0.f;
            if (j < cs){
                int sj = s_src[j], rj = s_et[j];
                const unsigned short* kp = kb + sj * 256 + hh * 32 + half * 16;
                const float* qa = &qA[(rj * NH + hh) * 33 + half * 16];
                uint4 u0 = *reinterpret_cast<const uint4*>(kp);
                uint4 u1 = *reinterpret_cast<const uint4*>(kp + 8);
                pt = lo2f(u0.x) * qa[0]  + hi2f(u0.x) * qa[1]
                   + lo2f(u0.y) * qa[2]  + hi2f(u0.y) * qa[3]
                   + lo2f(u0.z) * qa[4]  + hi2f(u0.z) * qa[5]
                   + lo2f(u0.w) * qa[6]  + hi2f(u0.w) * qa[7]
                   + lo2f(u1.x) * qa[8]  + hi2f(u1.x) * qa[9]
                   + lo2f(u1.y) * qa[10] + hi2f(u1.y) * qa[11]
                   + lo2f(u1.z) * qa[12] + hi2f(u1.z) * qa[13]
                   + lo2f(u1.w) * qa[14] + hi2f(u1.w) * qa[15];
            }
            pt += __shfl_xor(pt, 1);
            if (j < cs && half == 0)
                attS[j][hh] = pt * s_pri[s_et[j] * NH + hh] * 0.17677669529663687f;
        }
        __syncthreads();
        if (tid < RR * NH){
            int r = tid >> 3, hh = tid & 7;
            float m_old = mcur[r][hh];
            float m_new = m_old;
            for (int j = 0; j < cs; j++) if (s_et[j] == r) m_new = fmaxf(m_new, attS[j][hh]);
            float scale = __expf(m_old - m_new);
            float den = dcur[r][hh] * scale;
            for (int j = 0; j < cs; j++) if (s_et[j] == r) den += __expf(attS[j][hh] - m_new);
            mcur[r][hh] = m_new; dcur[r][hh] = den; scf[r][hh] = scale;
        }
        __syncthreads();
        #pragma unroll
        for (int r = 0; r < RR; r++) msum[r][tid] *= scf[r][h5];
        if (tid < cs * NH){
            int j = tid >> 3, hh = tid & 7;
            wnew[j][hh] = __expf(attS[j][hh] - mcur[s_et[j]][hh]);
        }
        __syncthreads();
        {
            float vvf[16];
            #pragma unroll
            for (int j = 0; j < 16; j++)
                if (j < cs) vvf[j] = us2f(vb[s_src[j] * 256 + tid]);
            for (int j = 0; j < cs; j++)
                msum[s_et[j]][tid] += wnew[j][h5] * vvf[j];
        }
        __syncthreads();
    }

    int mask = s_mask;
    #pragma unroll
    for (int r = 0; r < RR; r++){
        if ((mask >> r) & 1) msum[r][tid] /= dcur[r][h5];
    }
    __syncthreads();

    float tacc = 0.f;
    for (int r = 0; r < RR; r++){
        if (!((mask >> r) & 1)) continue;
        const float* ms = &msum[r][h5 * 32];
        int base = (r * NH + h5) * 1024 + z;
        float a0 = 0.f;
        #pragma unroll
        for (int c = 0; c < 32; c++)
            a0 += ms[c] * ldf(rel_msg, base + c * 32, frm);
        tacc += a0;
    }
    int np = __popc(mask); if (np == 0) np = 1;
    qtb[i * 256 + tid] = f2us(tacc / (float)np);
}

// ---- node attention using precomputed qt (f32 chunk); writes per-r aggregate M
//      (hi/lo bf16 planes) in place of the qt row ----
__global__ __launch_bounds__(256) void k_node4(
    const unsigned short* __restrict__ kb,
    const unsigned short* __restrict__ vb,
    float* __restrict__ qtM,
    const int* p2, const int* p3, const int* p4,
    const int* __restrict__ rowp, const int* __restrict__ eix,
    const void* __restrict__ rel_pri,
    const int* __restrict__ meta, int n, int c0)
{
    const int* srcv = sel3(p2, p3, p4, meta[25]);
    const int* etv  = sel3(p2, p3, p4, meta[27]);
    int fpri = meta[41];
    int i = c0 + blockIdx.x, tid = threadIdx.x;
    int h5 = tid >> 5;

    __shared__ float qA[RR * NH * 33];
    __shared__ float attS[16][NH];
    __shared__ float wnew[16][NH];
    __shared__ float mcur[RR][NH], dcur[RR][NH], scf[RR][NH];
    __shared__ int s_src[16], s_et[16];
    __shared__ float s_pri[RR * NH];
    __shared__ int s_mask;

    int e0 = rowp[i], deg = rowp[i + 1] - e0;

    if (tid < RR * NH) s_pri[tid] = ldf(rel_pri, tid, fpri);
    if (tid == 0) s_mask = 0;
    // stage this node's qt row (8 KB) into LDS, bank-safe [r][h][33] layout
    {
        const float4* qp = reinterpret_cast<const float4*>(
            (const char*)qtM + (size_t)blockIdx.x * 8192);
        #pragma unroll
        for (int c = 0; c < 2; c++){
            int G = c * 256 + tid;          // float4 index 0..511 (coalesced)
            int r = G >> 6, g4 = G & 63;
            float4 v = qp[G];
            int h = g4 >> 3, dd = (g4 & 7) * 4;
            float* dst = &qA[(r * NH + h) * 33 + dd];
            dst[0] = v.x; dst[1] = v.y; dst[2] = v.z; dst[3] = v.w;
        }
    }
    float racc[RR];
    #pragma unroll
    for (int r = 0; r < RR; r++) racc[r] = 0.f;
    if (tid < RR * NH){ mcur[tid >> 3][tid & 7] = -1e30f; dcur[tid >> 3][tid & 7] = 0.f; }
    __syncthreads();

    for (int done = 0; done < deg; done += 16){
        int cs = min(16, deg - done);
        if (tid < cs){
            int e = eix[e0 + done + tid];
            int sj = srcv[e]; sj = (sj < 0) ? 0 : (sj >= n) ? n - 1 : sj;
            s_src[tid] = sj;
            int rr = etv[e] & 7;
            s_et[tid] = rr;
            atomicOr(&s_mask, 1 << rr);
        }
        __syncthreads();
        // issue v gathers early: latency hides under dots + softmax
        float vvf[16];
        #pragma unroll
        for (int j = 0; j < 16; j++){
            vvf[j] = (j < cs) ? us2f(vb[(size_t)s_src[j] * 256 + tid]) : 0.f;
        }
        // attention dots: (j, h, half) parallel across 256 threads
        {
            int j = tid >> 4, hh = (tid >> 1) & 7, half = tid & 1;
            float pt = 0.f;
            if (j < cs){
                int sj = s_src[j], rj = s_et[j];
                const unsigned short* kp = kb + (size_t)sj * 256 + hh * 32 + half * 16;
                const float* qa = &qA[(rj * NH + hh) * 33 + half * 16];
                uint4 u0 = *reinterpret_cast<const uint4*>(kp);
                uint4 u1 = *reinterpret_cast<const uint4*>(kp + 8);
                pt = lo2f(u0.x) * qa[0]  + hi2f(u0.x) * qa[1]
                   + lo2f(u0.y) * qa[2]  + hi2f(u0.y) * qa[3]
                   + lo2f(u0.z) * qa[4]  + hi2f(u0.z) * qa[5]
                   + lo2f(u0.w) * qa[6]  + hi2f(u0.w) * qa[7]
                   + lo2f(u1.x) * qa[8]  + hi2f(u1.x) * qa[9]
                   + lo2f(u1.y) * qa[10] + hi2f(u1.y) * qa[11]
                   + lo2f(u1.z) * qa[12] + hi2f(u1.z) * qa[13]
                   + lo2f(u1.w) * qa[14] + hi2f(u1.w) * qa[15];
            }
            pt += __shfl_xor(pt, 1);
            if (j < cs && half == 0)
                attS[j][hh] = pt * s_pri[s_et[j] * NH + hh] * 0.17677669529663687f;
        }
        __syncthreads();
        if (tid < RR * NH){
            int r = tid >> 3, hh = tid & 7;
            float m_old = mcur[r][hh];
            float m_new = m_old;
            for (int j = 0; j < cs; j++) if (s_et[j] == r) m_new = fmaxf(m_new, attS[j][hh]);
            float scale = __expf(m_old - m_new);
            float den = dcur[r][hh] * scale;
            for (int j = 0; j < cs; j++) if (s_et[j] == r) den += __expf(attS[j][hh] - m_new);
            mcur[r][hh] = m_new; dcur[r][hh] = den; scf[r][hh] = scale;
        }
        __syncthreads();
        #pragma unroll
        for (int r = 0; r < RR; r++) racc[r] *= scf[r][h5];
        if (tid < cs * NH){
            int j = tid >> 3, hh = tid & 7;
            wnew[j][hh] = __expf(attS[j][hh] - mcur[s_et[j]][hh]);
        }
        __syncthreads();
        // register accumulation: branchless select over r
        #pragma unroll
        for (int j = 0; j < 16; j++){
            if (j < cs){
                float w = wnew[j][h5] * vvf[j];
                int et = s_et[j];
                #pragma unroll
                for (int r = 0; r < RR; r++)
                    racc[r] += (et == r) ? w : 0.f;
            }
        }
        __syncthreads();
    }

    int mask = s_mask;
    int np = __popc(mask); if (np == 0) np = 1;
    float inv = 1.f / (float)np;
    // overwrite qt row with M = msum/den/np as hi/lo bf16 planes (row-local, safe)
    unsigned short* Mhi = (unsigned short*)((char*)qtM + (size_t)blockIdx.x * 8192);
    unsigned short* Mlo = Mhi + 2048;
    #pragma unroll
    for (int r = 0; r < RR; r++){
        float mv = 0.f;
        if ((mask >> r) & 1) mv = racc[r] / dcur[r][h5] * inv;
        unsigned short hv = f2us(mv);
        Mhi[r * 256 + tid] = hv;
        Mlo[r * 256 + tid] = f2us(mv - us2f(hv));
    }
}

extern "C" void kernel_launch(void* const* d_in, const int* in_sizes, int n_in,
                              void* d_out, int out_size, void* d_ws, size_t ws_size,
                              hipStream_t stream)
{
    const void* x        = d_in[0];
    const int* node_type = (const int*)d_in[1];
    const int* p2        = (const int*)d_in[2];
    const int* p3        = (const int*)d_in[3];
    const int* p4        = (const int*)d_in[4];
    const void* Wk = d_in[5];  const void* bk = d_in[6];
    const void* Wq = d_in[7];  const void* bq = d_in[8];
    const void* Wv = d_in[9];  const void* bv = d_in[10];
    const void* Wa = d_in[11]; const void* ba = d_in[12];
    const void* rel_att = d_in[13];
    const void* rel_msg = d_in[14];
    const void* rel_pri = d_in[15];
    const void* skipv   = d_in[16];
    float* out = (float*)d_out;

    bool ok = (n_in == 17);
    if (ok){
        ok = ok && (in_sizes[0] == in_sizes[1] * 256);
        ok = ok && (in_sizes[2] == in_sizes[3]) && (in_sizes[3] == in_sizes[4]);
        ok = ok && (in_sizes[5] == 262144) && (in_sizes[7] == 262144)
                && (in_sizes[9] == 262144) && (in_sizes[11] == 262144);
        ok = ok && (in_sizes[6] == 1024) && (in_sizes[8] == 1024)
                && (in_sizes[10] == 1024) && (in_sizes[12] == 1024);
        ok = ok && (in_sizes[13] == 65536) && (in_sizes[14] == 65536);
        ok = ok && (in_sizes[15] == 64) && (in_sizes[16] == 4);
        ok = ok && (out_size == in_sizes[0]);
    }
    if (!ok){
        k_zerofill<<<(out_size + 255) / 256, 256, 0, stream>>>(out, out_size);
        return;
    }

    int n = in_sizes[1];
    int E = in_sizes[2];
    int nb = (n + 255) / 256;
    int eb = (E + 255) / 256;

    char* ws = (char*)d_ws;
    int* meta = (int*)ws;
    size_t off = 256;
    int* cnt  = (int*)(ws + off); off += ((size_t)n * 4 + 255) & ~(size_t)255;
    int* bsum = (int*)(ws + off); off += ((size_t)nb * 4 + 255) & ~(size_t)255;
    int* rowp = (int*)(ws + off); off += ((size_t)(n + 1) * 4 + 255) & ~(size_t)255;
    int* eix  = (int*)(ws + off); off += ((size_t)E * 4 + 255) & ~(size_t)255;
    unsigned short* kb2 = (unsigned short*)(ws + off); off += (size_t)n * 256 * 2;
    unsigned short* vb2 = (unsigned short*)(ws + off); off += (size_t)n * 256 * 2;
    unsigned short* qtb = (unsigned short*)(ws + off); off += (size_t)n * 256 * 2;
    size_t off_lean = off;
    int* perm = (int*)(ws + off); off += ((size_t)n * 4 + 255) & ~(size_t)255;
    unsigned short* WT = (unsigned short*)(ws + off); off += (size_t)16 * 65536 * 2;
    size_t off_full = off;
    // ---- rel-transform tables (hi/lo bf16) + adaptive chunk buffer ----
    unsigned short* RATh = (unsigned short*)(ws + off); off += (size_t)65536 * 2;
    unsigned short* RATl = (unsigned short*)(ws + off); off += (size_t)65536 * 2;
    unsigned short* RMTh = (unsigned short*)(ws + off); off += (size_t)65536 * 2;
    unsigned short* RMTl = (unsigned short*)(ws + off); off += (size_t)65536 * 2;
    float* qtM = (float*)(ws + off);                    // C * 8192 bytes
    size_t avail = (ws_size > off) ? ws_size - off : 0;
    long long Cll = (long long)(avail / 8192);
    int C = (Cll > (long long)n) ? n : (int)Cll;

    k_flags<<<13, 256, 0, stream>>>(x, Wk, Wq, Wv, Wa, bk, bq, bv, ba,
                                    rel_att, rel_msg, rel_pri, skipv,
                                    in_sizes[0], in_sizes[5], in_sizes[7], in_sizes[9],
                                    in_sizes[11], in_sizes[6], in_sizes[8], in_sizes[10],
                                    in_sizes[12], in_sizes[13], in_sizes[14],
                                    in_sizes[15], in_sizes[16], meta);
    k_flagfix<<<1, 64, 0, stream>>>(meta);

    if (ws_size < off_lean){
        k_copy<<<(n * 256 + 255) / 256, 256, 0, stream>>>(x, out, meta, n * 256);
        return;
    }
    bool full  = (ws_size >= off_full);
    bool full2 = full && (C >= 1024);

    k_trio<<<3, 256, 0, stream>>>(p2, p3, p4, E, n, meta);
    k_pick<<<1, 64, 0, stream>>>(meta);

    // CSR
    k_zero<<<nb, 256, 0, stream>>>(cnt, n);
    k_deg<<<eb, 256, 0, stream>>>(p2, p3, p4, cnt, meta, E, n);
    k_scan1<<<nb, 256, 0, stream>>>(cnt, rowp, bsum, n);
    k_scan2<<<1, 64, 0, stream>>>(bsum, rowp, nb, n);
    k_scan3<<<nb, 256, 0, stream>>>(rowp, bsum, n);
    k_zero<<<nb, 256, 0, stream>>>(cnt, n);
    k_escat<<<eb, 256, 0, stream>>>(p2, p3, p4, cnt, rowp, eix, meta, E, n);

    if (full){
        k_init<<<1, 64, 0, stream>>>(meta);
        k_count<<<nb, 256, 0, stream>>>(node_type, meta, n);
        k_prefix<<<1, 64, 0, stream>>>(meta);
        k_scatter<<<nb, 256, 0, stream>>>(node_type, meta, perm, n);
        k_transW<<<4096, 256, 0, stream>>>(Wk, Wq, Wv, Wa, WT, meta);
        int maxRT = n / 64 + TT;
        k_gemm_qkv<<<dim3(maxRT, 6), 256, 0, stream>>>(x, perm, meta, WT, bk, bq, bv,
                                                       kb2, qtb, vb2);
        if (full2){
            k_transR<<<256, 256, 0, stream>>>(rel_att, rel_msg, RATh, RATl, RMTh, RMTl, meta);
            for (int c0 = 0; c0 < n; c0 += C){
                int cend = (c0 + C < n) ? (c0 + C) : n;
                int blk64 = (cend - c0 + 63) >> 6;
                k_relq<<<blk64, 256, 0, stream>>>(qtb, RATh, RATl, qtM, c0, cend);
                k_node4<<<cend - c0, 256, 0, stream>>>(kb2, vb2, qtM, p2, p3, p4,
                                                       rowp, eix, rel_pri, meta, n, c0);
                k_relmsg<<<blk64, 256, 0, stream>>>(qtM, RMTh, RMTl, qtb, c0, cend);
            }
        } else {
            k_node2<<<n, 256, 0, stream>>>(qtb, kb2, vb2, p2, p3, p4, rowp, eix,
                                           rel_att, rel_msg, rel_pri, meta, n);
        }
        k_gemm_out<<<dim3(maxRT, 2), 256, 0, stream>>>(qtb, x, perm, meta,
                                                       WT + 12 * 65536, ba, skipv, out);
    } else {
        k_proj<<<n, 256, 0, stream>>>(x, node_type, Wk, Wq, Wv, bk, bq, bv,
                                      kb2, qtb, vb2, meta, n);
        k_node2<<<n, 256, 0, stream>>>(qtb, kb2, vb2, p2, p3, p4, rowp, eix,
                                       rel_att, rel_msg, rel_pri, meta, n);
        k_out<<<n, 256, 0, stream>>>(qtb, x, node_type, Wa, ba, skipv, out, meta, n);
    }
}

// Round 4
// 1346.587 us; speedup vs baseline: 2.1263x; 1.0794x over previous
//
#include <hip/hip_runtime.h>

#define TT 4
#define RR 8
#define NH 8
#define DKK 32

typedef float floatx4 __attribute__((ext_vector_type(4)));
typedef __bf16 bf16x8 __attribute__((ext_vector_type(8)));

__device__ __forceinline__ float us2f(unsigned short s){
    union{unsigned int u; float f;} x; x.u = ((unsigned int)s) << 16; return x.f;
}
__device__ __forceinline__ float lo2f(unsigned int u){
    union{unsigned int x; float f;} a; a.x = u << 16; return a.f;
}
__device__ __forceinline__ float hi2f(unsigned int u){
    union{unsigned int x; float f;} a; a.x = u & 0xffff0000u; return a.f;
}
__device__ __forceinline__ unsigned short f2us(float f){
    union{float f; unsigned int u;} x; x.f = f;
    unsigned int u = x.u;
    unsigned int r = (u + 0x7fffu + ((u >> 16) & 1u)) >> 16;   // RNE bf16
    return (unsigned short)r;
}
__device__ __forceinline__ float ldf(const void* p, int i, int isf32){
    return isf32 ? ((const float*)p)[i] : us2f(((const unsigned short*)p)[i]);
}
__device__ __forceinline__ float4 ldf4(const void* p, int i, int isf32){  // i % 4 == 0
    if (isf32) return *reinterpret_cast<const float4*>((const float*)p + i);
    uint2 u = *reinterpret_cast<const uint2*>((const unsigned short*)p + i);
    float4 r; r.x = lo2f(u.x); r.y = hi2f(u.x); r.z = lo2f(u.y); r.w = hi2f(u.y);
    return r;
}
__device__ __forceinline__ const int* sel3(const int* a, const int* b, const int* c, int s){
    return (s == 0) ? a : (s == 1) ? b : c;
}
__device__ __forceinline__ int sw32(int row, int g){
    return row * 32 + ((g ^ (row >> 2)) & 3) * 8;
}

// ---- per-array dtype flags: meta[30+id] = 0 bf16 / 1 fp32 / -1 unknown ----
__global__ void k_flags(const void* p0, const void* p1, const void* p2, const void* p3,
                        const void* p4, const void* p5, const void* p6, const void* p7,
                        const void* p8, const void* p9, const void* p10, const void* p11,
                        const void* p12,
                        int n0, int n1, int n2, int n3, int n4, int n5, int n6, int n7,
                        int n8, int n9, int n10, int n11, int n12,
                        int* __restrict__ meta)
{
    const void* ps[13] = {p0,p1,p2,p3,p4,p5,p6,p7,p8,p9,p10,p11,p12};
    int ns[13] = {n0,n1,n2,n3,n4,n5,n6,n7,n8,n9,n10,n11,n12};
    int id = blockIdx.x;
    const unsigned short* p = (const unsigned short*)ps[id];
    int half = ns[id] >> 1;
    int nsamp = (half < 256) ? half : 256;
    int step = (nsamp > 0) ? (half / nsamp) : 1;
    int tid = threadIdx.x;
    int sane = 0, nzv = 0;
    if (tid < nsamp){
        unsigned short u = p[2 * (tid * step)];
        nzv = (u != 0);
        int e = (u >> 7) & 0xFF;
        sane = (e >= 100 && e <= 140) ? 1 : 0;
    }
    __shared__ int c_s[4], c_n[4];
    unsigned long long ms = __ballot(sane != 0);
    unsigned long long mn = __ballot(nzv != 0);
    if ((tid & 63) == 0){ c_s[tid >> 6] = (int)__popcll(ms); c_n[tid >> 6] = (int)__popcll(mn); }
    __syncthreads();
    if (tid == 0){
        int cs = c_s[0] + c_s[1] + c_s[2] + c_s[3];
        int cn = c_n[0] + c_n[1] + c_n[2] + c_n[3];
        meta[30 + id] = (cn == 0) ? -1 : ((2 * cs >= nsamp) ? 0 : 1);
    }
}
__global__ void k_flagfix(int* meta){
    if (threadIdx.x == 0 && blockIdx.x == 0){
        int xf = meta[30]; if (xf < 0) xf = 1;
        meta[30] = xf; meta[24] = xf;
        for (int j = 1; j < 13; j++) if (meta[30 + j] < 0) meta[30 + j] = xf;
    }
}

// ---- identify src/dst/etype among the three E-sized int arrays ----
__global__ void k_trio(const int* pa, const int* pb, const int* pc, int E, int n,
                       int* __restrict__ meta){
    const int* ps[3] = {pa, pb, pc};
    int c = blockIdx.x, tid = threadIdx.x;
    const int* p = ps[c];
    int step = E / 1024; if (step < 1) step = 1;
    int mx = 0, hits = 0;
    for (int j = 0; j < 4; j++){
        long long e = (long long)(tid + j * 256) * step;
        if (e < E){
            int v = p[e];
            mx = max(mx, v);
            hits += (v == (int)(e % n)) ? 1 : 0;
        }
    }
    __shared__ int smx[4], sh[4];
    for (int o = 32; o; o >>= 1){ mx = max(mx, __shfl_down(mx, o, 64)); hits += __shfl_down(hits, o, 64); }
    if ((tid & 63) == 0){ smx[tid >> 6] = mx; sh[tid >> 6] = hits; }
    __syncthreads();
    if (tid == 0){
        mx = max(max(smx[0], smx[1]), max(smx[2], smx[3]));
        hits = sh[0] + sh[1] + sh[2] + sh[3];
        meta[44 + c] = mx; meta[47 + c] = hits;
    }
}
__global__ void k_pick(int* meta){
    if (threadIdx.x == 0 && blockIdx.x == 0){
        int m0 = meta[44], m1 = meta[45], m2 = meta[46];
        int h[3] = {meta[47], meta[48], meta[49]};
        int et = (m2 < 8) ? 2 : ((m0 < 8) ? 0 : ((m1 < 8) ? 1 : 2));
        int a = -1, b = -1;
        for (int c = 0; c < 3; c++) if (c != et){ if (a < 0) a = c; else b = c; }
        int srcsel = a, dstsel = b;
        if (h[a] >= 1000 && h[b] < 1000){ dstsel = a; srcsel = b; }
        meta[25] = srcsel; meta[26] = dstsel; meta[27] = et;
    }
}

// ---- fallbacks ----
__global__ void k_zerofill(float* out, int tot){
    int i = blockIdx.x * 256 + threadIdx.x;
    if (i < tot) out[i] = 0.f;
}
__global__ void k_copy(const void* __restrict__ xv, float* __restrict__ out,
                       const int* __restrict__ meta, int tot){
    int isf32 = meta[24];
    int i = blockIdx.x * 256 + threadIdx.x;
    if (i < tot) out[i] = ldf(xv, i, isf32);
}

// ---- bucket build (validated r3) ----
__global__ void k_init(int* meta){
    if (threadIdx.x < 24) meta[threadIdx.x] = 0;
}
__global__ void k_count(const int* __restrict__ nt, int* __restrict__ meta, int n){
    int i = blockIdx.x * 256 + threadIdx.x;
    int t = (i < n) ? (nt[i] & 3) : -1;
    int lane = threadIdx.x & 63;
    #pragma unroll
    for (int tt = 0; tt < TT; tt++){
        unsigned long long m = __ballot(t == tt);
        if (m){
            int leader = __builtin_ctzll(m);
            if (lane == leader) atomicAdd(&meta[tt], (int)__popcll(m));
        }
    }
}
__global__ void k_prefix(int* meta){
    if (threadIdx.x == 0){
        int off = 0, tb = 0;
        for (int t = 0; t < TT; t++){
            int c = meta[t];
            meta[4 + t]  = off;
            meta[13 + t] = off;
            meta[8 + t]  = tb;
            off += c;
            tb  += (c + 63) >> 6;
        }
        meta[12] = tb;
    }
}
__global__ void k_scatter(const int* __restrict__ nt, int* __restrict__ meta,
                          int* __restrict__ perm, int n){
    int i = blockIdx.x * 256 + threadIdx.x;
    int t = (i < n) ? (nt[i] & 3) : -1;
    int lane = threadIdx.x & 63;
    #pragma unroll
    for (int tt = 0; tt < TT; tt++){
        unsigned long long m = __ballot(t == tt);
        if (m){
            int leader = __builtin_ctzll(m);
            int base = 0;
            if (lane == leader) base = atomicAdd(&meta[13 + tt], (int)__popcll(m));
            base = __shfl(base, leader, 64);
            if (t == tt){
                int rank = __popcll(m & ((1ull << lane) - 1ull));
                perm[base + rank] = i;
            }
        }
    }
}

// ---- weight transpose: WT[m][outcol][k] = W[m][k][outcol] ----
__global__ void k_transW(const void* __restrict__ Wk, const void* __restrict__ Wq,
                         const void* __restrict__ Wv, const void* __restrict__ Wa,
                         unsigned short* __restrict__ WT, const int* __restrict__ meta)
{
    int idx = blockIdx.x * 256 + threadIdx.x;
    int m   = idx >> 16;
    int loc = idx & 65535;
    int j = loc >> 8, k = loc & 255;
    int mt = m >> 2, t = m & 3;
    const void* W = (mt == 0) ? Wk : (mt == 1) ? Wq : (mt == 2) ? Wv : Wa;
    int flag = meta[31 + mt];
    WT[idx] = f2us(ldf(W, t * 65536 + k * 256 + j, flag));
}

// ---- rel-table prep for MFMA path: hi/lo bf16 split; RMT transposed ----
// RAT[r][h][d][e] = rel_att[r][h][d][e]   (B layout [outcol=d][k=e])
// RMT[r][h][e][d] = rel_msg[r][h][d][e]   (B layout [outcol=e][k=d])
__global__ void k_transR(const void* __restrict__ rel_att, const void* __restrict__ rel_msg,
                         unsigned short* __restrict__ RATh, unsigned short* __restrict__ RATl,
                         unsigned short* __restrict__ RMTh, unsigned short* __restrict__ RMTl,
                         const int* __restrict__ meta)
{
    int idx = blockIdx.x * 256 + threadIdx.x;       // 0..65535
    int fra = meta[39], frm = meta[40];
    float wa = ldf(rel_att, idx, fra);
    unsigned short ha = f2us(wa);
    RATh[idx] = ha;
    RATl[idx] = f2us(wa - us2f(ha));
    int quad = idx >> 10, loc = idx & 1023, d = loc >> 5, e = loc & 31;
    float wm = ldf(rel_msg, quad * 1024 + d * 32 + e, frm);
    unsigned short hm = f2us(wm);
    int oidx = quad * 1024 + e * 32 + d;
    RMTh[oidx] = hm;
    RMTl[oidx] = f2us(wm - us2f(hm));
}

// ---- batched qt GEMM (B-reuse restructure): qt[node-c0][r*256 + h*32 + d] =
//      sum_e q[node][h*32+e] * rel_att[r][h][d][e]  (hi/lo bf16 B, f32 out)
//      wave w covers r in {2w,2w+1} x all 64 rows (4 tiles): each B-fragment
//      pair feeds 8 MFMAs instead of 2 ----
__global__ __launch_bounds__(256) void k_relq(
    const unsigned short* __restrict__ Ain,
    const unsigned short* __restrict__ Bhi, const unsigned short* __restrict__ Blo,
    float* __restrict__ outF, int c0, int cend)
{
    int base = c0 + blockIdx.x * 64;
    __shared__ __align__(16) unsigned short As[64 * 264];
    int tid = threadIdx.x;
    #pragma unroll
    for (int c = 0; c < 8; c++){
        int G = c * 256 + tid;            // granule of 8 halfs
        int row = G >> 5, g = G & 31;
        int node = base + row;
        uint4 v;
        if (node < cend) v = *reinterpret_cast<const uint4*>(Ain + (size_t)node * 256 + g * 8);
        else { v.x = v.y = v.z = v.w = 0u; }
        *reinterpret_cast<uint4*>(&As[row * 264 + g * 8]) = v;
    }
    __syncthreads();
    int wave = tid >> 6, lane = tid & 63;
    int m16 = lane & 15, quad = lane >> 4;

    #pragma unroll
    for (int rr = 0; rr < 2; rr++){
        int r = (wave << 1) + rr;
        #pragma unroll
        for (int h = 0; h < 8; h++){
            bf16x8 af[4];
            #pragma unroll
            for (int t = 0; t < 4; t++)
                af[t] = *reinterpret_cast<const bf16x8*>(&As[(t * 16 + m16) * 264 + h * 32 + quad * 8]);
            #pragma unroll
            for (int ct = 0; ct < 2; ct++){
                int bix = (((r * 8 + h) * 32) + ct * 16 + m16) * 32 + quad * 8;
                bf16x8 bh = *reinterpret_cast<const bf16x8*>(Bhi + bix);
                bf16x8 bl = *reinterpret_cast<const bf16x8*>(Blo + bix);
                floatx4 acr[4] = {};
                #pragma unroll
                for (int t = 0; t < 4; t++)
                    acr[t] = __builtin_amdgcn_mfma_f32_16x16x32_bf16(af[t], bl, acr[t], 0, 0, 0);
                #pragma unroll
                for (int t = 0; t < 4; t++)
                    acr[t] = __builtin_amdgcn_mfma_f32_16x16x32_bf16(af[t], bh, acr[t], 0, 0, 0);
                int colb = r * 256 + h * 32 + ct * 16 + m16;
                #pragma unroll
                for (int t = 0; t < 4; t++){
                    #pragma unroll
                    for (int reg = 0; reg < 4; reg++){
                        int node = base + t * 16 + quad * 4 + reg;
                        if (node < cend)
                            outF[(size_t)(node - c0) * 2048 + colb] = acr[t][reg];
                    }
                }
            }
        }
    }
}

// ---- batched rel_msg GEMM (B-reuse restructure):
//      t[node][h*32+e] = sum_{r,d} M[node][r,h*32+d]*rel_msg[r,h,d,e]
//      wave w covers h in {2w,2w+1} x all 64 rows; acc persists across r ----
__global__ __launch_bounds__(256) void k_relmsg(
    const float* __restrict__ Mv,
    const unsigned short* __restrict__ Bhi, const unsigned short* __restrict__ Blo,
    unsigned short* __restrict__ outT, int c0, int cend)
{
    int base = c0 + blockIdx.x * 64;
    __shared__ __align__(16) unsigned short Ahi[64 * 264];
    __shared__ __align__(16) unsigned short Alo[64 * 264];
    int tid = threadIdx.x;
    int wave = tid >> 6, lane = tid & 63;
    int m16 = lane & 15, quad = lane >> 4;

    floatx4 acc[2][2][4] = {};   // [hh][ct][tile]

    for (int r = 0; r < RR; r++){
        __syncthreads();
        #pragma unroll
        for (int it = 0; it < 8; it++){
            int G = it * 256 + tid;       // granule of 8 halfs: 64 rows x 32 granules
            int row = G >> 5, g = G & 31;
            int node = base + row;
            uint4 vh, vl;
            vh.x = vh.y = vh.z = vh.w = 0u;
            vl = vh;
            if (node < cend){
                const unsigned short* Mrow =
                    (const unsigned short*)((const char*)Mv + (size_t)(node - c0) * 8192);
                vh = *reinterpret_cast<const uint4*>(Mrow + r * 256 + g * 8);
                vl = *reinterpret_cast<const uint4*>(Mrow + 2048 + r * 256 + g * 8);
            }
            *reinterpret_cast<uint4*>(&Ahi[row * 264 + g * 8]) = vh;
            *reinterpret_cast<uint4*>(&Alo[row * 264 + g * 8]) = vl;
        }
        __syncthreads();
        #pragma unroll
        for (int hh = 0; hh < 2; hh++){
            int h = (wave << 1) + hh;
            bf16x8 ah[4], al[4];
            #pragma unroll
            for (int t = 0; t < 4; t++){
                int aoff = (t * 16 + m16) * 264 + h * 32 + quad * 8;
                ah[t] = *reinterpret_cast<const bf16x8*>(&Ahi[aoff]);
                al[t] = *reinterpret_cast<const bf16x8*>(&Alo[aoff]);
            }
            #pragma unroll
            for (int ct = 0; ct < 2; ct++){
                int bix = (((r * 8 + h) * 32) + ct * 16 + m16) * 32 + quad * 8;
                bf16x8 bh = *reinterpret_cast<const bf16x8*>(Bhi + bix);
                bf16x8 bl = *reinterpret_cast<const bf16x8*>(Blo + bix);
                #pragma unroll
                for (int t = 0; t < 4; t++){
                    acc[hh][ct][t] = __builtin_amdgcn_mfma_f32_16x16x32_bf16(ah[t], bh, acc[hh][ct][t], 0, 0, 0);
                    acc[hh][ct][t] = __builtin_amdgcn_mfma_f32_16x16x32_bf16(al[t], bh, acc[hh][ct][t], 0, 0, 0);
                    acc[hh][ct][t] = __builtin_amdgcn_mfma_f32_16x16x32_bf16(ah[t], bl, acc[hh][ct][t], 0, 0, 0);
                }
            }
        }
    }
    #pragma unroll
    for (int hh = 0; hh < 2; hh++){
        int h = (wave << 1) + hh;
        #pragma unroll
        for (int ct = 0; ct < 2; ct++){
            #pragma unroll
            for (int t = 0; t < 4; t++){
                #pragma unroll
                for (int reg = 0; reg < 4; reg++){
                    int node = base + t * 16 + quad * 4 + reg;
                    if (node < cend)
                        outT[(size_t)node * 256 + h * 32 + ct * 16 + m16] = f2us(acc[hh][ct][t][reg]);
                }
            }
        }
    }
}

// ---- CSR build ----
__global__ void k_zero(int* a, int n){
    int i = blockIdx.x * 256 + threadIdx.x;
    if (i < n) a[i] = 0;
}
__global__ void k_deg(const int* p2, const int* p3, const int* p4,
                      int* __restrict__ cnt, const int* __restrict__ meta, int E, int n){
    const int* dst = sel3(p2, p3, p4, meta[26]);
    int e = blockIdx.x * 256 + threadIdx.x;
    if (e < E){
        int d = dst[e];
        if (d >= 0 && d < n) atomicAdd(&cnt[d], 1);
    }
}
__global__ void k_scan1(const int* __restrict__ cnt, int* __restrict__ rowp,
                        int* __restrict__ bsum, int n){
    __shared__ int s[256];
    int b = blockIdx.x, tid = threadIdx.x;
    int i = b * 256 + tid;
    int v = (i < n) ? cnt[i] : 0;
    s[tid] = v;
    __syncthreads();
    for (int d = 1; d < 256; d <<= 1){
        int add = (tid >= d) ? s[tid - d] : 0;
        __syncthreads();
        s[tid] += add;
        __syncthreads();
    }
    if (i < n) rowp[i] = s[tid] - v;
    if (tid == 255) bsum[b] = s[255];
}
__global__ void k_scan2(int* bsum, int* rowp, int nb, int n){
    if (threadIdx.x == 0){
        int run = 0;
        for (int b = 0; b < nb; b++){ int t = bsum[b]; bsum[b] = run; run += t; }
        rowp[n] = run;
    }
}
__global__ void k_scan3(int* rowp, const int* __restrict__ bsum, int n){
    int i = blockIdx.x * 256 + threadIdx.x;
    if (i < n) rowp[i] += bsum[i >> 8];
}
__global__ void k_escat(const int* p2, const int* p3, const int* p4,
                        int* __restrict__ cur, const int* __restrict__ rowp,
                        int* __restrict__ eix, const int* __restrict__ meta, int E, int n){
    const int* dst = sel3(p2, p3, p4, meta[26]);
    int e = blockIdx.x * 256 + threadIdx.x;
    if (e < E){
        int d = dst[e];
        if (d >= 0 && d < n){
            int pos = atomicAdd(&cur[d], 1);
            eix[rowp[d] + pos] = e;
        }
    }
}

// ---- MFMA typed GEMM: QKV (validated r3, fp32-in adapted) ----
__global__ __launch_bounds__(256) void k_gemm_qkv(
    const void* __restrict__ Xv,
    const int* __restrict__ perm, const int* __restrict__ meta,
    const unsigned short* __restrict__ WT,
    const void* __restrict__ bk, const void* __restrict__ bq, const void* __restrict__ bv,
    unsigned short* __restrict__ kb, unsigned short* __restrict__ qb,
    unsigned short* __restrict__ vb)
{
    int rt = blockIdx.x;
    if (rt >= meta[12]) return;
    int fx = meta[30];
    int t = 0;
    while (t < TT - 1 && rt >= meta[8 + t + 1]) t++;
    int lt = rt - meta[8 + t];
    int rowStart = meta[4 + t] + (lt << 6);
    int rowEnd   = meta[4 + t] + meta[t];

    int ct = blockIdx.y;          // 0..5
    int mt = ct >> 1;             // 0=k 1=q 2=v
    int c0 = (ct & 1) * 128;
    const unsigned short* Wm = WT + (((mt << 2) + t) << 16);
    const void* bias = (mt == 0) ? bk : (mt == 1) ? bq : bv;
    int fb = meta[35 + mt];
    unsigned short* outb = (mt == 0) ? kb : (mt == 1) ? qb : vb;

    __shared__ __align__(16) unsigned short As[64 * 32];
    __shared__ __align__(16) unsigned short Bs[128 * 32];
    __shared__ int nodeIdx[64];

    int tid = threadIdx.x;
    if (tid < 64){
        int p = rowStart + tid;
        nodeIdx[tid] = perm[(p < rowEnd) ? p : (rowEnd - 1)];
    }
    __syncthreads();

    int wave = tid >> 6, lane = tid & 63;
    int wr = (wave >> 1) * 32;
    int wc = (wave & 1) * 64;
    int m16 = lane & 15, quad = lane >> 4;

    int arow = tid & 63, aseg = tid >> 6;
    int anode = nodeIdx[arow];

    floatx4 acc[2][4] = {};

    for (int k0 = 0; k0 < 256; k0 += 32){
        __syncthreads();
        uint4 av;
        if (fx){
            const float* af = (const float*)Xv + anode * 256 + aseg * 8 + k0;
            float4 f0 = *reinterpret_cast<const float4*>(af);
            float4 f1 = *reinterpret_cast<const float4*>(af + 4);
            av.x = (unsigned)f2us(f0.x) | ((unsigned)f2us(f0.y) << 16);
            av.y = (unsigned)f2us(f0.z) | ((unsigned)f2us(f0.w) << 16);
            av.z = (unsigned)f2us(f1.x) | ((unsigned)f2us(f1.y) << 16);
            av.w = (unsigned)f2us(f1.z) | ((unsigned)f2us(f1.w) << 16);
        } else {
            av = *reinterpret_cast<const uint4*>((const unsigned short*)Xv + anode * 256 + aseg * 8 + k0);
        }
        *reinterpret_cast<uint4*>(&As[sw32(arow, aseg)]) = av;
        #pragma unroll
        for (int it = 0; it < 2; it++){
            int idx2 = tid + it * 256;
            int cc = idx2 >> 2, g = idx2 & 3;
            uint4 bv4 = *reinterpret_cast<const uint4*>(Wm + (c0 + cc) * 256 + k0 + g * 8);
            *reinterpret_cast<uint4*>(&Bs[sw32(cc, g)]) = bv4;
        }
        __syncthreads();
        bf16x8 a[2], b[4];
        #pragma unroll
        for (int r = 0; r < 2; r++)
            a[r] = *reinterpret_cast<const bf16x8*>(&As[sw32(wr + r * 16 + m16, quad)]);
        #pragma unroll
        for (int c = 0; c < 4; c++)
            b[c] = *reinterpret_cast<const bf16x8*>(&Bs[sw32(wc + c * 16 + m16, quad)]);
        #pragma unroll
        for (int r = 0; r < 2; r++)
            #pragma unroll
            for (int c = 0; c < 4; c++)
                acc[r][c] = __builtin_amdgcn_mfma_f32_16x16x32_bf16(a[r], b[c], acc[r][c], 0, 0, 0);
    }

    #pragma unroll
    for (int r = 0; r < 2; r++){
        #pragma unroll
        for (int reg = 0; reg < 4; reg++){
            int row = wr + r * 16 + quad * 4 + reg;
            if (rowStart + row < rowEnd){
                int node = nodeIdx[row];
                #pragma unroll
                for (int c = 0; c < 4; c++){
                    int gc = c0 + wc + c * 16 + m16;
                    float v = acc[r][c][reg] + ldf(bias, t * 256 + gc, fb);
                    outb[node * 256 + gc] = f2us(v);
                }
            }
        }
    }
}

// ---- MFMA typed GEMM: output projection + skip gate (fp32 out) ----
__global__ __launch_bounds__(256) void k_gemm_out(
    const unsigned short* __restrict__ A,
    const void* __restrict__ Xv,
    const int* __restrict__ perm, const int* __restrict__ meta,
    const unsigned short* __restrict__ WTa,
    const void* __restrict__ ba, const void* __restrict__ skipv,
    float* __restrict__ out)
{
    int rt = blockIdx.x;
    if (rt >= meta[12]) return;
    int fx = meta[30], fba = meta[38], fsk = meta[42];
    int t = 0;
    while (t < TT - 1 && rt >= meta[8 + t + 1]) t++;
    int lt = rt - meta[8 + t];
    int rowStart = meta[4 + t] + (lt << 6);
    int rowEnd   = meta[4 + t] + meta[t];
    int c0 = blockIdx.y * 128;
    const unsigned short* Wm = WTa + (t << 16);
    float sg = ldf(skipv, t, fsk);
    float ag = 1.f / (1.f + __expf(-sg));

    __shared__ __align__(16) unsigned short As[64 * 32];
    __shared__ __align__(16) unsigned short Bs[128 * 32];
    __shared__ int nodeIdx[64];

    int tid = threadIdx.x;
    if (tid < 64){
        int p = rowStart + tid;
        nodeIdx[tid] = perm[(p < rowEnd) ? p : (rowEnd - 1)];
    }
    __syncthreads();

    int wave = tid >> 6, lane = tid & 63;
    int wr = (wave >> 1) * 32;
    int wc = (wave & 1) * 64;
    int m16 = lane & 15, quad = lane >> 4;

    int arow = tid & 63, aseg = tid >> 6;
    int anode = nodeIdx[arow];
    const unsigned short* aptr = A + anode * 256 + aseg * 8;

    floatx4 acc[2][4] = {};

    for (int k0 = 0; k0 < 256; k0 += 32){
        __syncthreads();
        uint4 av = *reinterpret_cast<const uint4*>(aptr + k0);
        *reinterpret_cast<uint4*>(&As[sw32(arow, aseg)]) = av;
        #pragma unroll
        for (int it = 0; it < 2; it++){
            int idx2 = tid + it * 256;
            int cc = idx2 >> 2, g = idx2 & 3;
            uint4 bv4 = *reinterpret_cast<const uint4*>(Wm + (c0 + cc) * 256 + k0 + g * 8);
            *reinterpret_cast<uint4*>(&Bs[sw32(cc, g)]) = bv4;
        }
        __syncthreads();
        bf16x8 a[2], b[4];
        #pragma unroll
        for (int r = 0; r < 2; r++)
            a[r] = *reinterpret_cast<const bf16x8*>(&As[sw32(wr + r * 16 + m16, quad)]);
        #pragma unroll
        for (int c = 0; c < 4; c++)
            b[c] = *reinterpret_cast<const bf16x8*>(&Bs[sw32(wc + c * 16 + m16, quad)]);
        #pragma unroll
        for (int r = 0; r < 2; r++)
            #pragma unroll
            for (int c = 0; c < 4; c++)
                acc[r][c] = __builtin_amdgcn_mfma_f32_16x16x32_bf16(a[r], b[c], acc[r][c], 0, 0, 0);
    }

    #pragma unroll
    for (int r = 0; r < 2; r++){
        #pragma unroll
        for (int reg = 0; reg < 4; reg++){
            int row = wr + r * 16 + quad * 4 + reg;
            if (rowStart + row < rowEnd){
                int node = nodeIdx[row];
                #pragma unroll
                for (int c = 0; c < 4; c++){
                    int gc = c0 + wc + c * 16 + m16;
                    float v = acc[r][c][reg] + ldf(ba, t * 256 + gc, fba);
                    float xv = ldf(Xv, node * 256 + gc, fx);
                    out[node * 256 + gc] = v * ag + xv * (1.f - ag);
                }
            }
        }
    }
}

// ---- VALU fallback projections (validated r7) ----
__global__ __launch_bounds__(256) void k_proj(
    const void* __restrict__ X, const int* __restrict__ nt,
    const void* __restrict__ Wk, const void* __restrict__ Wq, const void* __restrict__ Wv,
    const void* __restrict__ bk, const void* __restrict__ bq, const void* __restrict__ bv,
    unsigned short* __restrict__ kb, unsigned short* __restrict__ qtb,
    unsigned short* __restrict__ vb,
    const int* __restrict__ meta, int n)
{
    int i = blockIdx.x, tid = threadIdx.x;
    int fx = meta[30];
    int t = nt[i] & 3;
    __shared__ float xs[256];
    __shared__ float red[3][4][256];
    xs[tid] = ldf(X, i * 256 + tid, fx);
    __syncthreads();
    int seg = tid >> 6;
    int cg  = (tid & 63) * 4;
    int base = t * 65536 + cg;
    #pragma unroll
    for (int m = 0; m < 3; m++){
        const void* W = (m == 0) ? Wk : (m == 1) ? Wq : Wv;
        int fw = meta[31 + m];
        float ax = 0.f, ay = 0.f, az = 0.f, aw = 0.f;
        for (int k = seg * 64; k < seg * 64 + 64; k++){
            float xv = xs[k];
            float4 w = ldf4(W, base + k * 256, fw);
            ax += xv * w.x; ay += xv * w.y; az += xv * w.z; aw += xv * w.w;
        }
        float4 st = {ax, ay, az, aw};
        *reinterpret_cast<float4*>(&red[m][seg][cg]) = st;
    }
    __syncthreads();
    #pragma unroll
    for (int m = 0; m < 3; m++){
        const void* B = (m == 0) ? bk : (m == 1) ? bq : bv;
        unsigned short* O = (m == 0) ? kb : (m == 1) ? qtb : vb;
        float v = red[m][0][tid] + red[m][1][tid] + red[m][2][tid] + red[m][3][tid]
                + ldf(B, t * 256 + tid, meta[35 + m]);
        O[i * 256 + tid] = f2us(v);
    }
}
__global__ __launch_bounds__(256) void k_out(
    const unsigned short* __restrict__ tb,
    const void* __restrict__ X, const int* __restrict__ nt,
    const void* __restrict__ Wa, const void* __restrict__ ba,
    const void* __restrict__ skipv,
    float* __restrict__ out,
    const int* __restrict__ meta, int n)
{
    int i = blockIdx.x, tid = threadIdx.x;
    int fx = meta[30], fwa = meta[34], fba = meta[38], fsk = meta[42];
    int t = nt[i] & 3;
    __shared__ float xs[256];
    __shared__ float red[4][256];
    xs[tid] = us2f(tb[i * 256 + tid]);
    __syncthreads();
    int seg = tid >> 6;
    int cg  = (tid & 63) * 4;
    int base = t * 65536 + cg;
    float ax = 0.f, ay = 0.f, az = 0.f, aw = 0.f;
    for (int k = seg * 64; k < seg * 64 + 64; k++){
        float xv = xs[k];
        float4 w = ldf4(Wa, base + k * 256, fwa);
        ax += xv * w.x; ay += xv * w.y; az += xv * w.z; aw += xv * w.w;
    }
    float4 st = {ax, ay, az, aw};
    *reinterpret_cast<float4*>(&red[seg][cg]) = st;
    __syncthreads();
    float v = red[0][tid] + red[1][tid] + red[2][tid] + red[3][tid]
            + ldf(ba, t * 256 + tid, fba);
    float sg = ldf(skipv, t, fsk);
    float a  = 1.f / (1.f + __expf(-sg));
    float xv = ldf(X, i * 256 + tid, fx);
    out[i * 256 + tid] = v * a + xv * (1.f - a);
}

// ---- node attention + messages (fallback path, validated) ----
__global__ __launch_bounds__(256) void k_node2(
    unsigned short* qtb,
    const unsigned short* __restrict__ kb, const unsigned short* __restrict__ vb,
    const int* p2, const int* p3, const int* p4,
    const int* __restrict__ rowp, const int* __restrict__ eix,
    const void* __restrict__ rel_att, const void* __restrict__ rel_msg,
    const void* __restrict__ rel_pri,
    const int* __restrict__ meta, int n)
{
    const int* srcv = sel3(p2, p3, p4, meta[25]);
    const int* etv  = sel3(p2, p3, p4, meta[27]);
    int fra = meta[39], frm = meta[40], fpri = meta[41];
    int i = blockIdx.x, tid = threadIdx.x;
    int h5 = tid >> 5, z = tid & 31;

    __shared__ float qs[256];
    __shared__ float qA[RR * NH * 33];
    __shared__ float msum[RR][256];
    __shared__ float attS[16][NH];
    __shared__ float wnew[16][NH];
    __shared__ float mcur[RR][NH], dcur[RR][NH], scf[RR][NH];
    __shared__ int s_src[16], s_et[16];
    __shared__ float s_pri[RR * NH];
    __shared__ int s_mask;

    int e0 = rowp[i], deg = rowp[i + 1] - e0;

    if (tid < RR * NH) s_pri[tid] = ldf(rel_pri, tid, fpri);
    if (tid == 0) s_mask = 0;
    qs[tid] = us2f(qtb[i * 256 + tid]);
    #pragma unroll
    for (int r = 0; r < RR; r++) msum[r][tid] = 0.f;
    if (tid < RR * NH){ mcur[tid >> 3][tid & 7] = -1e30f; dcur[tid >> 3][tid & 7] = 0.f; }
    __syncthreads();

    {
        const float* qq = &qs[h5 * 32];
        #pragma unroll
        for (int r = 0; r < RR; r++){
            int base = (r * NH + h5) * 1024 + z * 32;
            float a0 = 0.f;
            #pragma unroll
            for (int e4 = 0; e4 < 8; e4++){
                float4 w = ldf4(rel_att, base + e4 * 4, fra);
                const float* q4 = qq + e4 * 4;
                a0 += w.x * q4[0] + w.y * q4[1] + w.z * q4[2] + w.w * q4[3];
            }
            qA[(r * NH + h5) * 33 + z] = a0;
        }
    }
    __syncthreads();

    for (int done = 0; done < deg; done += 16){
        int cs = min(16, deg - done);
        if (tid < cs){
            int e = eix[e0 + done + tid];
            int sj = srcv[e]; sj = (sj < 0) ? 0 : (sj >= n) ? n - 1 : sj;
            s_src[tid] = sj;
            int rr = etv[e] & 7;
            s_et[tid] = rr;
            atomicOr(&s_mask, 1 << rr);
        }
        __syncthreads();
        {
            int j = tid >> 4, hh = (tid >> 1) & 7, half = tid & 1;
            float pt = 0.f;
            if (j < cs){
                int sj = s_src[j], rj = s_et[j];
                const unsigned short* kp = kb + sj * 256 + hh * 32 + half * 16;
                const float* qa = &qA[(rj * NH + hh) * 33 + half * 16];
                uint4 u0 = *reinterpret_cast<const uint4*>(kp);
                uint4 u1 = *reinterpret_cast<const uint4*>(kp + 8);
                pt = lo2f(u0.x) * qa[0]  + hi2f(u0.x) * qa[1]
                   + lo2f(u0.y) * qa[2]  + hi2f(u0.y) * qa[3]
                   + lo2f(u0.z) * qa[4]  + hi2f(u0.z) * qa[5]
                   + lo2f(u0.w) * qa[6]  + hi2f(u0.w) * qa[7]
                   + lo2f(u1.x) * qa[8]  + hi2f(u1.x) * qa[9]
                   + lo2f(u1.y) * qa[10] + hi2f(u1.y) * qa[11]
                   + lo2f(u1.z) * qa[12] + hi2f(u1.z) * qa[13]
                   + lo2f(u1.w) * qa[14] + hi2f(u1.w) * qa[15];
            }
            pt += __shfl_xor(pt, 1);
            if (j < cs && half == 0)
                attS[j][hh] = pt * s_pri[s_et[j] * NH + hh] * 0.17677669529663687f;
        }
        __syncthreads();
        if (tid < RR * NH){
            int r = tid >> 3, hh = tid & 7;
            float m_old = mcur[r][hh];
            float m_new = m_old;
            for (int j = 0; j < cs; j++) if (s_et[j] == r) m_new = fmaxf(m_new, attS[j][hh]);
            float scale = __expf(m_old - m_new);
            float den = dcur[r][hh] * scale;
            for (int j = 0; j < cs; j++) if (s_et[j] == r) den += __expf(attS[j][hh] - m_new);
            mcur[r][hh] = m_new; dcur[r][hh] = den; scf[r][hh] = scale;
        }
        __syncthreads();
        #pragma unroll
        for (int r = 0; r < RR; r++) msum[r][tid] *= scf[r][h5];
        if (tid < cs * NH){
            int j = tid >> 3, hh = tid & 7;
            wnew[j][hh] = __expf(attS[j][hh] - mcur[s_et[j]][hh]);
        }
        __syncthreads();
        {
            float vvf[16];
            #pragma unroll
            for (int j = 0; j < 16; j++)
                if (j < cs) vvf[j] = us2f(vb[s_src[j] * 256 + tid]);
            for (int j = 0; j < cs; j++)
                msum[s_et[j]][tid] += wnew[j][h5] * vvf[j];
        }
        __syncthreads();
    }

    int mask = s_mask;
    #pragma unroll
    for (int r = 0; r < RR; r++){
        if ((mask >> r) & 1) msum[r][tid] /= dcur[r][h5];
    }
    __syncthreads();

    float tacc = 0.f;
    for (int r = 0; r < RR; r++){
        if (!((mask >> r) & 1)) continue;
        const float* ms = &msum[r][h5 * 32];
        int base = (r * NH + h5) * 1024 + z;
        float a0 = 0.f;
        #pragma unroll
        for (int c = 0; c < 32; c++)
            a0 += ms[c] * ldf(rel_msg, base + c * 32, frm);
        tacc += a0;
    }
    int np = __popc(mask); if (np == 0) np = 1;
    qtb[i * 256 + tid] = f2us(tacc / (float)np);
}

// ---- node attention using precomputed qt (f32 chunk); writes per-r aggregate M
//      (hi/lo bf16 planes) in place of the qt row ----
__global__ __launch_bounds__(256) void k_node4(
    const unsigned short* __restrict__ kb,
    const unsigned short* __restrict__ vb,
    float* __restrict__ qtM,
    const int* p2, const int* p3, const int* p4,
    const int* __restrict__ rowp, const int* __restrict__ eix,
    const void* __restrict__ rel_pri,
    const int* __restrict__ meta, int n, int c0)
{
    const int* srcv = sel3(p2, p3, p4, meta[25]);
    const int* etv  = sel3(p2, p3, p4, meta[27]);
    int fpri = meta[41];
    int i = c0 + blockIdx.x, tid = threadIdx.x;
    int h5 = tid >> 5;

    __shared__ float qA[RR * NH * 33];
    __shared__ float attS[16][NH];
    __shared__ float wnew[16][NH];
    __shared__ float mcur[RR][NH], dcur[RR][NH], scf[RR][NH];
    __shared__ int s_src[16], s_et[16];
    __shared__ float s_pri[RR * NH];
    __shared__ int s_mask;

    int e0 = rowp[i], deg = rowp[i + 1] - e0;

    if (tid < RR * NH) s_pri[tid] = ldf(rel_pri, tid, fpri);
    if (tid == 0) s_mask = 0;
    // stage this node's qt row (8 KB) into LDS, bank-safe [r][h][33] layout
    {
        const float4* qp = reinterpret_cast<const float4*>(
            (const char*)qtM + (size_t)blockIdx.x * 8192);
        #pragma unroll
        for (int c = 0; c < 2; c++){
            int G = c * 256 + tid;          // float4 index 0..511 (coalesced)
            int r = G >> 6, g4 = G & 63;
            float4 v = qp[G];
            int h = g4 >> 3, dd = (g4 & 7) * 4;
            float* dst = &qA[(r * NH + h) * 33 + dd];
            dst[0] = v.x; dst[1] = v.y; dst[2] = v.z; dst[3] = v.w;
        }
    }
    float racc[RR];
    #pragma unroll
    for (int r = 0; r < RR; r++) racc[r] = 0.f;
    if (tid < RR * NH){ mcur[tid >> 3][tid & 7] = -1e30f; dcur[tid >> 3][tid & 7] = 0.f; }
    __syncthreads();

    for (int done = 0; done < deg; done += 16){
        int cs = min(16, deg - done);
        if (tid < cs){
            int e = eix[e0 + done + tid];
            int sj = srcv[e]; sj = (sj < 0) ? 0 : (sj >= n) ? n - 1 : sj;
            s_src[tid] = sj;
            int rr = etv[e] & 7;
            s_et[tid] = rr;
            atomicOr(&s_mask, 1 << rr);
        }
        __syncthreads();
        // issue v gathers early: latency hides under dots + softmax
        float vvf[16];
        #pragma unroll
        for (int j = 0; j < 16; j++){
            vvf[j] = (j < cs) ? us2f(vb[(size_t)s_src[j] * 256 + tid]) : 0.f;
        }
        // attention dots: (j, h, half) parallel across 256 threads
        {
            int j = tid >> 4, hh = (tid >> 1) & 7, half = tid & 1;
            float pt = 0.f;
            if (j < cs){
                int sj = s_src[j], rj = s_et[j];
                const unsigned short* kp = kb + (size_t)sj * 256 + hh * 32 + half * 16;
                const float* qa = &qA[(rj * NH + hh) * 33 + half * 16];
                uint4 u0 = *reinterpret_cast<const uint4*>(kp);
                uint4 u1 = *reinterpret_cast<const uint4*>(kp + 8);
                pt = lo2f(u0.x) * qa[0]  + hi2f(u0.x) * qa[1]
                   + lo2f(u0.y) * qa[2]  + hi2f(u0.y) * qa[3]
                   + lo2f(u0.z) * qa[4]  + hi2f(u0.z) * qa[5]
                   + lo2f(u0.w) * qa[6]  + hi2f(u0.w) * qa[7]
                   + lo2f(u1.x) * qa[8]  + hi2f(u1.x) * qa[9]
                   + lo2f(u1.y) * qa[10] + hi2f(u1.y) * qa[11]
                   + lo2f(u1.z) * qa[12] + hi2f(u1.z) * qa[13]
                   + lo2f(u1.w) * qa[14] + hi2f(u1.w) * qa[15];
            }
            pt += __shfl_xor(pt, 1);
            if (j < cs && half == 0)
                attS[j][hh] = pt * s_pri[s_et[j] * NH + hh] * 0.17677669529663687f;
        }
        __syncthreads();
        if (tid < RR * NH){
            int r = tid >> 3, hh = tid & 7;
            float m_old = mcur[r][hh];
            float m_new = m_old;
            for (int j = 0; j < cs; j++) if (s_et[j] == r) m_new = fmaxf(m_new, attS[j][hh]);
            float scale = __expf(m_old - m_new);
            float den = dcur[r][hh] * scale;
            for (int j = 0; j < cs; j++) if (s_et[j] == r) den += __expf(attS[j][hh] - m_new);
            mcur[r][hh] = m_new; dcur[r][hh] = den; scf[r][hh] = scale;
        }
        __syncthreads();
        #pragma unroll
        for (int r = 0; r < RR; r++) racc[r] *= scf[r][h5];
        if (tid < cs * NH){
            int j = tid >> 3, hh = tid & 7;
            wnew[j][hh] = __expf(attS[j][hh] - mcur[s_et[j]][hh]);
        }
        __syncthreads();
        // register accumulation: branchless select over r
        #pragma unroll
        for (int j = 0; j < 16; j++){
            if (j < cs){
                float w = wnew[j][h5] * vvf[j];
                int et = s_et[j];
                #pragma unroll
                for (int r = 0; r < RR; r++)
                    racc[r] += (et == r) ? w : 0.f;
            }
        }
        __syncthreads();
    }

    int mask = s_mask;
    int np = __popc(mask); if (np == 0) np = 1;
    float inv = 1.f / (float)np;
    // overwrite qt row with M = msum/den/np as hi/lo bf16 planes (row-local, safe)
    unsigned short* Mhi = (unsigned short*)((char*)qtM + (size_t)blockIdx.x * 8192);
    unsigned short* Mlo = Mhi + 2048;
    #pragma unroll
    for (int r = 0; r < RR; r++){
        float mv = 0.f;
        if ((mask >> r) & 1) mv = racc[r] / dcur[r][h5] * inv;
        unsigned short hv = f2us(mv);
        Mhi[r * 256 + tid] = hv;
        Mlo[r * 256 + tid] = f2us(mv - us2f(hv));
    }
}

extern "C" void kernel_launch(void* const* d_in, const int* in_sizes, int n_in,
                              void* d_out, int out_size, void* d_ws, size_t ws_size,
                              hipStream_t stream)
{
    const void* x        = d_in[0];
    const int* node_type = (const int*)d_in[1];
    const int* p2        = (const int*)d_in[2];
    const int* p3        = (const int*)d_in[3];
    const int* p4        = (const int*)d_in[4];
    const void* Wk = d_in[5];  const void* bk = d_in[6];
    const void* Wq = d_in[7];  const void* bq = d_in[8];
    const void* Wv = d_in[9];  const void* bv = d_in[10];
    const void* Wa = d_in[11]; const void* ba = d_in[12];
    const void* rel_att = d_in[13];
    const void* rel_msg = d_in[14];
    const void* rel_pri = d_in[15];
    const void* skipv   = d_in[16];
    float* out = (float*)d_out;

    bool ok = (n_in == 17);
    if (ok){
        ok = ok && (in_sizes[0] == in_sizes[1] * 256);
        ok = ok && (in_sizes[2] == in_sizes[3]) && (in_sizes[3] == in_sizes[4]);
        ok = ok && (in_sizes[5] == 262144) && (in_sizes[7] == 262144)
                && (in_sizes[9] == 262144) && (in_sizes[11] == 262144);
        ok = ok && (in_sizes[6] == 1024) && (in_sizes[8] == 1024)
                && (in_sizes[10] == 1024) && (in_sizes[12] == 1024);
        ok = ok && (in_sizes[13] == 65536) && (in_sizes[14] == 65536);
        ok = ok && (in_sizes[15] == 64) && (in_sizes[16] == 4);
        ok = ok && (out_size == in_sizes[0]);
    }
    if (!ok){
        k_zerofill<<<(out_size + 255) / 256, 256, 0, stream>>>(out, out_size);
        return;
    }

    int n = in_sizes[1];
    int E = in_sizes[2];
    int nb = (n + 255) / 256;
    int eb = (E + 255) / 256;

    char* ws = (char*)d_ws;
    int* meta = (int*)ws;
    size_t off = 256;
    int* cnt  = (int*)(ws + off); off += ((size_t)n * 4 + 255) & ~(size_t)255;
    int* bsum = (int*)(ws + off); off += ((size_t)nb * 4 + 255) & ~(size_t)255;
    int* rowp = (int*)(ws + off); off += ((size_t)(n + 1) * 4 + 255) & ~(size_t)255;
    int* eix  = (int*)(ws + off); off += ((size_t)E * 4 + 255) & ~(size_t)255;
    unsigned short* kb2 = (unsigned short*)(ws + off); off += (size_t)n * 256 * 2;
    unsigned short* vb2 = (unsigned short*)(ws + off); off += (size_t)n * 256 * 2;
    unsigned short* qtb = (unsigned short*)(ws + off); off += (size_t)n * 256 * 2;
    size_t off_lean = off;
    int* perm = (int*)(ws + off); off += ((size_t)n * 4 + 255) & ~(size_t)255;
    unsigned short* WT = (unsigned short*)(ws + off); off += (size_t)16 * 65536 * 2;
    size_t off_full = off;
    // ---- rel-transform tables (hi/lo bf16) + adaptive L3-sized chunk buffer ----
    unsigned short* RATh = (unsigned short*)(ws + off); off += (size_t)65536 * 2;
    unsigned short* RATl = (unsigned short*)(ws + off); off += (size_t)65536 * 2;
    unsigned short* RMTh = (unsigned short*)(ws + off); off += (size_t)65536 * 2;
    unsigned short* RMTl = (unsigned short*)(ws + off); off += (size_t)65536 * 2;
    float* qtM = (float*)(ws + off);                    // C * 8192 bytes
    size_t avail = (ws_size > off) ? ws_size - off : 0;
    long long Cavail = (long long)(avail / 8192);
    if (Cavail > (long long)n) Cavail = n;
    int C = 0;
    if (Cavail >= 1024){
        // target ~12-16K nodes/chunk (~100-134 MB) so the qt/M stream stays
        // L3-resident across relq -> node4 -> relmsg; balance chunk sizes
        int target = 16384;
        int nch = (n + target - 1) / target;
        int Ceven = ((n + nch - 1) / nch + 63) & ~(int)63;
        C = (Ceven < (int)Cavail) ? Ceven : (int)Cavail;
    }

    k_flags<<<13, 256, 0, stream>>>(x, Wk, Wq, Wv, Wa, bk, bq, bv, ba,
                                    rel_att, rel_msg, rel_pri, skipv,
                                    in_sizes[0], in_sizes[5], in_sizes[7], in_sizes[9],
                                    in_sizes[11], in_sizes[6], in_sizes[8], in_sizes[10],
                                    in_sizes[12], in_sizes[13], in_sizes[14],
                                    in_sizes[15], in_sizes[16], meta);
    k_flagfix<<<1, 64, 0, stream>>>(meta);

    if (ws_size < off_lean){
        k_copy<<<(n * 256 + 255) / 256, 256, 0, stream>>>(x, out, meta, n * 256);
        return;
    }
    bool full  = (ws_size >= off_full);
    bool full2 = full && (C >= 1024);

    k_trio<<<3, 256, 0, stream>>>(p2, p3, p4, E, n, meta);
    k_pick<<<1, 64, 0, stream>>>(meta);

    // CSR
    k_zero<<<nb, 256, 0, stream>>>(cnt, n);
    k_deg<<<eb, 256, 0, stream>>>(p2, p3, p4, cnt, meta, E, n);
    k_scan1<<<nb, 256, 0, stream>>>(cnt, rowp, bsum, n);
    k_scan2<<<1, 64, 0, stream>>>(bsum, rowp, nb, n);
    k_scan3<<<nb, 256, 0, stream>>>(rowp, bsum, n);
    k_zero<<<nb, 256, 0, stream>>>(cnt, n);
    k_escat<<<eb, 256, 0, stream>>>(p2, p3, p4, cnt, rowp, eix, meta, E, n);

    if (full){
        k_init<<<1, 64, 0, stream>>>(meta);
        k_count<<<nb, 256, 0, stream>>>(node_type, meta, n);
        k_prefix<<<1, 64, 0, stream>>>(meta);
        k_scatter<<<nb, 256, 0, stream>>>(node_type, meta, perm, n);
        k_transW<<<4096, 256, 0, stream>>>(Wk, Wq, Wv, Wa, WT, meta);
        int maxRT = n / 64 + TT;
        k_gemm_qkv<<<dim3(maxRT, 6), 256, 0, stream>>>(x, perm, meta, WT, bk, bq, bv,
                                                       kb2, qtb, vb2);
        if (full2){
            k_transR<<<256, 256, 0, stream>>>(rel_att, rel_msg, RATh, RATl, RMTh, RMTl, meta);
            for (int c0 = 0; c0 < n; c0 += C){
                int cend = (c0 + C < n) ? (c0 + C) : n;
                int blk64 = (cend - c0 + 63) >> 6;
                k_relq<<<blk64, 256, 0, stream>>>(qtb, RATh, RATl, qtM, c0, cend);
                k_node4<<<cend - c0, 256, 0, stream>>>(kb2, vb2, qtM, p2, p3, p4,
                                                       rowp, eix, rel_pri, meta, n, c0);
                k_relmsg<<<blk64, 256, 0, stream>>>(qtM, RMTh, RMTl, qtb, c0, cend);
            }
        } else {
            k_node2<<<n, 256, 0, stream>>>(qtb, kb2, vb2, p2, p3, p4, rowp, eix,
                                           rel_att, rel_msg, rel_pri, meta, n);
        }
        k_gemm_out<<<dim3(maxRT, 2), 256, 0, stream>>>(qtb, x, perm, meta,
                                                       WT + 12 * 65536, ba, skipv, out);
    } else {
        k_proj<<<n, 256, 0, stream>>>(x, node_type, Wk, Wq, Wv, bk, bq, bv,
                                      kb2, qtb, vb2, meta, n);
        k_node2<<<n, 256, 0, stream>>>(qtb, kb2, vb2, p2, p3, p4, rowp, eix,
                                       rel_att, rel_msg, rel_pri, meta, n);
        k_out<<<n, 256, 0, stream>>>(qtb, x, node_type, Wa, ba, skipv, out, meta, n);
    }
}

// Round 5
// 1100.629 us; speedup vs baseline: 2.6015x; 1.2235x over previous
//
#include <hip/hip_runtime.h>

#define TT 4
#define RR 8
#define NH 8
#define DKK 32

typedef float floatx4 __attribute__((ext_vector_type(4)));
typedef __bf16 bf16x8 __attribute__((ext_vector_type(8)));

__device__ __forceinline__ float us2f(unsigned short s){
    union{unsigned int u; float f;} x; x.u = ((unsigned int)s) << 16; return x.f;
}
__device__ __forceinline__ float lo2f(unsigned int u){
    union{unsigned int x; float f;} a; a.x = u << 16; return a.f;
}
__device__ __forceinline__ float hi2f(unsigned int u){
    union{unsigned int x; float f;} a; a.x = u & 0xffff0000u; return a.f;
}
__device__ __forceinline__ unsigned short f2us(float f){
    union{float f; unsigned int u;} x; x.f = f;
    unsigned int u = x.u;
    unsigned int r = (u + 0x7fffu + ((u >> 16) & 1u)) >> 16;   // RNE bf16
    return (unsigned short)r;
}
__device__ __forceinline__ float ldf(const void* p, int i, int isf32){
    return isf32 ? ((const float*)p)[i] : us2f(((const unsigned short*)p)[i]);
}
__device__ __forceinline__ float4 ldf4(const void* p, int i, int isf32){  // i % 4 == 0
    if (isf32) return *reinterpret_cast<const float4*>((const float*)p + i);
    uint2 u = *reinterpret_cast<const uint2*>((const unsigned short*)p + i);
    float4 r; r.x = lo2f(u.x); r.y = hi2f(u.x); r.z = lo2f(u.y); r.w = hi2f(u.y);
    return r;
}
__device__ __forceinline__ const int* sel3(const int* a, const int* b, const int* c, int s){
    return (s == 0) ? a : (s == 1) ? b : c;
}
__device__ __forceinline__ int sw32(int row, int g){
    return row * 32 + ((g ^ (row >> 2)) & 3) * 8;
}

// ---- per-array dtype flags: meta[30+id] = 0 bf16 / 1 fp32 / -1 unknown ----
__global__ void k_flags(const void* p0, const void* p1, const void* p2, const void* p3,
                        const void* p4, const void* p5, const void* p6, const void* p7,
                        const void* p8, const void* p9, const void* p10, const void* p11,
                        const void* p12,
                        int n0, int n1, int n2, int n3, int n4, int n5, int n6, int n7,
                        int n8, int n9, int n10, int n11, int n12,
                        int* __restrict__ meta)
{
    const void* ps[13] = {p0,p1,p2,p3,p4,p5,p6,p7,p8,p9,p10,p11,p12};
    int ns[13] = {n0,n1,n2,n3,n4,n5,n6,n7,n8,n9,n10,n11,n12};
    int id = blockIdx.x;
    const unsigned short* p = (const unsigned short*)ps[id];
    int half = ns[id] >> 1;
    int nsamp = (half < 256) ? half : 256;
    int step = (nsamp > 0) ? (half / nsamp) : 1;
    int tid = threadIdx.x;
    int sane = 0, nzv = 0;
    if (tid < nsamp){
        unsigned short u = p[2 * (tid * step)];
        nzv = (u != 0);
        int e = (u >> 7) & 0xFF;
        sane = (e >= 100 && e <= 140) ? 1 : 0;
    }
    __shared__ int c_s[4], c_n[4];
    unsigned long long ms = __ballot(sane != 0);
    unsigned long long mn = __ballot(nzv != 0);
    if ((tid & 63) == 0){ c_s[tid >> 6] = (int)__popcll(ms); c_n[tid >> 6] = (int)__popcll(mn); }
    __syncthreads();
    if (tid == 0){
        int cs = c_s[0] + c_s[1] + c_s[2] + c_s[3];
        int cn = c_n[0] + c_n[1] + c_n[2] + c_n[3];
        meta[30 + id] = (cn == 0) ? -1 : ((2 * cs >= nsamp) ? 0 : 1);
    }
}
__global__ void k_flagfix(int* meta){
    if (threadIdx.x == 0 && blockIdx.x == 0){
        int xf = meta[30]; if (xf < 0) xf = 1;
        meta[30] = xf; meta[24] = xf;
        for (int j = 1; j < 13; j++) if (meta[30 + j] < 0) meta[30 + j] = xf;
    }
}

// ---- identify src/dst/etype among the three E-sized int arrays ----
__global__ void k_trio(const int* pa, const int* pb, const int* pc, int E, int n,
                       int* __restrict__ meta){
    const int* ps[3] = {pa, pb, pc};
    int c = blockIdx.x, tid = threadIdx.x;
    const int* p = ps[c];
    int step = E / 1024; if (step < 1) step = 1;
    int mx = 0, hits = 0;
    for (int j = 0; j < 4; j++){
        long long e = (long long)(tid + j * 256) * step;
        if (e < E){
            int v = p[e];
            mx = max(mx, v);
            hits += (v == (int)(e % n)) ? 1 : 0;
        }
    }
    __shared__ int smx[4], sh[4];
    for (int o = 32; o; o >>= 1){ mx = max(mx, __shfl_down(mx, o, 64)); hits += __shfl_down(hits, o, 64); }
    if ((tid & 63) == 0){ smx[tid >> 6] = mx; sh[tid >> 6] = hits; }
    __syncthreads();
    if (tid == 0){
        mx = max(max(smx[0], smx[1]), max(smx[2], smx[3]));
        hits = sh[0] + sh[1] + sh[2] + sh[3];
        meta[44 + c] = mx; meta[47 + c] = hits;
    }
}
__global__ void k_pick(int* meta){
    if (threadIdx.x == 0 && blockIdx.x == 0){
        int m0 = meta[44], m1 = meta[45], m2 = meta[46];
        int h[3] = {meta[47], meta[48], meta[49]};
        int et = (m2 < 8) ? 2 : ((m0 < 8) ? 0 : ((m1 < 8) ? 1 : 2));
        int a = -1, b = -1;
        for (int c = 0; c < 3; c++) if (c != et){ if (a < 0) a = c; else b = c; }
        int srcsel = a, dstsel = b;
        if (h[a] >= 1000 && h[b] < 1000){ dstsel = a; srcsel = b; }
        meta[25] = srcsel; meta[26] = dstsel; meta[27] = et;
    }
}

// ---- fallbacks ----
__global__ void k_zerofill(float* out, int tot){
    int i = blockIdx.x * 256 + threadIdx.x;
    if (i < tot) out[i] = 0.f;
}
__global__ void k_copy(const void* __restrict__ xv, float* __restrict__ out,
                       const int* __restrict__ meta, int tot){
    int isf32 = meta[24];
    int i = blockIdx.x * 256 + threadIdx.x;
    if (i < tot) out[i] = ldf(xv, i, isf32);
}

// ---- bucket build (validated r3) ----
__global__ void k_init(int* meta){
    if (threadIdx.x < 24) meta[threadIdx.x] = 0;
}
__global__ void k_count(const int* __restrict__ nt, int* __restrict__ meta, int n){
    int i = blockIdx.x * 256 + threadIdx.x;
    int t = (i < n) ? (nt[i] & 3) : -1;
    int lane = threadIdx.x & 63;
    #pragma unroll
    for (int tt = 0; tt < TT; tt++){
        unsigned long long m = __ballot(t == tt);
        if (m){
            int leader = __builtin_ctzll(m);
            if (lane == leader) atomicAdd(&meta[tt], (int)__popcll(m));
        }
    }
}
__global__ void k_prefix(int* meta){
    if (threadIdx.x == 0){
        int off = 0, tb = 0;
        for (int t = 0; t < TT; t++){
            int c = meta[t];
            meta[4 + t]  = off;
            meta[13 + t] = off;
            meta[8 + t]  = tb;
            off += c;
            tb  += (c + 63) >> 6;
        }
        meta[12] = tb;
    }
}
__global__ void k_scatter(const int* __restrict__ nt, int* __restrict__ meta,
                          int* __restrict__ perm, int n){
    int i = blockIdx.x * 256 + threadIdx.x;
    int t = (i < n) ? (nt[i] & 3) : -1;
    int lane = threadIdx.x & 63;
    #pragma unroll
    for (int tt = 0; tt < TT; tt++){
        unsigned long long m = __ballot(t == tt);
        if (m){
            int leader = __builtin_ctzll(m);
            int base = 0;
            if (lane == leader) base = atomicAdd(&meta[13 + tt], (int)__popcll(m));
            base = __shfl(base, leader, 64);
            if (t == tt){
                int rank = __popcll(m & ((1ull << lane) - 1ull));
                perm[base + rank] = i;
            }
        }
    }
}

// ---- weight transpose: WT[m][outcol][k] = W[m][k][outcol] ----
__global__ void k_transW(const void* __restrict__ Wk, const void* __restrict__ Wq,
                         const void* __restrict__ Wv, const void* __restrict__ Wa,
                         unsigned short* __restrict__ WT, const int* __restrict__ meta)
{
    int idx = blockIdx.x * 256 + threadIdx.x;
    int m   = idx >> 16;
    int loc = idx & 65535;
    int j = loc >> 8, k = loc & 255;
    int mt = m >> 2, t = m & 3;
    const void* W = (mt == 0) ? Wk : (mt == 1) ? Wq : (mt == 2) ? Wv : Wa;
    int flag = meta[31 + mt];
    WT[idx] = f2us(ldf(W, t * 65536 + k * 256 + j, flag));
}

// ---- rel-table prep for MFMA path: hi/lo bf16 split; RMT transposed ----
// RAT[r][h][d][e] = rel_att[r][h][d][e]   (B layout [outcol=d][k=e])
// RMT[r][h][e][d] = rel_msg[r][h][d][e]   (B layout [outcol=e][k=d])
__global__ void k_transR(const void* __restrict__ rel_att, const void* __restrict__ rel_msg,
                         unsigned short* __restrict__ RATh, unsigned short* __restrict__ RATl,
                         unsigned short* __restrict__ RMTh, unsigned short* __restrict__ RMTl,
                         const int* __restrict__ meta)
{
    int idx = blockIdx.x * 256 + threadIdx.x;       // 0..65535
    int fra = meta[39], frm = meta[40];
    float wa = ldf(rel_att, idx, fra);
    unsigned short ha = f2us(wa);
    RATh[idx] = ha;
    RATl[idx] = f2us(wa - us2f(ha));
    int quad = idx >> 10, loc = idx & 1023, d = loc >> 5, e = loc & 31;
    float wm = ldf(rel_msg, quad * 1024 + d * 32 + e, frm);
    unsigned short hm = f2us(wm);
    int oidx = quad * 1024 + e * 32 + d;
    RMTh[oidx] = hm;
    RMTl[oidx] = f2us(wm - us2f(hm));
}

// ---- batched qt GEMM (B-reuse, bf16 out): qt[node-c0][r*256 + h*32 + d] =
//      sum_e q[node][h*32+e] * rel_att[r][h][d][e]  (hi/lo bf16 B)
//      wave w covers r in {2w,2w+1} x all 64 rows (4 tiles) ----
__global__ __launch_bounds__(256) void k_relq(
    const unsigned short* __restrict__ Ain,
    const unsigned short* __restrict__ Bhi, const unsigned short* __restrict__ Blo,
    unsigned short* __restrict__ outF, int c0, int cend)
{
    int base = c0 + blockIdx.x * 64;
    __shared__ __align__(16) unsigned short As[64 * 264];
    int tid = threadIdx.x;
    #pragma unroll
    for (int c = 0; c < 8; c++){
        int G = c * 256 + tid;            // granule of 8 halfs
        int row = G >> 5, g = G & 31;
        int node = base + row;
        uint4 v;
        if (node < cend) v = *reinterpret_cast<const uint4*>(Ain + (size_t)node * 256 + g * 8);
        else { v.x = v.y = v.z = v.w = 0u; }
        *reinterpret_cast<uint4*>(&As[row * 264 + g * 8]) = v;
    }
    __syncthreads();
    int wave = tid >> 6, lane = tid & 63;
    int m16 = lane & 15, quad = lane >> 4;

    #pragma unroll
    for (int rr = 0; rr < 2; rr++){
        int r = (wave << 1) + rr;
        #pragma unroll
        for (int h = 0; h < 8; h++){
            bf16x8 af[4];
            #pragma unroll
            for (int t = 0; t < 4; t++)
                af[t] = *reinterpret_cast<const bf16x8*>(&As[(t * 16 + m16) * 264 + h * 32 + quad * 8]);
            #pragma unroll
            for (int ct = 0; ct < 2; ct++){
                int bix = (((r * 8 + h) * 32) + ct * 16 + m16) * 32 + quad * 8;
                bf16x8 bh = *reinterpret_cast<const bf16x8*>(Bhi + bix);
                bf16x8 bl = *reinterpret_cast<const bf16x8*>(Blo + bix);
                floatx4 acr[4] = {};
                #pragma unroll
                for (int t = 0; t < 4; t++)
                    acr[t] = __builtin_amdgcn_mfma_f32_16x16x32_bf16(af[t], bl, acr[t], 0, 0, 0);
                #pragma unroll
                for (int t = 0; t < 4; t++)
                    acr[t] = __builtin_amdgcn_mfma_f32_16x16x32_bf16(af[t], bh, acr[t], 0, 0, 0);
                int colb = r * 256 + h * 32 + ct * 16 + m16;
                #pragma unroll
                for (int t = 0; t < 4; t++){
                    #pragma unroll
                    for (int reg = 0; reg < 4; reg++){
                        int node = base + t * 16 + quad * 4 + reg;
                        if (node < cend)
                            outF[(size_t)(node - c0) * 2048 + colb] = f2us(acr[t][reg]);
                    }
                }
            }
        }
    }
}

// ---- batched rel_msg GEMM (bf16 A, B hi/lo):
//      t[node][h*32+e] = sum_{r,d} M[node][r,h*32+d]*rel_msg[r,h,d,e]
//      wave w covers h in {2w,2w+1} x all 64 rows; acc persists across r ----
__global__ __launch_bounds__(256) void k_relmsg(
    const unsigned short* __restrict__ Mv,
    const unsigned short* __restrict__ Bhi, const unsigned short* __restrict__ Blo,
    unsigned short* __restrict__ outT, int c0, int cend)
{
    int base = c0 + blockIdx.x * 64;
    __shared__ __align__(16) unsigned short Ahi[64 * 264];
    int tid = threadIdx.x;
    int wave = tid >> 6, lane = tid & 63;
    int m16 = lane & 15, quad = lane >> 4;

    floatx4 acc[2][2][4] = {};   // [hh][ct][tile]

    for (int r = 0; r < RR; r++){
        __syncthreads();
        #pragma unroll
        for (int it = 0; it < 8; it++){
            int G = it * 256 + tid;       // granule of 8 halfs: 64 rows x 32 granules
            int row = G >> 5, g = G & 31;
            int node = base + row;
            uint4 vh;
            vh.x = vh.y = vh.z = vh.w = 0u;
            if (node < cend)
                vh = *reinterpret_cast<const uint4*>(Mv + (size_t)(node - c0) * 2048 + r * 256 + g * 8);
            *reinterpret_cast<uint4*>(&Ahi[row * 264 + g * 8]) = vh;
        }
        __syncthreads();
        #pragma unroll
        for (int hh = 0; hh < 2; hh++){
            int h = (wave << 1) + hh;
            bf16x8 ah[4];
            #pragma unroll
            for (int t = 0; t < 4; t++)
                ah[t] = *reinterpret_cast<const bf16x8*>(&Ahi[(t * 16 + m16) * 264 + h * 32 + quad * 8]);
            #pragma unroll
            for (int ct = 0; ct < 2; ct++){
                int bix = (((r * 8 + h) * 32) + ct * 16 + m16) * 32 + quad * 8;
                bf16x8 bh = *reinterpret_cast<const bf16x8*>(Bhi + bix);
                bf16x8 bl = *reinterpret_cast<const bf16x8*>(Blo + bix);
                #pragma unroll
                for (int t = 0; t < 4; t++){
                    acc[hh][ct][t] = __builtin_amdgcn_mfma_f32_16x16x32_bf16(ah[t], bh, acc[hh][ct][t], 0, 0, 0);
                    acc[hh][ct][t] = __builtin_amdgcn_mfma_f32_16x16x32_bf16(ah[t], bl, acc[hh][ct][t], 0, 0, 0);
                }
            }
        }
    }
    #pragma unroll
    for (int hh = 0; hh < 2; hh++){
        int h = (wave << 1) + hh;
        #pragma unroll
        for (int ct = 0; ct < 2; ct++){
            #pragma unroll
            for (int t = 0; t < 4; t++){
                #pragma unroll
                for (int reg = 0; reg < 4; reg++){
                    int node = base + t * 16 + quad * 4 + reg;
                    if (node < cend)
                        outT[(size_t)node * 256 + h * 32 + ct * 16 + m16] = f2us(acc[hh][ct][t][reg]);
                }
            }
        }
    }
}

// ---- CSR build ----
__global__ void k_zero(int* a, int n){
    int i = blockIdx.x * 256 + threadIdx.x;
    if (i < n) a[i] = 0;
}
__global__ void k_deg(const int* p2, const int* p3, const int* p4,
                      int* __restrict__ cnt, const int* __restrict__ meta, int E, int n){
    const int* dst = sel3(p2, p3, p4, meta[26]);
    int e = blockIdx.x * 256 + threadIdx.x;
    if (e < E){
        int d = dst[e];
        if (d >= 0 && d < n) atomicAdd(&cnt[d], 1);
    }
}
__global__ void k_scan1(const int* __restrict__ cnt, int* __restrict__ rowp,
                        int* __restrict__ bsum, int n){
    __shared__ int s[256];
    int b = blockIdx.x, tid = threadIdx.x;
    int i = b * 256 + tid;
    int v = (i < n) ? cnt[i] : 0;
    s[tid] = v;
    __syncthreads();
    for (int d = 1; d < 256; d <<= 1){
        int add = (tid >= d) ? s[tid - d] : 0;
        __syncthreads();
        s[tid] += add;
        __syncthreads();
    }
    if (i < n) rowp[i] = s[tid] - v;
    if (tid == 255) bsum[b] = s[255];
}
__global__ void k_scan2(int* bsum, int* rowp, int nb, int n){
    if (threadIdx.x == 0){
        int run = 0;
        for (int b = 0; b < nb; b++){ int t = bsum[b]; bsum[b] = run; run += t; }
        rowp[n] = run;
    }
}
__global__ void k_scan3(int* rowp, const int* __restrict__ bsum, int n){
    int i = blockIdx.x * 256 + threadIdx.x;
    if (i < n) rowp[i] += bsum[i >> 8];
}
__global__ void k_escat(const int* p2, const int* p3, const int* p4,
                        int* __restrict__ cur, const int* __restrict__ rowp,
                        int* __restrict__ eix, const int* __restrict__ meta, int E, int n){
    const int* dst = sel3(p2, p3, p4, meta[26]);
    int e = blockIdx.x * 256 + threadIdx.x;
    if (e < E){
        int d = dst[e];
        if (d >= 0 && d < n){
            int pos = atomicAdd(&cur[d], 1);
            eix[rowp[d] + pos] = e;
        }
    }
}

// ---- MFMA typed GEMM: QKV (validated r3, fp32-in adapted) ----
__global__ __launch_bounds__(256) void k_gemm_qkv(
    const void* __restrict__ Xv,
    const int* __restrict__ perm, const int* __restrict__ meta,
    const unsigned short* __restrict__ WT,
    const void* __restrict__ bk, const void* __restrict__ bq, const void* __restrict__ bv,
    unsigned short* __restrict__ kb, unsigned short* __restrict__ qb,
    unsigned short* __restrict__ vb)
{
    int rt = blockIdx.x;
    if (rt >= meta[12]) return;
    int fx = meta[30];
    int t = 0;
    while (t < TT - 1 && rt >= meta[8 + t + 1]) t++;
    int lt = rt - meta[8 + t];
    int rowStart = meta[4 + t] + (lt << 6);
    int rowEnd   = meta[4 + t] + meta[t];

    int ct = blockIdx.y;          // 0..5
    int mt = ct >> 1;             // 0=k 1=q 2=v
    int c0 = (ct & 1) * 128;
    const unsigned short* Wm = WT + (((mt << 2) + t) << 16);
    const void* bias = (mt == 0) ? bk : (mt == 1) ? bq : bv;
    int fb = meta[35 + mt];
    unsigned short* outb = (mt == 0) ? kb : (mt == 1) ? qb : vb;

    __shared__ __align__(16) unsigned short As[64 * 32];
    __shared__ __align__(16) unsigned short Bs[128 * 32];
    __shared__ int nodeIdx[64];

    int tid = threadIdx.x;
    if (tid < 64){
        int p = rowStart + tid;
        nodeIdx[tid] = perm[(p < rowEnd) ? p : (rowEnd - 1)];
    }
    __syncthreads();

    int wave = tid >> 6, lane = tid & 63;
    int wr = (wave >> 1) * 32;
    int wc = (wave & 1) * 64;
    int m16 = lane & 15, quad = lane >> 4;

    int arow = tid & 63, aseg = tid >> 6;
    int anode = nodeIdx[arow];

    floatx4 acc[2][4] = {};

    for (int k0 = 0; k0 < 256; k0 += 32){
        __syncthreads();
        uint4 av;
        if (fx){
            const float* af = (const float*)Xv + anode * 256 + aseg * 8 + k0;
            float4 f0 = *reinterpret_cast<const float4*>(af);
            float4 f1 = *reinterpret_cast<const float4*>(af + 4);
            av.x = (unsigned)f2us(f0.x) | ((unsigned)f2us(f0.y) << 16);
            av.y = (unsigned)f2us(f0.z) | ((unsigned)f2us(f0.w) << 16);
            av.z = (unsigned)f2us(f1.x) | ((unsigned)f2us(f1.y) << 16);
            av.w = (unsigned)f2us(f1.z) | ((unsigned)f2us(f1.w) << 16);
        } else {
            av = *reinterpret_cast<const uint4*>((const unsigned short*)Xv + anode * 256 + aseg * 8 + k0);
        }
        *reinterpret_cast<uint4*>(&As[sw32(arow, aseg)]) = av;
        #pragma unroll
        for (int it = 0; it < 2; it++){
            int idx2 = tid + it * 256;
            int cc = idx2 >> 2, g = idx2 & 3;
            uint4 bv4 = *reinterpret_cast<const uint4*>(Wm + (c0 + cc) * 256 + k0 + g * 8);
            *reinterpret_cast<uint4*>(&Bs[sw32(cc, g)]) = bv4;
        }
        __syncthreads();
        bf16x8 a[2], b[4];
        #pragma unroll
        for (int r = 0; r < 2; r++)
            a[r] = *reinterpret_cast<const bf16x8*>(&As[sw32(wr + r * 16 + m16, quad)]);
        #pragma unroll
        for (int c = 0; c < 4; c++)
            b[c] = *reinterpret_cast<const bf16x8*>(&Bs[sw32(wc + c * 16 + m16, quad)]);
        #pragma unroll
        for (int r = 0; r < 2; r++)
            #pragma unroll
            for (int c = 0; c < 4; c++)
                acc[r][c] = __builtin_amdgcn_mfma_f32_16x16x32_bf16(a[r], b[c], acc[r][c], 0, 0, 0);
    }

    #pragma unroll
    for (int r = 0; r < 2; r++){
        #pragma unroll
        for (int reg = 0; reg < 4; reg++){
            int row = wr + r * 16 + quad * 4 + reg;
            if (rowStart + row < rowEnd){
                int node = nodeIdx[row];
                #pragma unroll
                for (int c = 0; c < 4; c++){
                    int gc = c0 + wc + c * 16 + m16;
                    float v = acc[r][c][reg] + ldf(bias, t * 256 + gc, fb);
                    outb[node * 256 + gc] = f2us(v);
                }
            }
        }
    }
}

// ---- MFMA typed GEMM: output projection + skip gate (fp32 out) ----
__global__ __launch_bounds__(256) void k_gemm_out(
    const unsigned short* __restrict__ A,
    const void* __restrict__ Xv,
    const int* __restrict__ perm, const int* __restrict__ meta,
    const unsigned short* __restrict__ WTa,
    const void* __restrict__ ba, const void* __restrict__ skipv,
    float* __restrict__ out)
{
    int rt = blockIdx.x;
    if (rt >= meta[12]) return;
    int fx = meta[30], fba = meta[38], fsk = meta[42];
    int t = 0;
    while (t < TT - 1 && rt >= meta[8 + t + 1]) t++;
    int lt = rt - meta[8 + t];
    int rowStart = meta[4 + t] + (lt << 6);
    int rowEnd   = meta[4 + t] + meta[t];
    int c0 = blockIdx.y * 128;
    const unsigned short* Wm = WTa + (t << 16);
    float sg = ldf(skipv, t, fsk);
    float ag = 1.f / (1.f + __expf(-sg));

    __shared__ __align__(16) unsigned short As[64 * 32];
    __shared__ __align__(16) unsigned short Bs[128 * 32];
    __shared__ int nodeIdx[64];

    int tid = threadIdx.x;
    if (tid < 64){
        int p = rowStart + tid;
        nodeIdx[tid] = perm[(p < rowEnd) ? p : (rowEnd - 1)];
    }
    __syncthreads();

    int wave = tid >> 6, lane = tid & 63;
    int wr = (wave >> 1) * 32;
    int wc = (wave & 1) * 64;
    int m16 = lane & 15, quad = lane >> 4;

    int arow = tid & 63, aseg = tid >> 6;
    int anode = nodeIdx[arow];
    const unsigned short* aptr = A + anode * 256 + aseg * 8;

    floatx4 acc[2][4] = {};

    for (int k0 = 0; k0 < 256; k0 += 32){
        __syncthreads();
        uint4 av = *reinterpret_cast<const uint4*>(aptr + k0);
        *reinterpret_cast<uint4*>(&As[sw32(arow, aseg)]) = av;
        #pragma unroll
        for (int it = 0; it < 2; it++){
            int idx2 = tid + it * 256;
            int cc = idx2 >> 2, g = idx2 & 3;
            uint4 bv4 = *reinterpret_cast<const uint4*>(Wm + (c0 + cc) * 256 + k0 + g * 8);
            *reinterpret_cast<uint4*>(&Bs[sw32(cc, g)]) = bv4;
        }
        __syncthreads();
        bf16x8 a[2], b[4];
        #pragma unroll
        for (int r = 0; r < 2; r++)
            a[r] = *reinterpret_cast<const bf16x8*>(&As[sw32(wr + r * 16 + m16, quad)]);
        #pragma unroll
        for (int c = 0; c < 4; c++)
            b[c] = *reinterpret_cast<const bf16x8*>(&Bs[sw32(wc + c * 16 + m16, quad)]);
        #pragma unroll
        for (int r = 0; r < 2; r++)
            #pragma unroll
            for (int c = 0; c < 4; c++)
                acc[r][c] = __builtin_amdgcn_mfma_f32_16x16x32_bf16(a[r], b[c], acc[r][c], 0, 0, 0);
    }

    #pragma unroll
    for (int r = 0; r < 2; r++){
        #pragma unroll
        for (int reg = 0; reg < 4; reg++){
            int row = wr + r * 16 + quad * 4 + reg;
            if (rowStart + row < rowEnd){
                int node = nodeIdx[row];
                #pragma unroll
                for (int c = 0; c < 4; c++){
                    int gc = c0 + wc + c * 16 + m16;
                    float v = acc[r][c][reg] + ldf(ba, t * 256 + gc, fba);
                    float xv = ldf(Xv, node * 256 + gc, fx);
                    out[node * 256 + gc] = v * ag + xv * (1.f - ag);
                }
            }
        }
    }
}

// ---- VALU fallback projections (validated r7) ----
__global__ __launch_bounds__(256) void k_proj(
    const void* __restrict__ X, const int* __restrict__ nt,
    const void* __restrict__ Wk, const void* __restrict__ Wq, const void* __restrict__ Wv,
    const void* __restrict__ bk, const void* __restrict__ bq, const void* __restrict__ bv,
    unsigned short* __restrict__ kb, unsigned short* __restrict__ qtb,
    unsigned short* __restrict__ vb,
    const int* __restrict__ meta, int n)
{
    int i = blockIdx.x, tid = threadIdx.x;
    int fx = meta[30];
    int t = nt[i] & 3;
    __shared__ float xs[256];
    __shared__ float red[3][4][256];
    xs[tid] = ldf(X, i * 256 + tid, fx);
    __syncthreads();
    int seg = tid >> 6;
    int cg  = (tid & 63) * 4;
    int base = t * 65536 + cg;
    #pragma unroll
    for (int m = 0; m < 3; m++){
        const void* W = (m == 0) ? Wk : (m == 1) ? Wq : Wv;
        int fw = meta[31 + m];
        float ax = 0.f, ay = 0.f, az = 0.f, aw = 0.f;
        for (int k = seg * 64; k < seg * 64 + 64; k++){
            float xv = xs[k];
            float4 w = ldf4(W, base + k * 256, fw);
            ax += xv * w.x; ay += xv * w.y; az += xv * w.z; aw += xv * w.w;
        }
        float4 st = {ax, ay, az, aw};
        *reinterpret_cast<float4*>(&red[m][seg][cg]) = st;
    }
    __syncthreads();
    #pragma unroll
    for (int m = 0; m < 3; m++){
        const void* B = (m == 0) ? bk : (m == 1) ? bq : bv;
        unsigned short* O = (m == 0) ? kb : (m == 1) ? qtb : vb;
        float v = red[m][0][tid] + red[m][1][tid] + red[m][2][tid] + red[m][3][tid]
                + ldf(B, t * 256 + tid, meta[35 + m]);
        O[i * 256 + tid] = f2us(v);
    }
}
__global__ __launch_bounds__(256) void k_out(
    const unsigned short* __restrict__ tb,
    const void* __restrict__ X, const int* __restrict__ nt,
    const void* __restrict__ Wa, const void* __restrict__ ba,
    const void* __restrict__ skipv,
    float* __restrict__ out,
    const int* __restrict__ meta, int n)
{
    int i = blockIdx.x, tid = threadIdx.x;
    int fx = meta[30], fwa = meta[34], fba = meta[38], fsk = meta[42];
    int t = nt[i] & 3;
    __shared__ float xs[256];
    __shared__ float red[4][256];
    xs[tid] = us2f(tb[i * 256 + tid]);
    __syncthreads();
    int seg = tid >> 6;
    int cg  = (tid & 63) * 4;
    int base = t * 65536 + cg;
    float ax = 0.f, ay = 0.f, az = 0.f, aw = 0.f;
    for (int k = seg * 64; k < seg * 64 + 64; k++){
        float xv = xs[k];
        float4 w = ldf4(Wa, base + k * 256, fwa);
        ax += xv * w.x; ay += xv * w.y; az += xv * w.z; aw += xv * w.w;
    }
    float4 st = {ax, ay, az, aw};
    *reinterpret_cast<float4*>(&red[seg][cg]) = st;
    __syncthreads();
    float v = red[0][tid] + red[1][tid] + red[2][tid] + red[3][tid]
            + ldf(ba, t * 256 + tid, fba);
    float sg = ldf(skipv, t, fsk);
    float a  = 1.f / (1.f + __expf(-sg));
    float xv = ldf(X, i * 256 + tid, fx);
    out[i * 256 + tid] = v * a + xv * (1.f - a);
}

// ---- node attention + messages (fallback path, validated) ----
__global__ __launch_bounds__(256) void k_node2(
    unsigned short* qtb,
    const unsigned short* __restrict__ kb, const unsigned short* __restrict__ vb,
    const int* p2, const int* p3, const int* p4,
    const int* __restrict__ rowp, const int* __restrict__ eix,
    const void* __restrict__ rel_att, const void* __restrict__ rel_msg,
    const void* __restrict__ rel_pri,
    const int* __restrict__ meta, int n)
{
    const int* srcv = sel3(p2, p3, p4, meta[25]);
    const int* etv  = sel3(p2, p3, p4, meta[27]);
    int fra = meta[39], frm = meta[40], fpri = meta[41];
    int i = blockIdx.x, tid = threadIdx.x;
    int h5 = tid >> 5, z = tid & 31;

    __shared__ float qs[256];
    __shared__ float qA[RR * NH * 33];
    __shared__ float msum[RR][256];
    __shared__ float attS[16][NH];
    __shared__ float wnew[16][NH];
    __shared__ float mcur[RR][NH], dcur[RR][NH], scf[RR][NH];
    __shared__ int s_src[16], s_et[16];
    __shared__ float s_pri[RR * NH];
    __shared__ int s_mask;

    int e0 = rowp[i], deg = rowp[i + 1] - e0;

    if (tid < RR * NH) s_pri[tid] = ldf(rel_pri, tid, fpri);
    if (tid == 0) s_mask = 0;
    qs[tid] = us2f(qtb[i * 256 + tid]);
    #pragma unroll
    for (int r = 0; r < RR; r++) msum[r][tid] = 0.f;
    if (tid < RR * NH){ mcur[tid >> 3][tid & 7] = -1e30f; dcur[tid >> 3][tid & 7] = 0.f; }
    __syncthreads();

    {
        const float* qq = &qs[h5 * 32];
        #pragma unroll
        for (int r = 0; r < RR; r++){
            int base = (r * NH + h5) * 1024 + z * 32;
            float a0 = 0.f;
            #pragma unroll
            for (int e4 = 0; e4 < 8; e4++){
                float4 w = ldf4(rel_att, base + e4 * 4, fra);
                const float* q4 = qq + e4 * 4;
                a0 += w.x * q4[0] + w.y * q4[1] + w.z * q4[2] + w.w * q4[3];
            }
            qA[(r * NH + h5) * 33 + z] = a0;
        }
    }
    __syncthreads();

    for (int done = 0; done < deg; done += 16){
        int cs = min(16, deg - done);
        if (tid < cs){
            int e = eix[e0 + done + tid];
            int sj = srcv[e]; sj = (sj < 0) ? 0 : (sj >= n) ? n - 1 : sj;
            s_src[tid] = sj;
            int rr = etv[e] & 7;
            s_et[tid] = rr;
            atomicOr(&s_mask, 1 << rr);
        }
        __syncthreads();
        {
            int j = tid >> 4, hh = (tid >> 1) & 7, half = tid & 1;
            float pt = 0.f;
            if (j < cs){
                int sj = s_src[j], rj = s_et[j];
                const unsigned short* kp = kb + sj * 256 + hh * 32 + half * 16;
                const float* qa = &qA[(rj * NH + hh) * 33 + half * 16];
                uint4 u0 = *reinterpret_cast<const uint4*>(kp);
                uint4 u1 = *reinterpret_cast<const uint4*>(kp + 8);
                pt = lo2f(u0.x) * qa[0]  + hi2f(u0.x) * qa[1]
                   + lo2f(u0.y) * qa[2]  + hi2f(u0.y) * qa[3]
                   + lo2f(u0.z) * qa[4]  + hi2f(u0.z) * qa[5]
                   + lo2f(u0.w) * qa[6]  + hi2f(u0.w) * qa[7]
                   + lo2f(u1.x) * qa[8]  + hi2f(u1.x) * qa[9]
                   + lo2f(u1.y) * qa[10] + hi2f(u1.y) * qa[11]
                   + lo2f(u1.z) * qa[12] + hi2f(u1.z) * qa[13]
                   + lo2f(u1.w) * qa[14] + hi2f(u1.w) * qa[15];
            }
            pt += __shfl_xor(pt, 1);
            if (j < cs && half == 0)
                attS[j][hh] = pt * s_pri[s_et[j] * NH + hh] * 0.17677669529663687f;
        }
        __syncthreads();
        if (tid < RR * NH){
            int r = tid >> 3, hh = tid & 7;
            float m_old = mcur[r][hh];
            float m_new = m_old;
            for (int j = 0; j < cs; j++) if (s_et[j] == r) m_new = fmaxf(m_new, attS[j][hh]);
            float scale = __expf(m_old - m_new);
            float den = dcur[r][hh] * scale;
            for (int j = 0; j < cs; j++) if (s_et[j] == r) den += __expf(attS[j][hh] - m_new);
            mcur[r][hh] = m_new; dcur[r][hh] = den; scf[r][hh] = scale;
        }
        __syncthreads();
        #pragma unroll
        for (int r = 0; r < RR; r++) msum[r][tid] *= scf[r][h5];
        if (tid < cs * NH){
            int j = tid >> 3, hh = tid & 7;
            wnew[j][hh] = __expf(attS[j][hh] - mcur[s_et[j]][hh]);
        }
        __syncthreads();
        {
            float vvf[16];
            #pragma unroll
            for (int j = 0; j < 16; j++)
                if (j < cs) vvf[j] = us2f(vb[s_src[j] * 256 + tid]);
            for (int j = 0; j < cs; j++)
                msum[s_et[j]][tid] += wnew[j][h5] * vvf[j];
        }
        __syncthreads();
    }

    int mask = s_mask;
    #pragma unroll
    for (int r = 0; r < RR; r++){
        if ((mask >> r) & 1) msum[r][tid] /= dcur[r][h5];
    }
    __syncthreads();

    float tacc = 0.f;
    for (int r = 0; r < RR; r++){
        if (!((mask >> r) & 1)) continue;
        const float* ms = &msum[r][h5 * 32];
        int base = (r * NH + h5) * 1024 + z;
        float a0 = 0.f;
        #pragma unroll
        for (int c = 0; c < 32; c++)
            a0 += ms[c] * ldf(rel_msg, base + c * 32, frm);
        tacc += a0;
    }
    int np = __popc(mask); if (np == 0) np = 1;
    qtb[i * 256 + tid] = f2us(tacc / (float)np);
}

// ---- node attention using precomputed qt (bf16 chunk rows, 4 KB/node);
//      writes per-r aggregate M (single bf16 plane) in place of the qt row ----
__global__ __launch_bounds__(256) void k_node4(
    const unsigned short* __restrict__ kb,
    const unsigned short* __restrict__ vb,
    unsigned short* __restrict__ qtM,
    const int* p2, const int* p3, const int* p4,
    const int* __restrict__ rowp, const int* __restrict__ eix,
    const void* __restrict__ rel_pri,
    const int* __restrict__ meta, int n, int c0)
{
    const int* srcv = sel3(p2, p3, p4, meta[25]);
    const int* etv  = sel3(p2, p3, p4, meta[27]);
    int fpri = meta[41];
    int i = c0 + blockIdx.x, tid = threadIdx.x;
    int h5 = tid >> 5;

    __shared__ float qA[RR * NH * 33];
    __shared__ float attS[16][NH];
    __shared__ float wnew[16][NH];
    __shared__ float mcur[RR][NH], dcur[RR][NH], scf[RR][NH];
    __shared__ int s_src[16], s_et[16];
    __shared__ float s_pri[RR * NH];
    __shared__ int s_mask;

    int e0 = rowp[i], deg = rowp[i + 1] - e0;

    if (tid < RR * NH) s_pri[tid] = ldf(rel_pri, tid, fpri);
    if (tid == 0) s_mask = 0;
    // stage this node's qt row (bf16, 4 KB) into LDS as f32, [r][h][33] layout
    {
        const unsigned short* qp = qtM + (size_t)blockIdx.x * 2048;
        uint4 v = *reinterpret_cast<const uint4*>(qp + tid * 8);   // 8 halfs/thread
        int r = tid >> 5, h = (tid >> 2) & 7, dd = (tid & 3) * 8;
        float* dst = &qA[(r * NH + h) * 33 + dd];
        dst[0] = lo2f(v.x); dst[1] = hi2f(v.x);
        dst[2] = lo2f(v.y); dst[3] = hi2f(v.y);
        dst[4] = lo2f(v.z); dst[5] = hi2f(v.z);
        dst[6] = lo2f(v.w); dst[7] = hi2f(v.w);
    }
    float racc[RR];
    #pragma unroll
    for (int r = 0; r < RR; r++) racc[r] = 0.f;
    if (tid < RR * NH){ mcur[tid >> 3][tid & 7] = -1e30f; dcur[tid >> 3][tid & 7] = 0.f; }
    __syncthreads();

    for (int done = 0; done < deg; done += 16){
        int cs = min(16, deg - done);
        if (tid < cs){
            int e = eix[e0 + done + tid];
            int sj = srcv[e]; sj = (sj < 0) ? 0 : (sj >= n) ? n - 1 : sj;
            s_src[tid] = sj;
            int rr = etv[e] & 7;
            s_et[tid] = rr;
            atomicOr(&s_mask, 1 << rr);
        }
        __syncthreads();
        // issue v gathers early: latency hides under dots + softmax
        float vvf[16];
        #pragma unroll
        for (int j = 0; j < 16; j++){
            vvf[j] = (j < cs) ? us2f(vb[(size_t)s_src[j] * 256 + tid]) : 0.f;
        }
        // attention dots: (j, h, half) parallel across 256 threads
        {
            int j = tid >> 4, hh = (tid >> 1) & 7, half = tid & 1;
            float pt = 0.f;
            if (j < cs){
                int sj = s_src[j], rj = s_et[j];
                const unsigned short* kp = kb + (size_t)sj * 256 + hh * 32 + half * 16;
                const float* qa = &qA[(rj * NH + hh) * 33 + half * 16];
                uint4 u0 = *reinterpret_cast<const uint4*>(kp);
                uint4 u1 = *reinterpret_cast<const uint4*>(kp + 8);
                pt = lo2f(u0.x) * qa[0]  + hi2f(u0.x) * qa[1]
                   + lo2f(u0.y) * qa[2]  + hi2f(u0.y) * qa[3]
                   + lo2f(u0.z) * qa[4]  + hi2f(u0.z) * qa[5]
                   + lo2f(u0.w) * qa[6]  + hi2f(u0.w) * qa[7]
                   + lo2f(u1.x) * qa[8]  + hi2f(u1.x) * qa[9]
                   + lo2f(u1.y) * qa[10] + hi2f(u1.y) * qa[11]
                   + lo2f(u1.z) * qa[12] + hi2f(u1.z) * qa[13]
                   + lo2f(u1.w) * qa[14] + hi2f(u1.w) * qa[15];
            }
            pt += __shfl_xor(pt, 1);
            if (j < cs && half == 0)
                attS[j][hh] = pt * s_pri[s_et[j] * NH + hh] * 0.17677669529663687f;
        }
        __syncthreads();
        if (tid < RR * NH){
            int r = tid >> 3, hh = tid & 7;
            float m_old = mcur[r][hh];
            float m_new = m_old;
            for (int j = 0; j < cs; j++) if (s_et[j] == r) m_new = fmaxf(m_new, attS[j][hh]);
            float scale = __expf(m_old - m_new);
            float den = dcur[r][hh] * scale;
            for (int j = 0; j < cs; j++) if (s_et[j] == r) den += __expf(attS[j][hh] - m_new);
            mcur[r][hh] = m_new; dcur[r][hh] = den; scf[r][hh] = scale;
        }
        __syncthreads();
        #pragma unroll
        for (int r = 0; r < RR; r++) racc[r] *= scf[r][h5];
        if (tid < cs * NH){
            int j = tid >> 3, hh = tid & 7;
            wnew[j][hh] = __expf(attS[j][hh] - mcur[s_et[j]][hh]);
        }
        __syncthreads();
        // register accumulation: branchless select over r
        #pragma unroll
        for (int j = 0; j < 16; j++){
            if (j < cs){
                float w = wnew[j][h5] * vvf[j];
                int et = s_et[j];
                #pragma unroll
                for (int r = 0; r < RR; r++)
                    racc[r] += (et == r) ? w : 0.f;
            }
        }
        __syncthreads();
    }

    int mask = s_mask;
    int np = __popc(mask); if (np == 0) np = 1;
    float inv = 1.f / (float)np;
    // overwrite qt row with M = msum/den/np as one bf16 plane (row-local, safe)
    unsigned short* Mp = qtM + (size_t)blockIdx.x * 2048;
    #pragma unroll
    for (int r = 0; r < RR; r++){
        float mv = 0.f;
        if ((mask >> r) & 1) mv = racc[r] / dcur[r][h5] * inv;
        Mp[r * 256 + tid] = f2us(mv);
    }
}

extern "C" void kernel_launch(void* const* d_in, const int* in_sizes, int n_in,
                              void* d_out, int out_size, void* d_ws, size_t ws_size,
                              hipStream_t stream)
{
    const void* x        = d_in[0];
    const int* node_type = (const int*)d_in[1];
    const int* p2        = (const int*)d_in[2];
    const int* p3        = (const int*)d_in[3];
    const int* p4        = (const int*)d_in[4];
    const void* Wk = d_in[5];  const void* bk = d_in[6];
    const void* Wq = d_in[7];  const void* bq = d_in[8];
    const void* Wv = d_in[9];  const void* bv = d_in[10];
    const void* Wa = d_in[11]; const void* ba = d_in[12];
    const void* rel_att = d_in[13];
    const void* rel_msg = d_in[14];
    const void* rel_pri = d_in[15];
    const void* skipv   = d_in[16];
    float* out = (float*)d_out;

    bool ok = (n_in == 17);
    if (ok){
        ok = ok && (in_sizes[0] == in_sizes[1] * 256);
        ok = ok && (in_sizes[2] == in_sizes[3]) && (in_sizes[3] == in_sizes[4]);
        ok = ok && (in_sizes[5] == 262144) && (in_sizes[7] == 262144)
                && (in_sizes[9] == 262144) && (in_sizes[11] == 262144);
        ok = ok && (in_sizes[6] == 1024) && (in_sizes[8] == 1024)
                && (in_sizes[10] == 1024) && (in_sizes[12] == 1024);
        ok = ok && (in_sizes[13] == 65536) && (in_sizes[14] == 65536);
        ok = ok && (in_sizes[15] == 64) && (in_sizes[16] == 4);
        ok = ok && (out_size == in_sizes[0]);
    }
    if (!ok){
        k_zerofill<<<(out_size + 255) / 256, 256, 0, stream>>>(out, out_size);
        return;
    }

    int n = in_sizes[1];
    int E = in_sizes[2];
    int nb = (n + 255) / 256;
    int eb = (E + 255) / 256;

    char* ws = (char*)d_ws;
    int* meta = (int*)ws;
    size_t off = 256;
    int* cnt  = (int*)(ws + off); off += ((size_t)n * 4 + 255) & ~(size_t)255;
    int* bsum = (int*)(ws + off); off += ((size_t)nb * 4 + 255) & ~(size_t)255;
    int* rowp = (int*)(ws + off); off += ((size_t)(n + 1) * 4 + 255) & ~(size_t)255;
    int* eix  = (int*)(ws + off); off += ((size_t)E * 4 + 255) & ~(size_t)255;
    unsigned short* kb2 = (unsigned short*)(ws + off); off += (size_t)n * 256 * 2;
    unsigned short* vb2 = (unsigned short*)(ws + off); off += (size_t)n * 256 * 2;
    unsigned short* qtb = (unsigned short*)(ws + off); off += (size_t)n * 256 * 2;
    size_t off_lean = off;
    int* perm = (int*)(ws + off); off += ((size_t)n * 4 + 255) & ~(size_t)255;
    unsigned short* WT = (unsigned short*)(ws + off); off += (size_t)16 * 65536 * 2;
    size_t off_full = off;
    // ---- rel-transform tables (hi/lo bf16) + adaptive chunk buffer (bf16 rows) ----
    unsigned short* RATh = (unsigned short*)(ws + off); off += (size_t)65536 * 2;
    unsigned short* RATl = (unsigned short*)(ws + off); off += (size_t)65536 * 2;
    unsigned short* RMTh = (unsigned short*)(ws + off); off += (size_t)65536 * 2;
    unsigned short* RMTl = (unsigned short*)(ws + off); off += (size_t)65536 * 2;
    unsigned short* qtM = (unsigned short*)(ws + off);   // C * 4096 bytes
    size_t avail = (ws_size > off) ? ws_size - off : 0;
    long long Cavail = (long long)(avail / 4096);
    if (Cavail > (long long)n) Cavail = n;
    int C = 0;
    if (Cavail >= 1024){
        // target ~32K nodes/chunk (~128 MB qt+M stream) for L3 residency across
        // relq -> node4 -> relmsg; balance chunk sizes
        int target = 32768;
        int nch = (n + target - 1) / target;
        int Ceven = ((n + nch - 1) / nch + 63) & ~(int)63;
        C = (Ceven < (int)Cavail) ? Ceven : (int)Cavail;
    }

    k_flags<<<13, 256, 0, stream>>>(x, Wk, Wq, Wv, Wa, bk, bq, bv, ba,
                                    rel_att, rel_msg, rel_pri, skipv,
                                    in_sizes[0], in_sizes[5], in_sizes[7], in_sizes[9],
                                    in_sizes[11], in_sizes[6], in_sizes[8], in_sizes[10],
                                    in_sizes[12], in_sizes[13], in_sizes[14],
                                    in_sizes[15], in_sizes[16], meta);
    k_flagfix<<<1, 64, 0, stream>>>(meta);

    if (ws_size < off_lean){
        k_copy<<<(n * 256 + 255) / 256, 256, 0, stream>>>(x, out, meta, n * 256);
        return;
    }
    bool full  = (ws_size >= off_full);
    bool full2 = full && (C >= 1024);

    k_trio<<<3, 256, 0, stream>>>(p2, p3, p4, E, n, meta);
    k_pick<<<1, 64, 0, stream>>>(meta);

    // CSR
    k_zero<<<nb, 256, 0, stream>>>(cnt, n);
    k_deg<<<eb, 256, 0, stream>>>(p2, p3, p4, cnt, meta, E, n);
    k_scan1<<<nb, 256, 0, stream>>>(cnt, rowp, bsum, n);
    k_scan2<<<1, 64, 0, stream>>>(bsum, rowp, nb, n);
    k_scan3<<<nb, 256, 0, stream>>>(rowp, bsum, n);
    k_zero<<<nb, 256, 0, stream>>>(cnt, n);
    k_escat<<<eb, 256, 0, stream>>>(p2, p3, p4, cnt, rowp, eix, meta, E, n);

    if (full){
        k_init<<<1, 64, 0, stream>>>(meta);
        k_count<<<nb, 256, 0, stream>>>(node_type, meta, n);
        k_prefix<<<1, 64, 0, stream>>>(meta);
        k_scatter<<<nb, 256, 0, stream>>>(node_type, meta, perm, n);
        k_transW<<<4096, 256, 0, stream>>>(Wk, Wq, Wv, Wa, WT, meta);
        int maxRT = n / 64 + TT;
        k_gemm_qkv<<<dim3(maxRT, 6), 256, 0, stream>>>(x, perm, meta, WT, bk, bq, bv,
                                                       kb2, qtb, vb2);
        if (full2){
            k_transR<<<256, 256, 0, stream>>>(rel_att, rel_msg, RATh, RATl, RMTh, RMTl, meta);
            for (int c0 = 0; c0 < n; c0 += C){
                int cend = (c0 + C < n) ? (c0 + C) : n;
                int blk64 = (cend - c0 + 63) >> 6;
                k_relq<<<blk64, 256, 0, stream>>>(qtb, RATh, RATl, qtM, c0, cend);
                k_node4<<<cend - c0, 256, 0, stream>>>(kb2, vb2, qtM, p2, p3, p4,
                                                       rowp, eix, rel_pri, meta, n, c0);
                k_relmsg<<<blk64, 256, 0, stream>>>(qtM, RMTh, RMTl, qtb, c0, cend);
            }
        } else {
            k_node2<<<n, 256, 0, stream>>>(qtb, kb2, vb2, p2, p3, p4, rowp, eix,
                                           rel_att, rel_msg, rel_pri, meta, n);
        }
        k_gemm_out<<<dim3(maxRT, 2), 256, 0, stream>>>(qtb, x, perm, meta,
                                                       WT + 12 * 65536, ba, skipv, out);
    } else {
        k_proj<<<n, 256, 0, stream>>>(x, node_type, Wk, Wq, Wv, bk, bq, bv,
                                      kb2, qtb, vb2, meta, n);
        k_node2<<<n, 256, 0, stream>>>(qtb, kb2, vb2, p2, p3, p4, rowp, eix,
                                       rel_att, rel_msg, rel_pri, meta, n);
        k_out<<<n, 256, 0, stream>>>(qtb, x, node_type, Wa, ba, skipv, out, meta, n);
    }
}

// Round 6
// 857.728 us; speedup vs baseline: 3.3382x; 1.2832x over previous
//
#include <hip/hip_runtime.h>

#define TT 4
#define RR 8
#define NH 8
#define DKK 32

typedef float floatx4 __attribute__((ext_vector_type(4)));
typedef __bf16 bf16x8 __attribute__((ext_vector_type(8)));

__device__ __forceinline__ float us2f(unsigned short s){
    union{unsigned int u; float f;} x; x.u = ((unsigned int)s) << 16; return x.f;
}
__device__ __forceinline__ float lo2f(unsigned int u){
    union{unsigned int x; float f;} a; a.x = u << 16; return a.f;
}
__device__ __forceinline__ float hi2f(unsigned int u){
    union{unsigned int x; float f;} a; a.x = u & 0xffff0000u; return a.f;
}
__device__ __forceinline__ unsigned short f2us(float f){
    union{float f; unsigned int u;} x; x.f = f;
    unsigned int u = x.u;
    unsigned int r = (u + 0x7fffu + ((u >> 16) & 1u)) >> 16;   // RNE bf16
    return (unsigned short)r;
}
__device__ __forceinline__ float ldf(const void* p, int i, int isf32){
    return isf32 ? ((const float*)p)[i] : us2f(((const unsigned short*)p)[i]);
}
__device__ __forceinline__ float4 ldf4(const void* p, int i, int isf32){  // i % 4 == 0
    if (isf32) return *reinterpret_cast<const float4*>((const float*)p + i);
    uint2 u = *reinterpret_cast<const uint2*>((const unsigned short*)p + i);
    float4 r; r.x = lo2f(u.x); r.y = hi2f(u.x); r.z = lo2f(u.y); r.w = hi2f(u.y);
    return r;
}
__device__ __forceinline__ const int* sel3(const int* a, const int* b, const int* c, int s){
    return (s == 0) ? a : (s == 1) ? b : c;
}
__device__ __forceinline__ int sw32(int row, int g){
    return row * 32 + ((g ^ (row >> 2)) & 3) * 8;
}
__device__ __forceinline__ float dot8(uint4 u, const float* qa){
    return lo2f(u.x)*qa[0] + hi2f(u.x)*qa[1] + lo2f(u.y)*qa[2] + hi2f(u.y)*qa[3]
         + lo2f(u.z)*qa[4] + hi2f(u.z)*qa[5] + lo2f(u.w)*qa[6] + hi2f(u.w)*qa[7];
}

// ---- per-array dtype flags: meta[30+id] = 0 bf16 / 1 fp32 / -1 unknown ----
__global__ void k_flags(const void* p0, const void* p1, const void* p2, const void* p3,
                        const void* p4, const void* p5, const void* p6, const void* p7,
                        const void* p8, const void* p9, const void* p10, const void* p11,
                        const void* p12,
                        int n0, int n1, int n2, int n3, int n4, int n5, int n6, int n7,
                        int n8, int n9, int n10, int n11, int n12,
                        int* __restrict__ meta)
{
    const void* ps[13] = {p0,p1,p2,p3,p4,p5,p6,p7,p8,p9,p10,p11,p12};
    int ns[13] = {n0,n1,n2,n3,n4,n5,n6,n7,n8,n9,n10,n11,n12};
    int id = blockIdx.x;
    const unsigned short* p = (const unsigned short*)ps[id];
    int half = ns[id] >> 1;
    int nsamp = (half < 256) ? half : 256;
    int step = (nsamp > 0) ? (half / nsamp) : 1;
    int tid = threadIdx.x;
    int sane = 0, nzv = 0;
    if (tid < nsamp){
        unsigned short u = p[2 * (tid * step)];
        nzv = (u != 0);
        int e = (u >> 7) & 0xFF;
        sane = (e >= 100 && e <= 140) ? 1 : 0;
    }
    __shared__ int c_s[4], c_n[4];
    unsigned long long ms = __ballot(sane != 0);
    unsigned long long mn = __ballot(nzv != 0);
    if ((tid & 63) == 0){ c_s[tid >> 6] = (int)__popcll(ms); c_n[tid >> 6] = (int)__popcll(mn); }
    __syncthreads();
    if (tid == 0){
        int cs = c_s[0] + c_s[1] + c_s[2] + c_s[3];
        int cn = c_n[0] + c_n[1] + c_n[2] + c_n[3];
        meta[30 + id] = (cn == 0) ? -1 : ((2 * cs >= nsamp) ? 0 : 1);
    }
}
__global__ void k_flagfix(int* meta){
    if (threadIdx.x == 0 && blockIdx.x == 0){
        int xf = meta[30]; if (xf < 0) xf = 1;
        meta[30] = xf; meta[24] = xf;
        for (int j = 1; j < 13; j++) if (meta[30 + j] < 0) meta[30 + j] = xf;
    }
}

// ---- identify src/dst/etype among the three E-sized int arrays ----
__global__ void k_trio(const int* pa, const int* pb, const int* pc, int E, int n,
                       int* __restrict__ meta){
    const int* ps[3] = {pa, pb, pc};
    int c = blockIdx.x, tid = threadIdx.x;
    const int* p = ps[c];
    int step = E / 1024; if (step < 1) step = 1;
    int mx = 0, hits = 0;
    for (int j = 0; j < 4; j++){
        long long e = (long long)(tid + j * 256) * step;
        if (e < E){
            int v = p[e];
            mx = max(mx, v);
            hits += (v == (int)(e % n)) ? 1 : 0;
        }
    }
    __shared__ int smx[4], sh[4];
    for (int o = 32; o; o >>= 1){ mx = max(mx, __shfl_down(mx, o, 64)); hits += __shfl_down(hits, o, 64); }
    if ((tid & 63) == 0){ smx[tid >> 6] = mx; sh[tid >> 6] = hits; }
    __syncthreads();
    if (tid == 0){
        mx = max(max(smx[0], smx[1]), max(smx[2], smx[3]));
        hits = sh[0] + sh[1] + sh[2] + sh[3];
        meta[44 + c] = mx; meta[47 + c] = hits;
    }
}
__global__ void k_pick(int* meta){
    if (threadIdx.x == 0 && blockIdx.x == 0){
        int m0 = meta[44], m1 = meta[45], m2 = meta[46];
        int h[3] = {meta[47], meta[48], meta[49]};
        int et = (m2 < 8) ? 2 : ((m0 < 8) ? 0 : ((m1 < 8) ? 1 : 2));
        int a = -1, b = -1;
        for (int c = 0; c < 3; c++) if (c != et){ if (a < 0) a = c; else b = c; }
        int srcsel = a, dstsel = b;
        if (h[a] >= 1000 && h[b] < 1000){ dstsel = a; srcsel = b; }
        meta[25] = srcsel; meta[26] = dstsel; meta[27] = et;
    }
}

// ---- fallbacks ----
__global__ void k_zerofill(float* out, int tot){
    int i = blockIdx.x * 256 + threadIdx.x;
    if (i < tot) out[i] = 0.f;
}
__global__ void k_copy(const void* __restrict__ xv, float* __restrict__ out,
                       const int* __restrict__ meta, int tot){
    int isf32 = meta[24];
    int i = blockIdx.x * 256 + threadIdx.x;
    if (i < tot) out[i] = ldf(xv, i, isf32);
}

// ---- bucket build (validated r3) ----
__global__ void k_init(int* meta){
    if (threadIdx.x < 24) meta[threadIdx.x] = 0;
}
__global__ void k_count(const int* __restrict__ nt, int* __restrict__ meta, int n){
    int i = blockIdx.x * 256 + threadIdx.x;
    int t = (i < n) ? (nt[i] & 3) : -1;
    int lane = threadIdx.x & 63;
    #pragma unroll
    for (int tt = 0; tt < TT; tt++){
        unsigned long long m = __ballot(t == tt);
        if (m){
            int leader = __builtin_ctzll(m);
            if (lane == leader) atomicAdd(&meta[tt], (int)__popcll(m));
        }
    }
}
__global__ void k_prefix(int* meta){
    if (threadIdx.x == 0){
        int off = 0, tb = 0;
        for (int t = 0; t < TT; t++){
            int c = meta[t];
            meta[4 + t]  = off;
            meta[13 + t] = off;
            meta[8 + t]  = tb;
            off += c;
            tb  += (c + 63) >> 6;
        }
        meta[12] = tb;
    }
}
__global__ void k_scatter(const int* __restrict__ nt, int* __restrict__ meta,
                          int* __restrict__ perm, int n){
    int i = blockIdx.x * 256 + threadIdx.x;
    int t = (i < n) ? (nt[i] & 3) : -1;
    int lane = threadIdx.x & 63;
    #pragma unroll
    for (int tt = 0; tt < TT; tt++){
        unsigned long long m = __ballot(t == tt);
        if (m){
            int leader = __builtin_ctzll(m);
            int base = 0;
            if (lane == leader) base = atomicAdd(&meta[13 + tt], (int)__popcll(m));
            base = __shfl(base, leader, 64);
            if (t == tt){
                int rank = __popcll(m & ((1ull << lane) - 1ull));
                perm[base + rank] = i;
            }
        }
    }
}

// ---- weight transpose: WT[m][outcol][k] = W[m][k][outcol] ----
__global__ void k_transW(const void* __restrict__ Wk, const void* __restrict__ Wq,
                         const void* __restrict__ Wv, const void* __restrict__ Wa,
                         unsigned short* __restrict__ WT, const int* __restrict__ meta)
{
    int idx = blockIdx.x * 256 + threadIdx.x;
    int m   = idx >> 16;
    int loc = idx & 65535;
    int j = loc >> 8, k = loc & 255;
    int mt = m >> 2, t = m & 3;
    const void* W = (mt == 0) ? Wk : (mt == 1) ? Wq : (mt == 2) ? Wv : Wa;
    int flag = meta[31 + mt];
    WT[idx] = f2us(ldf(W, t * 65536 + k * 256 + j, flag));
}

// ---- rel-table prep for MFMA path: hi/lo bf16 split; RMT transposed ----
// RAT[r][h][d][e] = rel_att[r][h][d][e]   (B layout [outcol=d][k=e])
// RMT[r][h][e][d] = rel_msg[r][h][d][e]   (B layout [outcol=e][k=d])
__global__ void k_transR(const void* __restrict__ rel_att, const void* __restrict__ rel_msg,
                         unsigned short* __restrict__ RATh, unsigned short* __restrict__ RATl,
                         unsigned short* __restrict__ RMTh, unsigned short* __restrict__ RMTl,
                         const int* __restrict__ meta)
{
    int idx = blockIdx.x * 256 + threadIdx.x;       // 0..65535
    int fra = meta[39], frm = meta[40];
    float wa = ldf(rel_att, idx, fra);
    unsigned short ha = f2us(wa);
    RATh[idx] = ha;
    RATl[idx] = f2us(wa - us2f(ha));
    int quad = idx >> 10, loc = idx & 1023, d = loc >> 5, e = loc & 31;
    float wm = ldf(rel_msg, quad * 1024 + d * 32 + e, frm);
    unsigned short hm = f2us(wm);
    int oidx = quad * 1024 + e * 32 + d;
    RMTh[oidx] = hm;
    RMTl[oidx] = f2us(wm - us2f(hm));
}

// ---- batched qt GEMM (B-reuse, bf16 out): qt[node-c0][r*256 + h*32 + d] =
//      sum_e q[node][h*32+e] * rel_att[r][h][d][e]  (hi/lo bf16 B)
//      wave w covers r in {2w,2w+1} x all 64 rows (4 tiles) ----
__global__ __launch_bounds__(256) void k_relq(
    const unsigned short* __restrict__ Ain,
    const unsigned short* __restrict__ Bhi, const unsigned short* __restrict__ Blo,
    unsigned short* __restrict__ outF, int c0, int cend)
{
    int base = c0 + blockIdx.x * 64;
    __shared__ __align__(16) unsigned short As[64 * 264];
    int tid = threadIdx.x;
    #pragma unroll
    for (int c = 0; c < 8; c++){
        int G = c * 256 + tid;            // granule of 8 halfs
        int row = G >> 5, g = G & 31;
        int node = base + row;
        uint4 v;
        if (node < cend) v = *reinterpret_cast<const uint4*>(Ain + (size_t)node * 256 + g * 8);
        else { v.x = v.y = v.z = v.w = 0u; }
        *reinterpret_cast<uint4*>(&As[row * 264 + g * 8]) = v;
    }
    __syncthreads();
    int wave = tid >> 6, lane = tid & 63;
    int m16 = lane & 15, quad = lane >> 4;

    #pragma unroll
    for (int rr = 0; rr < 2; rr++){
        int r = (wave << 1) + rr;
        #pragma unroll
        for (int h = 0; h < 8; h++){
            bf16x8 af[4];
            #pragma unroll
            for (int t = 0; t < 4; t++)
                af[t] = *reinterpret_cast<const bf16x8*>(&As[(t * 16 + m16) * 264 + h * 32 + quad * 8]);
            #pragma unroll
            for (int ct = 0; ct < 2; ct++){
                int bix = (((r * 8 + h) * 32) + ct * 16 + m16) * 32 + quad * 8;
                bf16x8 bh = *reinterpret_cast<const bf16x8*>(Bhi + bix);
                bf16x8 bl = *reinterpret_cast<const bf16x8*>(Blo + bix);
                floatx4 acr[4] = {};
                #pragma unroll
                for (int t = 0; t < 4; t++)
                    acr[t] = __builtin_amdgcn_mfma_f32_16x16x32_bf16(af[t], bl, acr[t], 0, 0, 0);
                #pragma unroll
                for (int t = 0; t < 4; t++)
                    acr[t] = __builtin_amdgcn_mfma_f32_16x16x32_bf16(af[t], bh, acr[t], 0, 0, 0);
                int colb = r * 256 + h * 32 + ct * 16 + m16;
                #pragma unroll
                for (int t = 0; t < 4; t++){
                    #pragma unroll
                    for (int reg = 0; reg < 4; reg++){
                        int node = base + t * 16 + quad * 4 + reg;
                        if (node < cend)
                            outF[(size_t)(node - c0) * 2048 + colb] = f2us(acr[t][reg]);
                    }
                }
            }
        }
    }
}

// ---- batched rel_msg GEMM (bf16 A, B hi/lo):
//      t[node][h*32+e] = sum_{r,d} M[node][r,h*32+d]*rel_msg[r,h,d,e]
//      wave w covers h in {2w,2w+1} x all 64 rows; acc persists across r ----
__global__ __launch_bounds__(256) void k_relmsg(
    const unsigned short* __restrict__ Mv,
    const unsigned short* __restrict__ Bhi, const unsigned short* __restrict__ Blo,
    unsigned short* __restrict__ outT, int c0, int cend)
{
    int base = c0 + blockIdx.x * 64;
    __shared__ __align__(16) unsigned short Ahi[64 * 264];
    int tid = threadIdx.x;
    int wave = tid >> 6, lane = tid & 63;
    int m16 = lane & 15, quad = lane >> 4;

    floatx4 acc[2][2][4] = {};   // [hh][ct][tile]

    for (int r = 0; r < RR; r++){
        __syncthreads();
        #pragma unroll
        for (int it = 0; it < 8; it++){
            int G = it * 256 + tid;       // granule of 8 halfs: 64 rows x 32 granules
            int row = G >> 5, g = G & 31;
            int node = base + row;
            uint4 vh;
            vh.x = vh.y = vh.z = vh.w = 0u;
            if (node < cend)
                vh = *reinterpret_cast<const uint4*>(Mv + (size_t)(node - c0) * 2048 + r * 256 + g * 8);
            *reinterpret_cast<uint4*>(&Ahi[row * 264 + g * 8]) = vh;
        }
        __syncthreads();
        #pragma unroll
        for (int hh = 0; hh < 2; hh++){
            int h = (wave << 1) + hh;
            bf16x8 ah[4];
            #pragma unroll
            for (int t = 0; t < 4; t++)
                ah[t] = *reinterpret_cast<const bf16x8*>(&Ahi[(t * 16 + m16) * 264 + h * 32 + quad * 8]);
            #pragma unroll
            for (int ct = 0; ct < 2; ct++){
                int bix = (((r * 8 + h) * 32) + ct * 16 + m16) * 32 + quad * 8;
                bf16x8 bh = *reinterpret_cast<const bf16x8*>(Bhi + bix);
                bf16x8 bl = *reinterpret_cast<const bf16x8*>(Blo + bix);
                #pragma unroll
                for (int t = 0; t < 4; t++){
                    acc[hh][ct][t] = __builtin_amdgcn_mfma_f32_16x16x32_bf16(ah[t], bh, acc[hh][ct][t], 0, 0, 0);
                    acc[hh][ct][t] = __builtin_amdgcn_mfma_f32_16x16x32_bf16(ah[t], bl, acc[hh][ct][t], 0, 0, 0);
                }
            }
        }
    }
    #pragma unroll
    for (int hh = 0; hh < 2; hh++){
        int h = (wave << 1) + hh;
        #pragma unroll
        for (int ct = 0; ct < 2; ct++){
            #pragma unroll
            for (int t = 0; t < 4; t++){
                #pragma unroll
                for (int reg = 0; reg < 4; reg++){
                    int node = base + t * 16 + quad * 4 + reg;
                    if (node < cend)
                        outT[(size_t)node * 256 + h * 32 + ct * 16 + m16] = f2us(acc[hh][ct][t][reg]);
                }
            }
        }
    }
}

// ---- CSR build ----
__global__ void k_zero(int* a, int n){
    int i = blockIdx.x * 256 + threadIdx.x;
    if (i < n) a[i] = 0;
}
__global__ void k_deg(const int* p2, const int* p3, const int* p4,
                      int* __restrict__ cnt, const int* __restrict__ meta, int E, int n){
    const int* dst = sel3(p2, p3, p4, meta[26]);
    int e = blockIdx.x * 256 + threadIdx.x;
    if (e < E){
        int d = dst[e];
        if (d >= 0 && d < n) atomicAdd(&cnt[d], 1);
    }
}
__global__ void k_scan1(const int* __restrict__ cnt, int* __restrict__ rowp,
                        int* __restrict__ bsum, int n){
    __shared__ int s[256];
    int b = blockIdx.x, tid = threadIdx.x;
    int i = b * 256 + tid;
    int v = (i < n) ? cnt[i] : 0;
    s[tid] = v;
    __syncthreads();
    for (int d = 1; d < 256; d <<= 1){
        int add = (tid >= d) ? s[tid - d] : 0;
        __syncthreads();
        s[tid] += add;
        __syncthreads();
    }
    if (i < n) rowp[i] = s[tid] - v;
    if (tid == 255) bsum[b] = s[255];
}
__global__ void k_scan2(int* bsum, int* rowp, int nb, int n){
    if (threadIdx.x == 0){
        int run = 0;
        for (int b = 0; b < nb; b++){ int t = bsum[b]; bsum[b] = run; run += t; }
        rowp[n] = run;
    }
}
__global__ void k_scan3(int* rowp, const int* __restrict__ bsum, int n){
    int i = blockIdx.x * 256 + threadIdx.x;
    if (i < n) rowp[i] += bsum[i >> 8];
}
__global__ void k_escat(const int* p2, const int* p3, const int* p4,
                        int* __restrict__ cur, const int* __restrict__ rowp,
                        int* __restrict__ eix, const int* __restrict__ meta, int E, int n){
    const int* dst = sel3(p2, p3, p4, meta[26]);
    int e = blockIdx.x * 256 + threadIdx.x;
    if (e < E){
        int d = dst[e];
        if (d >= 0 && d < n){
            int pos = atomicAdd(&cur[d], 1);
            eix[rowp[d] + pos] = e;
        }
    }
}

// ---- MFMA typed GEMM: QKV (validated r3, fp32-in adapted) ----
__global__ __launch_bounds__(256) void k_gemm_qkv(
    const void* __restrict__ Xv,
    const int* __restrict__ perm, const int* __restrict__ meta,
    const unsigned short* __restrict__ WT,
    const void* __restrict__ bk, const void* __restrict__ bq, const void* __restrict__ bv,
    unsigned short* __restrict__ kb, unsigned short* __restrict__ qb,
    unsigned short* __restrict__ vb)
{
    int rt = blockIdx.x;
    if (rt >= meta[12]) return;
    int fx = meta[30];
    int t = 0;
    while (t < TT - 1 && rt >= meta[8 + t + 1]) t++;
    int lt = rt - meta[8 + t];
    int rowStart = meta[4 + t] + (lt << 6);
    int rowEnd   = meta[4 + t] + meta[t];

    int ct = blockIdx.y;          // 0..5
    int mt = ct >> 1;             // 0=k 1=q 2=v
    int c0 = (ct & 1) * 128;
    const unsigned short* Wm = WT + (((mt << 2) + t) << 16);
    const void* bias = (mt == 0) ? bk : (mt == 1) ? bq : bv;
    int fb = meta[35 + mt];
    unsigned short* outb = (mt == 0) ? kb : (mt == 1) ? qb : vb;

    __shared__ __align__(16) unsigned short As[64 * 32];
    __shared__ __align__(16) unsigned short Bs[128 * 32];
    __shared__ int nodeIdx[64];

    int tid = threadIdx.x;
    if (tid < 64){
        int p = rowStart + tid;
        nodeIdx[tid] = perm[(p < rowEnd) ? p : (rowEnd - 1)];
    }
    __syncthreads();

    int wave = tid >> 6, lane = tid & 63;
    int wr = (wave >> 1) * 32;
    int wc = (wave & 1) * 64;
    int m16 = lane & 15, quad = lane >> 4;

    int arow = tid & 63, aseg = tid >> 6;
    int anode = nodeIdx[arow];

    floatx4 acc[2][4] = {};

    for (int k0 = 0; k0 < 256; k0 += 32){
        __syncthreads();
        uint4 av;
        if (fx){
            const float* af = (const float*)Xv + anode * 256 + aseg * 8 + k0;
            float4 f0 = *reinterpret_cast<const float4*>(af);
            float4 f1 = *reinterpret_cast<const float4*>(af + 4);
            av.x = (unsigned)f2us(f0.x) | ((unsigned)f2us(f0.y) << 16);
            av.y = (unsigned)f2us(f0.z) | ((unsigned)f2us(f0.w) << 16);
            av.z = (unsigned)f2us(f1.x) | ((unsigned)f2us(f1.y) << 16);
            av.w = (unsigned)f2us(f1.z) | ((unsigned)f2us(f1.w) << 16);
        } else {
            av = *reinterpret_cast<const uint4*>((const unsigned short*)Xv + anode * 256 + aseg * 8 + k0);
        }
        *reinterpret_cast<uint4*>(&As[sw32(arow, aseg)]) = av;
        #pragma unroll
        for (int it = 0; it < 2; it++){
            int idx2 = tid + it * 256;
            int cc = idx2 >> 2, g = idx2 & 3;
            uint4 bv4 = *reinterpret_cast<const uint4*>(Wm + (c0 + cc) * 256 + k0 + g * 8);
            *reinterpret_cast<uint4*>(&Bs[sw32(cc, g)]) = bv4;
        }
        __syncthreads();
        bf16x8 a[2], b[4];
        #pragma unroll
        for (int r = 0; r < 2; r++)
            a[r] = *reinterpret_cast<const bf16x8*>(&As[sw32(wr + r * 16 + m16, quad)]);
        #pragma unroll
        for (int c = 0; c < 4; c++)
            b[c] = *reinterpret_cast<const bf16x8*>(&Bs[sw32(wc + c * 16 + m16, quad)]);
        #pragma unroll
        for (int r = 0; r < 2; r++)
            #pragma unroll
            for (int c = 0; c < 4; c++)
                acc[r][c] = __builtin_amdgcn_mfma_f32_16x16x32_bf16(a[r], b[c], acc[r][c], 0, 0, 0);
    }

    #pragma unroll
    for (int r = 0; r < 2; r++){
        #pragma unroll
        for (int reg = 0; reg < 4; reg++){
            int row = wr + r * 16 + quad * 4 + reg;
            if (rowStart + row < rowEnd){
                int node = nodeIdx[row];
                #pragma unroll
                for (int c = 0; c < 4; c++){
                    int gc = c0 + wc + c * 16 + m16;
                    float v = acc[r][c][reg] + ldf(bias, t * 256 + gc, fb);
                    outb[node * 256 + gc] = f2us(v);
                }
            }
        }
    }
}

// ---- MFMA typed GEMM: output projection + skip gate (fp32 out) ----
__global__ __launch_bounds__(256) void k_gemm_out(
    const unsigned short* __restrict__ A,
    const void* __restrict__ Xv,
    const int* __restrict__ perm, const int* __restrict__ meta,
    const unsigned short* __restrict__ WTa,
    const void* __restrict__ ba, const void* __restrict__ skipv,
    float* __restrict__ out)
{
    int rt = blockIdx.x;
    if (rt >= meta[12]) return;
    int fx = meta[30], fba = meta[38], fsk = meta[42];
    int t = 0;
    while (t < TT - 1 && rt >= meta[8 + t + 1]) t++;
    int lt = rt - meta[8 + t];
    int rowStart = meta[4 + t] + (lt << 6);
    int rowEnd   = meta[4 + t] + meta[t];
    int c0 = blockIdx.y * 128;
    const unsigned short* Wm = WTa + (t << 16);
    float sg = ldf(skipv, t, fsk);
    float ag = 1.f / (1.f + __expf(-sg));

    __shared__ __align__(16) unsigned short As[64 * 32];
    __shared__ __align__(16) unsigned short Bs[128 * 32];
    __shared__ int nodeIdx[64];

    int tid = threadIdx.x;
    if (tid < 64){
        int p = rowStart + tid;
        nodeIdx[tid] = perm[(p < rowEnd) ? p : (rowEnd - 1)];
    }
    __syncthreads();

    int wave = tid >> 6, lane = tid & 63;
    int wr = (wave >> 1) * 32;
    int wc = (wave & 1) * 64;
    int m16 = lane & 15, quad = lane >> 4;

    int arow = tid & 63, aseg = tid >> 6;
    int anode = nodeIdx[arow];
    const unsigned short* aptr = A + anode * 256 + aseg * 8;

    floatx4 acc[2][4] = {};

    for (int k0 = 0; k0 < 256; k0 += 32){
        __syncthreads();
        uint4 av = *reinterpret_cast<const uint4*>(aptr + k0);
        *reinterpret_cast<uint4*>(&As[sw32(arow, aseg)]) = av;
        #pragma unroll
        for (int it = 0; it < 2; it++){
            int idx2 = tid + it * 256;
            int cc = idx2 >> 2, g = idx2 & 3;
            uint4 bv4 = *reinterpret_cast<const uint4*>(Wm + (c0 + cc) * 256 + k0 + g * 8);
            *reinterpret_cast<uint4*>(&Bs[sw32(cc, g)]) = bv4;
        }
        __syncthreads();
        bf16x8 a[2], b[4];
        #pragma unroll
        for (int r = 0; r < 2; r++)
            a[r] = *reinterpret_cast<const bf16x8*>(&As[sw32(wr + r * 16 + m16, quad)]);
        #pragma unroll
        for (int c = 0; c < 4; c++)
            b[c] = *reinterpret_cast<const bf16x8*>(&Bs[sw32(wc + c * 16 + m16, quad)]);
        #pragma unroll
        for (int r = 0; r < 2; r++)
            #pragma unroll
            for (int c = 0; c < 4; c++)
                acc[r][c] = __builtin_amdgcn_mfma_f32_16x16x32_bf16(a[r], b[c], acc[r][c], 0, 0, 0);
    }

    #pragma unroll
    for (int r = 0; r < 2; r++){
        #pragma unroll
        for (int reg = 0; reg < 4; reg++){
            int row = wr + r * 16 + quad * 4 + reg;
            if (rowStart + row < rowEnd){
                int node = nodeIdx[row];
                #pragma unroll
                for (int c = 0; c < 4; c++){
                    int gc = c0 + wc + c * 16 + m16;
                    float v = acc[r][c][reg] + ldf(ba, t * 256 + gc, fba);
                    float xv = ldf(Xv, node * 256 + gc, fx);
                    out[node * 256 + gc] = v * ag + xv * (1.f - ag);
                }
            }
        }
    }
}

// ---- VALU fallback projections (validated r7) ----
__global__ __launch_bounds__(256) void k_proj(
    const void* __restrict__ X, const int* __restrict__ nt,
    const void* __restrict__ Wk, const void* __restrict__ Wq, const void* __restrict__ Wv,
    const void* __restrict__ bk, const void* __restrict__ bq, const void* __restrict__ bv,
    unsigned short* __restrict__ kb, unsigned short* __restrict__ qtb,
    unsigned short* __restrict__ vb,
    const int* __restrict__ meta, int n)
{
    int i = blockIdx.x, tid = threadIdx.x;
    int fx = meta[30];
    int t = nt[i] & 3;
    __shared__ float xs[256];
    __shared__ float red[3][4][256];
    xs[tid] = ldf(X, i * 256 + tid, fx);
    __syncthreads();
    int seg = tid >> 6;
    int cg  = (tid & 63) * 4;
    int base = t * 65536 + cg;
    #pragma unroll
    for (int m = 0; m < 3; m++){
        const void* W = (m == 0) ? Wk : (m == 1) ? Wq : Wv;
        int fw = meta[31 + m];
        float ax = 0.f, ay = 0.f, az = 0.f, aw = 0.f;
        for (int k = seg * 64; k < seg * 64 + 64; k++){
            float xv = xs[k];
            float4 w = ldf4(W, base + k * 256, fw);
            ax += xv * w.x; ay += xv * w.y; az += xv * w.z; aw += xv * w.w;
        }
        float4 st = {ax, ay, az, aw};
        *reinterpret_cast<float4*>(&red[m][seg][cg]) = st;
    }
    __syncthreads();
    #pragma unroll
    for (int m = 0; m < 3; m++){
        const void* B = (m == 0) ? bk : (m == 1) ? bq : bv;
        unsigned short* O = (m == 0) ? kb : (m == 1) ? qtb : vb;
        float v = red[m][0][tid] + red[m][1][tid] + red[m][2][tid] + red[m][3][tid]
                + ldf(B, t * 256 + tid, meta[35 + m]);
        O[i * 256 + tid] = f2us(v);
    }
}
__global__ __launch_bounds__(256) void k_out(
    const unsigned short* __restrict__ tb,
    const void* __restrict__ X, const int* __restrict__ nt,
    const void* __restrict__ Wa, const void* __restrict__ ba,
    const void* __restrict__ skipv,
    float* __restrict__ out,
    const int* __restrict__ meta, int n)
{
    int i = blockIdx.x, tid = threadIdx.x;
    int fx = meta[30], fwa = meta[34], fba = meta[38], fsk = meta[42];
    int t = nt[i] & 3;
    __shared__ float xs[256];
    __shared__ float red[4][256];
    xs[tid] = us2f(tb[i * 256 + tid]);
    __syncthreads();
    int seg = tid >> 6;
    int cg  = (tid & 63) * 4;
    int base = t * 65536 + cg;
    float ax = 0.f, ay = 0.f, az = 0.f, aw = 0.f;
    for (int k = seg * 64; k < seg * 64 + 64; k++){
        float xv = xs[k];
        float4 w = ldf4(Wa, base + k * 256, fwa);
        ax += xv * w.x; ay += xv * w.y; az += xv * w.z; aw += xv * w.w;
    }
    float4 st = {ax, ay, az, aw};
    *reinterpret_cast<float4*>(&red[seg][cg]) = st;
    __syncthreads();
    float v = red[0][tid] + red[1][tid] + red[2][tid] + red[3][tid]
            + ldf(ba, t * 256 + tid, fba);
    float sg = ldf(skipv, t, fsk);
    float a  = 1.f / (1.f + __expf(-sg));
    float xv = ldf(X, i * 256 + tid, fx);
    out[i * 256 + tid] = v * a + xv * (1.f - a);
}

// ---- node attention + messages (fallback path, validated) ----
__global__ __launch_bounds__(256) void k_node2(
    unsigned short* qtb,
    const unsigned short* __restrict__ kb, const unsigned short* __restrict__ vb,
    const int* p2, const int* p3, const int* p4,
    const int* __restrict__ rowp, const int* __restrict__ eix,
    const void* __restrict__ rel_att, const void* __restrict__ rel_msg,
    const void* __restrict__ rel_pri,
    const int* __restrict__ meta, int n)
{
    const int* srcv = sel3(p2, p3, p4, meta[25]);
    const int* etv  = sel3(p2, p3, p4, meta[27]);
    int fra = meta[39], frm = meta[40], fpri = meta[41];
    int i = blockIdx.x, tid = threadIdx.x;
    int h5 = tid >> 5, z = tid & 31;

    __shared__ float qs[256];
    __shared__ float qA[RR * NH * 33];
    __shared__ float msum[RR][256];
    __shared__ float attS[16][NH];
    __shared__ float wnew[16][NH];
    __shared__ float mcur[RR][NH], dcur[RR][NH], scf[RR][NH];
    __shared__ int s_src[16], s_et[16];
    __shared__ float s_pri[RR * NH];
    __shared__ int s_mask;

    int e0 = rowp[i], deg = rowp[i + 1] - e0;

    if (tid < RR * NH) s_pri[tid] = ldf(rel_pri, tid, fpri);
    if (tid == 0) s_mask = 0;
    qs[tid] = us2f(qtb[i * 256 + tid]);
    #pragma unroll
    for (int r = 0; r < RR; r++) msum[r][tid] = 0.f;
    if (tid < RR * NH){ mcur[tid >> 3][tid & 7] = -1e30f; dcur[tid >> 3][tid & 7] = 0.f; }
    __syncthreads();

    {
        const float* qq = &qs[h5 * 32];
        #pragma unroll
        for (int r = 0; r < RR; r++){
            int base = (r * NH + h5) * 1024 + z * 32;
            float a0 = 0.f;
            #pragma unroll
            for (int e4 = 0; e4 < 8; e4++){
                float4 w = ldf4(rel_att, base + e4 * 4, fra);
                const float* q4 = qq + e4 * 4;
                a0 += w.x * q4[0] + w.y * q4[1] + w.z * q4[2] + w.w * q4[3];
            }
            qA[(r * NH + h5) * 33 + z] = a0;
        }
    }
    __syncthreads();

    for (int done = 0; done < deg; done += 16){
        int cs = min(16, deg - done);
        if (tid < cs){
            int e = eix[e0 + done + tid];
            int sj = srcv[e]; sj = (sj < 0) ? 0 : (sj >= n) ? n - 1 : sj;
            s_src[tid] = sj;
            int rr = etv[e] & 7;
            s_et[tid] = rr;
            atomicOr(&s_mask, 1 << rr);
        }
        __syncthreads();
        {
            int j = tid >> 4, hh = (tid >> 1) & 7, half = tid & 1;
            float pt = 0.f;
            if (j < cs){
                int sj = s_src[j], rj = s_et[j];
                const unsigned short* kp = kb + sj * 256 + hh * 32 + half * 16;
                const float* qa = &qA[(rj * NH + hh) * 33 + half * 16];
                uint4 u0 = *reinterpret_cast<const uint4*>(kp);
                uint4 u1 = *reinterpret_cast<const uint4*>(kp + 8);
                pt = lo2f(u0.x) * qa[0]  + hi2f(u0.x) * qa[1]
                   + lo2f(u0.y) * qa[2]  + hi2f(u0.y) * qa[3]
                   + lo2f(u0.z) * qa[4]  + hi2f(u0.z) * qa[5]
                   + lo2f(u0.w) * qa[6]  + hi2f(u0.w) * qa[7]
                   + lo2f(u1.x) * qa[8]  + hi2f(u1.x) * qa[9]
                   + lo2f(u1.y) * qa[10] + hi2f(u1.y) * qa[11]
                   + lo2f(u1.z) * qa[12] + hi2f(u1.z) * qa[13]
                   + lo2f(u1.w) * qa[14] + hi2f(u1.w) * qa[15];
            }
            pt += __shfl_xor(pt, 1);
            if (j < cs && half == 0)
                attS[j][hh] = pt * s_pri[s_et[j] * NH + hh] * 0.17677669529663687f;
        }
        __syncthreads();
        if (tid < RR * NH){
            int r = tid >> 3, hh = tid & 7;
            float m_old = mcur[r][hh];
            float m_new = m_old;
            for (int j = 0; j < cs; j++) if (s_et[j] == r) m_new = fmaxf(m_new, attS[j][hh]);
            float scale = __expf(m_old - m_new);
            float den = dcur[r][hh] * scale;
            for (int j = 0; j < cs; j++) if (s_et[j] == r) den += __expf(attS[j][hh] - m_new);
            mcur[r][hh] = m_new; dcur[r][hh] = den; scf[r][hh] = scale;
        }
        __syncthreads();
        #pragma unroll
        for (int r = 0; r < RR; r++) msum[r][tid] *= scf[r][h5];
        if (tid < cs * NH){
            int j = tid >> 3, hh = tid & 7;
            wnew[j][hh] = __expf(attS[j][hh] - mcur[s_et[j]][hh]);
        }
        __syncthreads();
        {
            float vvf[16];
            #pragma unroll
            for (int j = 0; j < 16; j++)
                if (j < cs) vvf[j] = us2f(vb[s_src[j] * 256 + tid]);
            for (int j = 0; j < cs; j++)
                msum[s_et[j]][tid] += wnew[j][h5] * vvf[j];
        }
        __syncthreads();
    }

    int mask = s_mask;
    #pragma unroll
    for (int r = 0; r < RR; r++){
        if ((mask >> r) & 1) msum[r][tid] /= dcur[r][h5];
    }
    __syncthreads();

    float tacc = 0.f;
    for (int r = 0; r < RR; r++){
        if (!((mask >> r) & 1)) continue;
        const float* ms = &msum[r][h5 * 32];
        int base = (r * NH + h5) * 1024 + z;
        float a0 = 0.f;
        #pragma unroll
        for (int c = 0; c < 32; c++)
            a0 += ms[c] * ldf(rel_msg, base + c * 32, frm);
        tacc += a0;
    }
    int np = __popc(mask); if (np == 0) np = 1;
    qtb[i * 256 + tid] = f2us(tacc / (float)np);
}

// ---- node attention, wave-per-node: 64-thread blocks, one node per block.
//      qt (bf16, 4 KB/node) read; M (bf16 plane) written in place ----
__global__ __launch_bounds__(64) void k_node5(
    const unsigned short* __restrict__ kb,
    const unsigned short* __restrict__ vb,
    unsigned short* __restrict__ qtM,
    const int* p2, const int* p3, const int* p4,
    const int* __restrict__ rowp, const int* __restrict__ eix,
    const void* __restrict__ rel_pri,
    const int* __restrict__ meta, int n, int c0)
{
    const int* srcv = sel3(p2, p3, p4, meta[25]);
    const int* etv  = sel3(p2, p3, p4, meta[27]);
    int fpri = meta[41];
    int i = c0 + blockIdx.x;
    int l = threadIdx.x;              // 0..63

    __shared__ float qA[RR * NH * 33];
    __shared__ float attS[16][NH];
    __shared__ float wnew[16][NH];
    __shared__ float mcur[RR][NH], dcur[RR][NH], scf[RR][NH];
    __shared__ int s_src[16], s_et[16];
    __shared__ float s_pri[RR * NH];
    __shared__ int s_mask;

    int e0 = rowp[i], deg = rowp[i + 1] - e0;

    s_pri[l] = ldf(rel_pri, l, fpri);
    if (l == 0) s_mask = 0;
    // stage qt row (bf16, 2048 vals) into LDS as f32, [r][h][33] layout
    {
        const unsigned short* qp = qtM + (size_t)blockIdx.x * 2048;
        #pragma unroll
        for (int c = 0; c < 4; c++){
            int G = c * 64 + l;          // granule of 8 halfs, 0..255
            uint4 v = *reinterpret_cast<const uint4*>(qp + G * 8);
            int r = G >> 5, h = (G >> 2) & 7, dd = (G & 3) * 8;
            float* dst = &qA[(r * NH + h) * 33 + dd];
            dst[0] = lo2f(v.x); dst[1] = hi2f(v.x);
            dst[2] = lo2f(v.y); dst[3] = hi2f(v.y);
            dst[4] = lo2f(v.z); dst[5] = hi2f(v.z);
            dst[6] = lo2f(v.w); dst[7] = hi2f(v.w);
        }
    }
    float racc[RR][4];
    #pragma unroll
    for (int r = 0; r < RR; r++){
        racc[r][0] = racc[r][1] = racc[r][2] = racc[r][3] = 0.f;
    }
    mcur[l >> 3][l & 7] = -1e30f;
    dcur[l >> 3][l & 7] = 0.f;
    __syncthreads();

    int hl = l >> 3;                  // h for cols l*4 .. l*4+3

    for (int done = 0; done < deg; done += 16){
        int cs = min(16, deg - done);
        if (l < cs){
            int e = eix[e0 + done + l];
            int sj = srcv[e]; sj = (sj < 0) ? 0 : (sj >= n) ? n - 1 : sj;
            s_src[l] = sj;
            int rr = etv[e] & 7;
            s_et[l] = rr;
            atomicOr(&s_mask, 1 << rr);
        }
        __syncthreads();
        // dots: lane = (j = l>>2, h2 = l&3) covers h = 2*h2, 2*h2+1 (full 32-d dots)
        {
            int j = l >> 2, h2 = l & 3;
            if (j < cs){
                int sj = s_src[j], rj = s_et[j];
                const unsigned short* kp = kb + (size_t)sj * 256 + h2 * 64;
                uint4 u0 = *reinterpret_cast<const uint4*>(kp);
                uint4 u1 = *reinterpret_cast<const uint4*>(kp + 8);
                uint4 u2 = *reinterpret_cast<const uint4*>(kp + 16);
                uint4 u3 = *reinterpret_cast<const uint4*>(kp + 24);
                uint4 u4 = *reinterpret_cast<const uint4*>(kp + 32);
                uint4 u5 = *reinterpret_cast<const uint4*>(kp + 40);
                uint4 u6 = *reinterpret_cast<const uint4*>(kp + 48);
                uint4 u7 = *reinterpret_cast<const uint4*>(kp + 56);
                const float* qa0 = &qA[(rj * NH + 2 * h2) * 33];
                const float* qa1 = qa0 + 33;
                float pt0 = dot8(u0, qa0) + dot8(u1, qa0 + 8)
                          + dot8(u2, qa0 + 16) + dot8(u3, qa0 + 24);
                float pt1 = dot8(u4, qa1) + dot8(u5, qa1 + 8)
                          + dot8(u6, qa1 + 16) + dot8(u7, qa1 + 24);
                int pb = s_et[j] * NH + 2 * h2;
                attS[j][2 * h2]     = pt0 * s_pri[pb]     * 0.17677669529663687f;
                attS[j][2 * h2 + 1] = pt1 * s_pri[pb + 1] * 0.17677669529663687f;
            }
        }
        __syncthreads();
        // online softmax: lane = (r = l>>3, h = l&7), exactly 64 combos
        {
            int r = l >> 3, hh = l & 7;
            float m_old = mcur[r][hh];
            float m_new = m_old;
            for (int j = 0; j < cs; j++) if (s_et[j] == r) m_new = fmaxf(m_new, attS[j][hh]);
            float scale = __expf(m_old - m_new);
            float den = dcur[r][hh] * scale;
            for (int j = 0; j < cs; j++) if (s_et[j] == r) den += __expf(attS[j][hh] - m_new);
            mcur[r][hh] = m_new; dcur[r][hh] = den; scf[r][hh] = scale;
        }
        __syncthreads();
        // wnew: lane = (j = l>>2, h2 = l&3)
        {
            int j = l >> 2, h2 = l & 3;
            if (j < cs){
                int rj = s_et[j];
                wnew[j][2 * h2]     = __expf(attS[j][2 * h2]     - mcur[rj][2 * h2]);
                wnew[j][2 * h2 + 1] = __expf(attS[j][2 * h2 + 1] - mcur[rj][2 * h2 + 1]);
            }
        }
        // rescale register accumulators (scf valid after previous barrier)
        #pragma unroll
        for (int r = 0; r < RR; r++){
            float sc = scf[r][hl];
            racc[r][0] *= sc; racc[r][1] *= sc; racc[r][2] *= sc; racc[r][3] *= sc;
        }
        __syncthreads();
        // accumulate: lane covers cols l*4 .. l*4+3 (h = hl for all 4)
        for (int j = 0; j < cs; j++){
            int sj = s_src[j];
            uint2 v2 = *reinterpret_cast<const uint2*>(vb + (size_t)sj * 256 + l * 4);
            float w = wnew[j][hl];
            int et = s_et[j];
            float wv0 = w * lo2f(v2.x), wv1 = w * hi2f(v2.x);
            float wv2 = w * lo2f(v2.y), wv3 = w * hi2f(v2.y);
            #pragma unroll
            for (int r = 0; r < RR; r++){
                bool m = (et == r);
                racc[r][0] += m ? wv0 : 0.f;
                racc[r][1] += m ? wv1 : 0.f;
                racc[r][2] += m ? wv2 : 0.f;
                racc[r][3] += m ? wv3 : 0.f;
            }
        }
        __syncthreads();
    }

    int mask = s_mask;
    int np = __popc(mask); if (np == 0) np = 1;
    float inv = 1.f / (float)np;
    // overwrite qt row with M = msum/den/np as one bf16 plane (row-local, safe)
    unsigned short* Mp = qtM + (size_t)blockIdx.x * 2048;
    #pragma unroll
    for (int r = 0; r < RR; r++){
        float d = ((mask >> r) & 1) ? (inv / dcur[r][hl]) : 0.f;
        unsigned int w0 = (unsigned)f2us(racc[r][0] * d) | ((unsigned)f2us(racc[r][1] * d) << 16);
        unsigned int w1 = (unsigned)f2us(racc[r][2] * d) | ((unsigned)f2us(racc[r][3] * d) << 16);
        uint2 pk; pk.x = w0; pk.y = w1;
        *reinterpret_cast<uint2*>(Mp + r * 256 + l * 4) = pk;
    }
}

extern "C" void kernel_launch(void* const* d_in, const int* in_sizes, int n_in,
                              void* d_out, int out_size, void* d_ws, size_t ws_size,
                              hipStream_t stream)
{
    const void* x        = d_in[0];
    const int* node_type = (const int*)d_in[1];
    const int* p2        = (const int*)d_in[2];
    const int* p3        = (const int*)d_in[3];
    const int* p4        = (const int*)d_in[4];
    const void* Wk = d_in[5];  const void* bk = d_in[6];
    const void* Wq = d_in[7];  const void* bq = d_in[8];
    const void* Wv = d_in[9];  const void* bv = d_in[10];
    const void* Wa = d_in[11]; const void* ba = d_in[12];
    const void* rel_att = d_in[13];
    const void* rel_msg = d_in[14];
    const void* rel_pri = d_in[15];
    const void* skipv   = d_in[16];
    float* out = (float*)d_out;

    bool ok = (n_in == 17);
    if (ok){
        ok = ok && (in_sizes[0] == in_sizes[1] * 256);
        ok = ok && (in_sizes[2] == in_sizes[3]) && (in_sizes[3] == in_sizes[4]);
        ok = ok && (in_sizes[5] == 262144) && (in_sizes[7] == 262144)
                && (in_sizes[9] == 262144) && (in_sizes[11] == 262144);
        ok = ok && (in_sizes[6] == 1024) && (in_sizes[8] == 1024)
                && (in_sizes[10] == 1024) && (in_sizes[12] == 1024);
        ok = ok && (in_sizes[13] == 65536) && (in_sizes[14] == 65536);
        ok = ok && (in_sizes[15] == 64) && (in_sizes[16] == 4);
        ok = ok && (out_size == in_sizes[0]);
    }
    if (!ok){
        k_zerofill<<<(out_size + 255) / 256, 256, 0, stream>>>(out, out_size);
        return;
    }

    int n = in_sizes[1];
    int E = in_sizes[2];
    int nb = (n + 255) / 256;
    int eb = (E + 255) / 256;

    char* ws = (char*)d_ws;
    int* meta = (int*)ws;
    size_t off = 256;
    int* cnt  = (int*)(ws + off); off += ((size_t)n * 4 + 255) & ~(size_t)255;
    int* bsum = (int*)(ws + off); off += ((size_t)nb * 4 + 255) & ~(size_t)255;
    int* rowp = (int*)(ws + off); off += ((size_t)(n + 1) * 4 + 255) & ~(size_t)255;
    int* eix  = (int*)(ws + off); off += ((size_t)E * 4 + 255) & ~(size_t)255;
    unsigned short* kb2 = (unsigned short*)(ws + off); off += (size_t)n * 256 * 2;
    unsigned short* vb2 = (unsigned short*)(ws + off); off += (size_t)n * 256 * 2;
    unsigned short* qtb = (unsigned short*)(ws + off); off += (size_t)n * 256 * 2;
    size_t off_lean = off;
    int* perm = (int*)(ws + off); off += ((size_t)n * 4 + 255) & ~(size_t)255;
    unsigned short* WT = (unsigned short*)(ws + off); off += (size_t)16 * 65536 * 2;
    size_t off_full = off;
    // ---- rel-transform tables (hi/lo bf16) + adaptive chunk buffer (bf16 rows) ----
    unsigned short* RATh = (unsigned short*)(ws + off); off += (size_t)65536 * 2;
    unsigned short* RATl = (unsigned short*)(ws + off); off += (size_t)65536 * 2;
    unsigned short* RMTh = (unsigned short*)(ws + off); off += (size_t)65536 * 2;
    unsigned short* RMTl = (unsigned short*)(ws + off); off += (size_t)65536 * 2;
    unsigned short* qtM = (unsigned short*)(ws + off);   // C * 4096 bytes
    size_t avail = (ws_size > off) ? ws_size - off : 0;
    long long Cavail = (long long)(avail / 4096);
    if (Cavail > (long long)n) Cavail = n;
    int C = 0;
    if (Cavail >= 1024){
        // target ~32K nodes/chunk (~128 MB qt+M stream); balance chunk sizes
        int target = 32768;
        int nch = (n + target - 1) / target;
        int Ceven = ((n + nch - 1) / nch + 63) & ~(int)63;
        C = (Ceven < (int)Cavail) ? Ceven : (int)Cavail;
    }

    k_flags<<<13, 256, 0, stream>>>(x, Wk, Wq, Wv, Wa, bk, bq, bv, ba,
                                    rel_att, rel_msg, rel_pri, skipv,
                                    in_sizes[0], in_sizes[5], in_sizes[7], in_sizes[9],
                                    in_sizes[11], in_sizes[6], in_sizes[8], in_sizes[10],
                                    in_sizes[12], in_sizes[13], in_sizes[14],
                                    in_sizes[15], in_sizes[16], meta);
    k_flagfix<<<1, 64, 0, stream>>>(meta);

    if (ws_size < off_lean){
        k_copy<<<(n * 256 + 255) / 256, 256, 0, stream>>>(x, out, meta, n * 256);
        return;
    }
    bool full  = (ws_size >= off_full);
    bool full2 = full && (C >= 1024);

    k_trio<<<3, 256, 0, stream>>>(p2, p3, p4, E, n, meta);
    k_pick<<<1, 64, 0, stream>>>(meta);

    // CSR
    k_zero<<<nb, 256, 0, stream>>>(cnt, n);
    k_deg<<<eb, 256, 0, stream>>>(p2, p3, p4, cnt, meta, E, n);
    k_scan1<<<nb, 256, 0, stream>>>(cnt, rowp, bsum, n);
    k_scan2<<<1, 64, 0, stream>>>(bsum, rowp, nb, n);
    k_scan3<<<nb, 256, 0, stream>>>(rowp, bsum, n);
    k_zero<<<nb, 256, 0, stream>>>(cnt, n);
    k_escat<<<eb, 256, 0, stream>>>(p2, p3, p4, cnt, rowp, eix, meta, E, n);

    if (full){
        k_init<<<1, 64, 0, stream>>>(meta);
        k_count<<<nb, 256, 0, stream>>>(node_type, meta, n);
        k_prefix<<<1, 64, 0, stream>>>(meta);
        k_scatter<<<nb, 256, 0, stream>>>(node_type, meta, perm, n);
        k_transW<<<4096, 256, 0, stream>>>(Wk, Wq, Wv, Wa, WT, meta);
        int maxRT = n / 64 + TT;
        k_gemm_qkv<<<dim3(maxRT, 6), 256, 0, stream>>>(x, perm, meta, WT, bk, bq, bv,
                                                       kb2, qtb, vb2);
        if (full2){
            k_transR<<<256, 256, 0, stream>>>(rel_att, rel_msg, RATh, RATl, RMTh, RMTl, meta);
            for (int c0 = 0; c0 < n; c0 += C){
                int cend = (c0 + C < n) ? (c0 + C) : n;
                int blk64 = (cend - c0 + 63) >> 6;
                k_relq<<<blk64, 256, 0, stream>>>(qtb, RATh, RATl, qtM, c0, cend);
                k_node5<<<cend - c0, 64, 0, stream>>>(kb2, vb2, qtM, p2, p3, p4,
                                                      rowp, eix, rel_pri, meta, n, c0);
                k_relmsg<<<blk64, 256, 0, stream>>>(qtM, RMTh, RMTl, qtb, c0, cend);
            }
        } else {
            k_node2<<<n, 256, 0, stream>>>(qtb, kb2, vb2, p2, p3, p4, rowp, eix,
                                           rel_att, rel_msg, rel_pri, meta, n);
        }
        k_gemm_out<<<dim3(maxRT, 2), 256, 0, stream>>>(qtb, x, perm, meta,
                                                       WT + 12 * 65536, ba, skipv, out);
    } else {
        k_proj<<<n, 256, 0, stream>>>(x, node_type, Wk, Wq, Wv, bk, bq, bv,
                                      kb2, qtb, vb2, meta, n);
        k_node2<<<n, 256, 0, stream>>>(qtb, kb2, vb2, p2, p3, p4, rowp, eix,
                                       rel_att, rel_msg, rel_pri, meta, n);
        k_out<<<n, 256, 0, stream>>>(qtb, x, node_type, Wa, ba, skipv, out, meta, n);
    }
}